// Round 1
// baseline (5331.981 us; speedup 1.0000x reference)
//
#include <hip/hip_runtime.h>
#include <math.h>

#define TID threadIdx.x

static __device__ __forceinline__ int wave_sum(int v) {
#pragma unroll
    for (int o = 32; o >= 1; o >>= 1) v += __shfl_xor(v, o, 64);
    return v;
}

// ---------------------------------------------------------------------------
// Curvature: per-point 10-NN covariance, lambda_min / sum(lambda)
// ---------------------------------------------------------------------------
__global__ __launch_bounds__(256) void curv_kernel(const float* __restrict__ pos,
                                                   float* __restrict__ curv) {
    __shared__ float4 sp[2048];
    int cloud = blockIdx.x >> 3;
    int base = cloud << 11;
    for (int j = TID; j < 2048; j += 256) {
        const float* p = pos + (size_t)(base + j) * 3;
        float x = p[0], y = p[1], z = p[2];
        sp[j] = make_float4(x, y, z, fmaf(x, x, fmaf(y, y, z * z)));
    }
    __syncthreads();
    int li = ((blockIdx.x & 7) << 8) + TID;
    float4 pi = sp[li];
    float bd[10];
    int bi[10];
#pragma unroll
    for (int t = 0; t < 10; ++t) { bd[t] = 3.0e38f; bi[t] = 0; }
    for (int j = 0; j < 2048; ++j) {
        float4 pj = sp[j];
        float dot = fmaf(pi.x, pj.x, fmaf(pi.y, pj.y, pi.z * pj.z));
        float d2 = pi.w + pj.w - 2.0f * dot;   // same form as reference _sqdist
        if (d2 < bd[9]) {
            bd[9] = d2; bi[9] = j;
#pragma unroll
            for (int t = 9; t > 0; --t) {
                if (bd[t] < bd[t - 1]) {
                    float td = bd[t]; bd[t] = bd[t - 1]; bd[t - 1] = td;
                    int ti = bi[t]; bi[t] = bi[t - 1]; bi[t - 1] = ti;
                }
            }
        }
    }
    double sx = 0, sy = 0, sz = 0;
#pragma unroll
    for (int t = 0; t < 10; ++t) { float4 p = sp[bi[t]]; sx += p.x; sy += p.y; sz += p.z; }
    double mx = sx / 10.0, my = sy / 10.0, mz = sz / 10.0;
    double cxx = 0, cxy = 0, cxz = 0, cyy = 0, cyz = 0, czz = 0;
#pragma unroll
    for (int t = 0; t < 10; ++t) {
        float4 p = sp[bi[t]];
        double dx = p.x - mx, dy = p.y - my, dz = p.z - mz;
        cxx += dx * dx; cxy += dx * dy; cxz += dx * dz;
        cyy += dy * dy; cyz += dy * dz; czz += dz * dz;
    }
    cxx /= 10.0; cxy /= 10.0; cxz /= 10.0; cyy /= 10.0; cyz /= 10.0; czz /= 10.0;
    double q = (cxx + cyy + czz) / 3.0;
    double b00 = cxx - q, b11 = cyy - q, b22 = czz - q;
    double p2 = b00 * b00 + b11 * b11 + b22 * b22 +
                2.0 * (cxy * cxy + cxz * cxz + cyz * cyz);
    double lmin;
    if (p2 <= 0.0) {
        lmin = q;
    } else {
        double p = sqrt(p2 / 6.0);
        double inv = 1.0 / p;
        double c00 = b00 * inv, c01 = cxy * inv, c02 = cxz * inv;
        double c11 = b11 * inv, c12 = cyz * inv, c22 = b22 * inv;
        double detB = c00 * (c11 * c22 - c12 * c12)
                    - c01 * (c01 * c22 - c12 * c02)
                    + c02 * (c01 * c12 - c11 * c02);
        double r = 0.5 * detB;
        r = fmin(1.0, fmax(-1.0, r));
        double phi = acos(r) / 3.0;
        lmin = q + 2.0 * p * cos(phi + 2.0943951023931953);  // smallest eigenvalue
    }
    double s3 = cxx + cyy + czz;
    curv[base + li] = (float)(lmin / (s3 + 1e-8));
}

// ---------------------------------------------------------------------------
// Weighted farthest point sampling (sequential; one block per cloud)
// ---------------------------------------------------------------------------
template <int N, int M, int SLOTS>
__global__ __launch_bounds__(256, 1) void fps_kernel(
    const float* __restrict__ srcpos, int stride, const float* __restrict__ srccurv,
    int* __restrict__ outIdx, float4* __restrict__ outPos,
    float* __restrict__ outCurv, float* __restrict__ outA, int ldA) {
    __shared__ float4 sp[N];
    __shared__ int sidx[M];
    __shared__ float rb[4];
    __shared__ int ri[4];
    int cloud = blockIdx.x;
    const float* cp = srcpos + (size_t)cloud * N * stride;
    for (int j = TID; j < N; j += 256)
        sp[j] = make_float4(cp[j * stride], cp[j * stride + 1], cp[j * stride + 2], 0.f);
    __syncthreads();
    float md[SLOTS], wv_[SLOTS], px[SLOTS], py[SLOTS], pz[SLOTS];
#pragma unroll
    for (int s = 0; s < SLOTS; ++s) {
        int p = (s << 8) + TID;
        float4 qq = sp[p];
        px[s] = qq.x; py[s] = qq.y; pz[s] = qq.z;
        md[s] = 3.0e38f;
        wv_[s] = fmaf(10.0f, srccurv[cloud * N + p], 1.0f);
    }
    int lane = TID & 63, w4 = TID >> 6;
    int cur = 0;
    if (TID == 0) sidx[0] = 0;
    for (int t = 1; t < M; ++t) {
        float4 cq = sp[cur];
        float best = -1.0f;
        int bix = 0;
#pragma unroll
        for (int s = 0; s < SLOTS; ++s) {
            float dx = px[s] - cq.x, dy = py[s] - cq.y, dz = pz[s] - cq.z;
            float nd = fmaf(dx, dx, fmaf(dy, dy, dz * dz));
            float m2 = fminf(md[s], nd);
            md[s] = m2;
            float sc = m2 * wv_[s];
            bool g = sc > best;           // strict > keeps earliest (lowest idx)
            best = g ? sc : best;
            bix = g ? ((s << 8) + TID) : bix;
        }
#pragma unroll
        for (int o = 32; o >= 1; o >>= 1) {
            float ob = __shfl_xor(best, o, 64);
            int oi = __shfl_xor(bix, o, 64);
            if (ob > best || (ob == best && oi < bix)) { best = ob; bix = oi; }
        }
        if (lane == 0) { rb[w4] = best; ri[w4] = bix; }
        __syncthreads();
        float b0 = rb[0];
        int i0 = ri[0];
#pragma unroll
        for (int k = 1; k < 4; ++k) {
            float bk = rb[k]; int ik = ri[k];
            if (bk > b0 || (bk == b0 && ik < i0)) { b0 = bk; i0 = ik; }
        }
        cur = i0;
        if (TID == 0) sidx[t] = cur;
        __syncthreads();
    }
    for (int j = TID; j < M; j += 256) {
        int id = sidx[j];
        float4 qv = sp[id];
        outIdx[cloud * M + j] = id;
        outPos[cloud * M + j] = qv;
        if (outCurv) outCurv[cloud * M + j] = srccurv[cloud * N + id];
        if (outA) {
            float* a = outA + (size_t)(cloud * M + j) * ldA;
            a[256] = qv.x; a[257] = qv.y; a[258] = qv.z;
        }
    }
}

// ---------------------------------------------------------------------------
// Exact top-64 (smallest d2, idx tie-break) selection within one wave.
// Candidates (key,idx) live in wave-private LDS lists; set semantics only.
// ---------------------------------------------------------------------------
static __device__ __forceinline__ int select_k64(const unsigned int* ck, const int* ci,
                                                 int c, int lane, int* cnt2, int* sel,
                                                 int* nbOut) {
    if (c <= 64) {
        *nbOut = c;
        return (lane < c) ? ci[lane] : 0;
    }
    unsigned int T = 0;  // becomes the 64th-smallest key
    for (int bit = 31; bit >= 0; --bit) {
        unsigned int mid = T | (1u << bit);
        int cl = 0;
        for (int q = lane; q < c; q += 64) cl += (ck[q] < mid) ? 1 : 0;
        if (wave_sum(cl) < 64) T = mid;
    }
    int cl = 0;
    for (int q = lane; q < c; q += 64) cl += (ck[q] < T) ? 1 : 0;
    int need = 64 - wave_sum(cl);
    int TI = 0;  // becomes the need-th smallest idx among keys == T
    for (int bit = 11; bit >= 0; --bit) {
        int mid = TI | (1 << bit);
        int ce = 0;
        for (int q = lane; q < c; q += 64) ce += (ck[q] == T && ci[q] < mid) ? 1 : 0;
        if (wave_sum(ce) < need) TI = mid;
    }
    for (int q = lane; q < c; q += 64) {
        unsigned int kq = ck[q];
        int iq = ci[q];
        if (kq < T || (kq == T && iq <= TI)) sel[atomicAdd(cnt2, 1)] = iq;
    }
    *nbOut = 64;
    return sel[lane];
}

// ---------------------------------------------------------------------------
// SA1: radius r=0.2 grouping over 2048 pts + PointNetConv(3->64->64->128) + max
// One wave per centroid, lane = neighbor slot. Weights via uniform (scalar) loads.
// ---------------------------------------------------------------------------
__global__ __launch_bounds__(256, 2) void conv1_kernel(
    const float* __restrict__ pos, const float4* __restrict__ pos1,
    const float* __restrict__ W1, const float* __restrict__ B1,
    const float* __restrict__ W2, const float* __restrict__ B2,
    const float* __restrict__ W3, const float* __restrict__ B3,
    float* __restrict__ x1) {
    __shared__ float4 sp[2048];
    __shared__ unsigned int ck[4][256];
    __shared__ int ci[4][256];
    __shared__ int cnt[4], cnt2[4];
    __shared__ int sel[4][64];
    int cloud = blockIdx.x >> 8;
    int w4 = TID >> 6, lane = TID & 63;
    int cent = ((blockIdx.x & 255) << 2) + w4;
    int g = (cloud << 10) + cent;
    int base = cloud << 11;
    for (int j = TID; j < 2048; j += 256) {
        const float* p = pos + (size_t)(base + j) * 3;
        sp[j] = make_float4(p[0], p[1], p[2], 0.f);
    }
    if (lane == 0) { cnt[w4] = 0; cnt2[w4] = 0; }
    __syncthreads();
    float4 cq = pos1[g];
    double cx = cq.x, cy = cq.y, cz = cq.z;
    for (int s = 0; s < 32; ++s) {
        int j = (s << 6) + lane;
        float4 pj = sp[j];
        double dx = (double)pj.x - cx, dy = (double)pj.y - cy, dz = (double)pj.z - cz;
        double d2 = dx * dx + dy * dy + dz * dz;
        if (d2 <= 0.2 * 0.2) {  // double-folded threshold matches reference r*r
            int p = atomicAdd(&cnt[w4], 1);
            if (p < 256) { ck[w4][p] = __float_as_uint((float)d2); ci[w4][p] = j; }
        }
    }
    __syncthreads();
    int c = min(cnt[w4], 256);
    int nb;
    int idxn = select_k64(ck[w4], ci[w4], c, lane, &cnt2[w4], sel[w4], &nb);
    bool valid = lane < nb;
    float4 pn = sp[idxn];
    float rx = pn.x - cq.x, ry = pn.y - cq.y, rz = pn.z - cq.z;
    // L1: 3 -> 64 (relu)
    float h1[64];
#pragma unroll
    for (int cc2 = 0; cc2 < 64; ++cc2) {
        float v = fmaf(rx, W1[cc2], fmaf(ry, W1[64 + cc2], fmaf(rz, W1[128 + cc2], B1[cc2])));
        h1[cc2] = fmaxf(v, 0.f);
    }
    // L2: 64 -> 64 (relu)
    float h2[64];
#pragma unroll
    for (int cc2 = 0; cc2 < 64; ++cc2) h2[cc2] = B2[cc2];
#pragma unroll
    for (int i = 0; i < 64; ++i) {
        float hv = h1[i];
        const float* wr = W2 + i * 64;
#pragma unroll
        for (int cc2 = 0; cc2 < 64; ++cc2) h2[cc2] = fmaf(hv, wr[cc2], h2[cc2]);
    }
#pragma unroll
    for (int cc2 = 0; cc2 < 64; ++cc2) h2[cc2] = fmaxf(h2[cc2], 0.f);
    // L3: 64 -> 128 (no relu) + masked max over neighbors
    float ores[2];
#pragma unroll
    for (int ch = 0; ch < 2; ++ch) {
        for (int k = 0; k < 64; ++k) {
            int cc2 = (ch << 6) + k;
            float v = B3[cc2];
#pragma unroll
            for (int i = 0; i < 64; ++i) v = fmaf(h2[i], W3[i * 128 + cc2], v);
            if (!valid) v = -1e30f;
#pragma unroll
            for (int o = 32; o >= 1; o >>= 1) v = fmaxf(v, __shfl_xor(v, o, 64));
            if (k == lane) ores[ch] = v;
        }
    }
    x1[(size_t)g * 128 + lane] = ores[0];
    x1[(size_t)g * 128 + 64 + lane] = ores[1];
}

// ---------------------------------------------------------------------------
// SA2: radius r=0.4 grouping over 1024 pts + PointNetConv(131->128->128->256)
// Writes x2 directly into MLP3's A buffer (row stride 260; cols 256..258 = pos2)
// ---------------------------------------------------------------------------
__global__ __launch_bounds__(256, 1) void conv2_kernel(
    const float4* __restrict__ pos1, const float4* __restrict__ pos2,
    const float* __restrict__ x1,
    const float* __restrict__ Wa, const float* __restrict__ Ba,
    const float* __restrict__ Wb, const float* __restrict__ Bb,
    const float* __restrict__ Wc, const float* __restrict__ Bc,
    float* __restrict__ Aout) {
    __shared__ float4 sp[1024];
    __shared__ unsigned int ck[4][512];
    __shared__ int ci[4][512];
    __shared__ int cnt[4], cnt2[4];
    __shared__ int sel[4][64];
    int cloud = blockIdx.x >> 6;
    int w4 = TID >> 6, lane = TID & 63;
    int cent = ((blockIdx.x & 63) << 2) + w4;
    int g = (cloud << 8) + cent;
    for (int j = TID; j < 1024; j += 256) sp[j] = pos1[(cloud << 10) + j];
    if (lane == 0) { cnt[w4] = 0; cnt2[w4] = 0; }
    __syncthreads();
    float4 cq = pos2[g];
    double cx = cq.x, cy = cq.y, cz = cq.z;
    for (int s = 0; s < 16; ++s) {
        int j = (s << 6) + lane;
        float4 pj = sp[j];
        double dx = (double)pj.x - cx, dy = (double)pj.y - cy, dz = (double)pj.z - cz;
        double d2 = dx * dx + dy * dy + dz * dz;
        if (d2 <= 0.4 * 0.4) {
            int p = atomicAdd(&cnt[w4], 1);
            if (p < 512) { ck[w4][p] = __float_as_uint((float)d2); ci[w4][p] = j; }
        }
    }
    __syncthreads();
    int c = min(cnt[w4], 512);
    int nb;
    int idxn = select_k64(ck[w4], ci[w4], c, lane, &cnt2[w4], sel[w4], &nb);
    bool valid = lane < nb;
    float4 pn = sp[idxn];
    float rx = pn.x - cq.x, ry = pn.y - cq.y, rz = pn.z - cq.z;
    const float4* xr = (const float4*)(x1 + (size_t)((cloud << 10) + idxn) * 128);
    // L1 (131 -> 128, relu) fused with L2 (128 -> 128) in two 64-channel halves
    // to cap register pressure (~200 VGPR peak instead of 270).
    float h2[128];
#pragma unroll
    for (int cc2 = 0; cc2 < 128; ++cc2) h2[cc2] = Bb[cc2];
#pragma unroll
    for (int half = 0; half < 2; ++half) {
        float h1[64];
#pragma unroll
        for (int cc2 = 0; cc2 < 64; ++cc2) h1[cc2] = Ba[(half << 6) + cc2];
        for (int ic = 0; ic < 32; ++ic) {
            float4 xv = xr[ic];
            const float* wr = Wa + (ic * 4) * 128 + (half << 6);
#pragma unroll
            for (int ii = 0; ii < 4; ++ii) {
                float xs = (&xv.x)[ii];
#pragma unroll
                for (int cc2 = 0; cc2 < 64; ++cc2)
                    h1[cc2] = fmaf(xs, wr[ii * 128 + cc2], h1[cc2]);
            }
        }
#pragma unroll
        for (int cc2 = 0; cc2 < 64; ++cc2) {
            float v = fmaf(rx, Wa[128 * 128 + (half << 6) + cc2],
                    fmaf(ry, Wa[129 * 128 + (half << 6) + cc2],
                    fmaf(rz, Wa[130 * 128 + (half << 6) + cc2], h1[cc2])));
            h1[cc2] = fmaxf(v, 0.f);
        }
#pragma unroll
        for (int i = 0; i < 64; ++i) {
            float hv = h1[i];
            const float* wr = Wb + ((half << 6) + i) * 128;
#pragma unroll
            for (int cc2 = 0; cc2 < 128; ++cc2) h2[cc2] = fmaf(hv, wr[cc2], h2[cc2]);
        }
    }
#pragma unroll
    for (int cc2 = 0; cc2 < 128; ++cc2) h2[cc2] = fmaxf(h2[cc2], 0.f);
    // L3 (128 -> 256, no relu) + masked max
    float ores[4];
#pragma unroll
    for (int ch = 0; ch < 4; ++ch) {
        for (int k = 0; k < 64; ++k) {
            int cc2 = (ch << 6) + k;
            float v = Bc[cc2];
#pragma unroll
            for (int i = 0; i < 128; ++i) v = fmaf(h2[i], Wc[i * 256 + cc2], v);
            if (!valid) v = -1e30f;
#pragma unroll
            for (int o = 32; o >= 1; o >>= 1) v = fmaxf(v, __shfl_xor(v, o, 64));
            if (k == lane) ores[ch] = v;
        }
    }
    float* arow = Aout + (size_t)g * 260;
    arow[lane] = ores[0];
    arow[64 + lane] = ores[1];
    arow[128 + lane] = ores[2];
    arow[192 + lane] = ores[3];
}

// ---------------------------------------------------------------------------
// fp32 tiled GEMM: C[M,N] = A[M,K] @ B[K,N] + bias (+relu). 64x64 tiles.
// ---------------------------------------------------------------------------
__global__ __launch_bounds__(256, 2) void gemm_bias(
    const float* __restrict__ A, int lda, const float* __restrict__ Bw, int ldb,
    const float* __restrict__ bias, float* __restrict__ C, int ldc,
    int M, int N, int K, int relu) {
    __shared__ float As[16][68];
    __shared__ float Bs[16][68];
    int nbx = N >> 6;
    int bx = blockIdx.x % nbx, by = blockIdx.x / nbx;
    int tx = TID & 15, ty = TID >> 4;
    int r0 = by << 6, c0 = bx << 6;
    float acc[4][4];
#pragma unroll
    for (int i = 0; i < 4; ++i)
#pragma unroll
        for (int j = 0; j < 4; ++j) acc[i][j] = 0.f;
    int lr = TID >> 2, lk = (TID & 3) << 2;
    int ln = TID & 63, lk2 = TID >> 6;
    for (int k0 = 0; k0 < K; k0 += 16) {
#pragma unroll
        for (int u = 0; u < 4; ++u) {
            int kk = k0 + lk + u;
            As[lk + u][lr] = (kk < K) ? A[(size_t)(r0 + lr) * lda + kk] : 0.f;
        }
#pragma unroll
        for (int u = 0; u < 4; ++u) {
            int krow = lk2 + (u << 2);
            int kk = k0 + krow;
            Bs[krow][ln] = (kk < K) ? Bw[(size_t)kk * ldb + c0 + ln] : 0.f;
        }
        __syncthreads();
#pragma unroll
        for (int kk = 0; kk < 16; ++kk) {
            float av[4], bv[4];
#pragma unroll
            for (int i = 0; i < 4; ++i) av[i] = As[kk][(ty << 2) + i];
#pragma unroll
            for (int j = 0; j < 4; ++j) bv[j] = Bs[kk][(tx << 2) + j];
#pragma unroll
            for (int i = 0; i < 4; ++i)
#pragma unroll
                for (int j = 0; j < 4; ++j) acc[i][j] = fmaf(av[i], bv[j], acc[i][j]);
        }
        __syncthreads();
    }
#pragma unroll
    for (int i = 0; i < 4; ++i) {
        int row = r0 + (ty << 2) + i;
#pragma unroll
        for (int j = 0; j < 4; ++j) {
            int col = c0 + (tx << 2) + j;
            float v = acc[i][j] + bias[col];
            if (relu) v = fmaxf(v, 0.f);
            C[(size_t)row * ldc + col] = v;
        }
    }
}

// ---------------------------------------------------------------------------
// Per-cloud max over 256 rows of h3 -> gfeat[8][1024]
// ---------------------------------------------------------------------------
__global__ __launch_bounds__(256) void rowmax_kernel(const float* __restrict__ h3,
                                                     float* __restrict__ gfeat) {
    int cloud = blockIdx.x;
    for (int cc = TID; cc < 1024; cc += 256) {
        float m = -3.0e38f;
        for (int r = 0; r < 256; ++r)
            m = fmaxf(m, h3[(size_t)((cloud << 8) + r) * 1024 + cc]);
        gfeat[(cloud << 10) + cc] = m;
    }
}

// ---------------------------------------------------------------------------
// Head MLP 1024->512->256->10 + log_softmax (one block per cloud)
// ---------------------------------------------------------------------------
__global__ __launch_bounds__(256) void head_kernel(
    const float* __restrict__ gfeat,
    const float* __restrict__ Wh1, const float* __restrict__ bh1,
    const float* __restrict__ Wh2, const float* __restrict__ bh2,
    const float* __restrict__ Wh3, const float* __restrict__ bh3,
    float* __restrict__ out) {
    __shared__ float gg[1024];
    __shared__ float s1[512];
    __shared__ float s2[256];
    __shared__ float lg[10];
    int cloud = blockIdx.x;
    for (int i = TID; i < 1024; i += 256) gg[i] = gfeat[(cloud << 10) + i];
    __syncthreads();
    for (int cc = TID; cc < 512; cc += 256) {
        float v = bh1[cc];
        for (int i = 0; i < 1024; ++i) v = fmaf(gg[i], Wh1[i * 512 + cc], v);
        s1[cc] = fmaxf(v, 0.f);
    }
    __syncthreads();
    for (int cc = TID; cc < 256; cc += 256) {
        float v = bh2[cc];
        for (int i = 0; i < 512; ++i) v = fmaf(s1[i], Wh2[i * 256 + cc], v);
        s2[cc] = fmaxf(v, 0.f);
    }
    __syncthreads();
    if (TID < 10) {
        float v = bh3[TID];
        for (int i = 0; i < 256; ++i) v = fmaf(s2[i], Wh3[i * 10 + TID], v);
        lg[TID] = v;
    }
    __syncthreads();
    if (TID == 0) {
        float mx = lg[0];
        for (int i = 1; i < 10; ++i) mx = fmaxf(mx, lg[i]);
        float s = 0.f;
        for (int i = 0; i < 10; ++i) s += expf(lg[i] - mx);
        float lse = mx + logf(s);
        for (int i = 0; i < 10; ++i) out[cloud * 10 + i] = lg[i] - lse;
    }
}

// ---------------------------------------------------------------------------
// Launch. Workspace layout (12.5 MB total; regions reused across phases):
//   [0      ] curv      64 KB      [512K   ] x1   4 MB  (reused as h2g)
//   [64K    ] idx1      32 KB      [4.5M   ] A    2.03 MB (reused under h3g)
//   [96K    ] pos1     128 KB      [~6.53M ] h1g  2 MB   (reused under h3g)
//   [224K   ] curv1     32 KB      [4.5M   ] h3g  8 MB  -> ends 12.5M
//   [256K   ] idx2       8 KB
//   [264K   ] pos2      32 KB
//   [296K   ] gfeat     32 KB
// ---------------------------------------------------------------------------
extern "C" void kernel_launch(void* const* d_in, const int* in_sizes, int n_in,
                              void* d_out, int out_size, void* d_ws, size_t ws_size,
                              hipStream_t stream) {
    (void)in_sizes; (void)n_in; (void)out_size; (void)ws_size;
    const float* pos = (const float*)d_in[0];
    const float* W1a = (const float*)d_in[1];  const float* b1a = (const float*)d_in[2];
    const float* W1b = (const float*)d_in[3];  const float* b1b = (const float*)d_in[4];
    const float* W1c = (const float*)d_in[5];  const float* b1c = (const float*)d_in[6];
    const float* W2a = (const float*)d_in[7];  const float* b2a = (const float*)d_in[8];
    const float* W2b = (const float*)d_in[9];  const float* b2b = (const float*)d_in[10];
    const float* W2c = (const float*)d_in[11]; const float* b2c = (const float*)d_in[12];
    const float* W3a = (const float*)d_in[13]; const float* b3a = (const float*)d_in[14];
    const float* W3b = (const float*)d_in[15]; const float* b3b = (const float*)d_in[16];
    const float* W3c = (const float*)d_in[17]; const float* b3c = (const float*)d_in[18];
    const float* Wh1 = (const float*)d_in[19]; const float* bh1 = (const float*)d_in[20];
    const float* Wh2 = (const float*)d_in[21]; const float* bh2 = (const float*)d_in[22];
    const float* Wh3 = (const float*)d_in[23]; const float* bh3 = (const float*)d_in[24];

    char* ws = (char*)d_ws;
    float*  curv  = (float*)(ws + 0);
    int*    idx1  = (int*)(ws + 65536);
    float4* pos1  = (float4*)(ws + 98304);
    float*  curv1 = (float*)(ws + 229376);
    int*    idx2  = (int*)(ws + 262144);
    float4* pos2  = (float4*)(ws + 270336);
    float*  gfeat = (float*)(ws + 303104);
    float*  x1    = (float*)(ws + 524288);
    float*  Abuf  = (float*)(ws + 4718592);
    float*  h1g   = (float*)(ws + 6848512);
    float*  h2g   = x1;     // x1 dead after conv2
    float*  h3g   = Abuf;   // A + h1g dead after gemm2

    curv_kernel<<<64, 256, 0, stream>>>(pos, curv);
    fps_kernel<2048, 1024, 8><<<8, 256, 0, stream>>>(pos, 3, curv, idx1, pos1, curv1,
                                                     nullptr, 0);
    fps_kernel<1024, 256, 4><<<8, 256, 0, stream>>>((const float*)pos1, 4, curv1, idx2,
                                                    pos2, nullptr, Abuf, 260);
    conv1_kernel<<<2048, 256, 0, stream>>>(pos, pos1, W1a, b1a, W1b, b1b, W1c, b1c, x1);
    conv2_kernel<<<512, 256, 0, stream>>>(pos1, pos2, x1, W2a, b2a, W2b, b2b, W2c, b2c,
                                          Abuf);
    gemm_bias<<<128, 256, 0, stream>>>(Abuf, 260, W3a, 256, b3a, h1g, 256,
                                       2048, 256, 259, 1);
    gemm_bias<<<256, 256, 0, stream>>>(h1g, 256, W3b, 512, b3b, h2g, 512,
                                       2048, 512, 256, 1);
    gemm_bias<<<512, 256, 0, stream>>>(h2g, 512, W3c, 1024, b3c, h3g, 1024,
                                       2048, 1024, 512, 0);
    rowmax_kernel<<<8, 256, 0, stream>>>(h3g, gfeat);
    head_kernel<<<8, 256, 0, stream>>>(gfeat, Wh1, bh1, Wh2, bh2, Wh3, bh3,
                                       (float*)d_out);
}

// Round 2
// 3063.949 us; speedup vs baseline: 1.7402x; 1.7402x over previous
//
#include <hip/hip_runtime.h>
#include <hip/hip_fp16.h>
#include <math.h>

#define TID threadIdx.x

static __device__ __forceinline__ int wave_sum(int v) {
#pragma unroll
    for (int o = 32; o >= 1; o >>= 1) v += __shfl_xor(v, o, 64);
    return v;
}

// ---------------------------------------------------------------------------
// Curvature: per-point 10-NN covariance, lambda_min / sum(lambda)
// ---------------------------------------------------------------------------
__global__ __launch_bounds__(256) void curv_kernel(const float* __restrict__ pos,
                                                   float* __restrict__ curv) {
    __shared__ float4 sp[2048];
    int cloud = blockIdx.x >> 3;
    int base = cloud << 11;
    for (int j = TID; j < 2048; j += 256) {
        const float* p = pos + (size_t)(base + j) * 3;
        float x = p[0], y = p[1], z = p[2];
        sp[j] = make_float4(x, y, z, fmaf(x, x, fmaf(y, y, z * z)));
    }
    __syncthreads();
    int li = ((blockIdx.x & 7) << 8) + TID;
    float4 pi = sp[li];
    float bd[10];
    int bi[10];
#pragma unroll
    for (int t = 0; t < 10; ++t) { bd[t] = 3.0e38f; bi[t] = 0; }
    for (int j = 0; j < 2048; ++j) {
        float4 pj = sp[j];
        float dot = fmaf(pi.x, pj.x, fmaf(pi.y, pj.y, pi.z * pj.z));
        float d2 = pi.w + pj.w - 2.0f * dot;   // same form as reference _sqdist
        if (d2 < bd[9]) {
            bd[9] = d2; bi[9] = j;
#pragma unroll
            for (int t = 9; t > 0; --t) {
                if (bd[t] < bd[t - 1]) {
                    float td = bd[t]; bd[t] = bd[t - 1]; bd[t - 1] = td;
                    int ti = bi[t]; bi[t] = bi[t - 1]; bi[t - 1] = ti;
                }
            }
        }
    }
    double sx = 0, sy = 0, sz = 0;
#pragma unroll
    for (int t = 0; t < 10; ++t) { float4 p = sp[bi[t]]; sx += p.x; sy += p.y; sz += p.z; }
    double mx = sx / 10.0, my = sy / 10.0, mz = sz / 10.0;
    double cxx = 0, cxy = 0, cxz = 0, cyy = 0, cyz = 0, czz = 0;
#pragma unroll
    for (int t = 0; t < 10; ++t) {
        float4 p = sp[bi[t]];
        double dx = p.x - mx, dy = p.y - my, dz = p.z - mz;
        cxx += dx * dx; cxy += dx * dy; cxz += dx * dz;
        cyy += dy * dy; cyz += dy * dz; czz += dz * dz;
    }
    cxx /= 10.0; cxy /= 10.0; cxz /= 10.0; cyy /= 10.0; cyz /= 10.0; czz /= 10.0;
    double q = (cxx + cyy + czz) / 3.0;
    double b00 = cxx - q, b11 = cyy - q, b22 = czz - q;
    double p2 = b00 * b00 + b11 * b11 + b22 * b22 +
                2.0 * (cxy * cxy + cxz * cxz + cyz * cyz);
    double lmin;
    if (p2 <= 0.0) {
        lmin = q;
    } else {
        double p = sqrt(p2 / 6.0);
        double inv = 1.0 / p;
        double c00 = b00 * inv, c01 = cxy * inv, c02 = cxz * inv;
        double c11 = b11 * inv, c12 = cyz * inv, c22 = b22 * inv;
        double detB = c00 * (c11 * c22 - c12 * c12)
                    - c01 * (c01 * c22 - c12 * c02)
                    + c02 * (c01 * c12 - c11 * c02);
        double r = 0.5 * detB;
        r = fmin(1.0, fmax(-1.0, r));
        double phi = acos(r) / 3.0;
        lmin = q + 2.0 * p * cos(phi + 2.0943951023931953);  // smallest eigenvalue
    }
    double s3 = cxx + cyy + czz;
    curv[base + li] = (float)(lmin / (s3 + 1e-8));
}

// ---------------------------------------------------------------------------
// Weighted farthest point sampling (sequential; one block per cloud)
// ---------------------------------------------------------------------------
template <int N, int M, int SLOTS>
__global__ __launch_bounds__(256, 1) void fps_kernel(
    const float* __restrict__ srcpos, int stride, const float* __restrict__ srccurv,
    int* __restrict__ outIdx, float4* __restrict__ outPos,
    float* __restrict__ outCurv, float* __restrict__ outA, int ldA) {
    __shared__ float4 sp[N];
    __shared__ int sidx[M];
    __shared__ float rb[4];
    __shared__ int ri[4];
    int cloud = blockIdx.x;
    const float* cp = srcpos + (size_t)cloud * N * stride;
    for (int j = TID; j < N; j += 256)
        sp[j] = make_float4(cp[j * stride], cp[j * stride + 1], cp[j * stride + 2], 0.f);
    __syncthreads();
    float md[SLOTS], wv_[SLOTS], px[SLOTS], py[SLOTS], pz[SLOTS];
#pragma unroll
    for (int s = 0; s < SLOTS; ++s) {
        int p = (s << 8) + TID;
        float4 qq = sp[p];
        px[s] = qq.x; py[s] = qq.y; pz[s] = qq.z;
        md[s] = 3.0e38f;
        wv_[s] = fmaf(10.0f, srccurv[cloud * N + p], 1.0f);
    }
    int lane = TID & 63, w4 = TID >> 6;
    int cur = 0;
    if (TID == 0) sidx[0] = 0;
    for (int t = 1; t < M; ++t) {
        float4 cq = sp[cur];
        float best = -1.0f;
        int bix = 0;
#pragma unroll
        for (int s = 0; s < SLOTS; ++s) {
            float dx = px[s] - cq.x, dy = py[s] - cq.y, dz = pz[s] - cq.z;
            float nd = fmaf(dx, dx, fmaf(dy, dy, dz * dz));
            float m2 = fminf(md[s], nd);
            md[s] = m2;
            float sc = m2 * wv_[s];
            bool g = sc > best;           // strict > keeps earliest (lowest idx)
            best = g ? sc : best;
            bix = g ? ((s << 8) + TID) : bix;
        }
#pragma unroll
        for (int o = 32; o >= 1; o >>= 1) {
            float ob = __shfl_xor(best, o, 64);
            int oi = __shfl_xor(bix, o, 64);
            if (ob > best || (ob == best && oi < bix)) { best = ob; bix = oi; }
        }
        if (lane == 0) { rb[w4] = best; ri[w4] = bix; }
        __syncthreads();
        float b0 = rb[0];
        int i0 = ri[0];
#pragma unroll
        for (int k = 1; k < 4; ++k) {
            float bk = rb[k]; int ik = ri[k];
            if (bk > b0 || (bk == b0 && ik < i0)) { b0 = bk; i0 = ik; }
        }
        cur = i0;
        if (TID == 0) sidx[t] = cur;
        __syncthreads();
    }
    for (int j = TID; j < M; j += 256) {
        int id = sidx[j];
        float4 qv = sp[id];
        outIdx[cloud * M + j] = id;
        outPos[cloud * M + j] = qv;
        if (outCurv) outCurv[cloud * M + j] = srccurv[cloud * N + id];
        if (outA) {
            float* a = outA + (size_t)(cloud * M + j) * ldA;
            a[256] = qv.x; a[257] = qv.y; a[258] = qv.z;
        }
    }
}

// ---------------------------------------------------------------------------
// Exact top-64 (smallest d2, idx tie-break) selection within one wave.
// ---------------------------------------------------------------------------
static __device__ __forceinline__ int select_k64(const unsigned int* ck, const int* ci,
                                                 int c, int lane, int* cnt2, int* sel,
                                                 int* nbOut) {
    if (c <= 64) {
        *nbOut = c;
        return (lane < c) ? ci[lane] : 0;
    }
    unsigned int T = 0;  // becomes the 64th-smallest key
    for (int bit = 31; bit >= 0; --bit) {
        unsigned int mid = T | (1u << bit);
        int cl = 0;
        for (int q = lane; q < c; q += 64) cl += (ck[q] < mid) ? 1 : 0;
        if (wave_sum(cl) < 64) T = mid;
    }
    int cl = 0;
    for (int q = lane; q < c; q += 64) cl += (ck[q] < T) ? 1 : 0;
    int need = 64 - wave_sum(cl);
    int TI = 0;  // becomes the need-th smallest idx among keys == T
    for (int bit = 11; bit >= 0; --bit) {
        int mid = TI | (1 << bit);
        int ce = 0;
        for (int q = lane; q < c; q += 64) ce += (ck[q] == T && ci[q] < mid) ? 1 : 0;
        if (wave_sum(ce) < need) TI = mid;
    }
    for (int q = lane; q < c; q += 64) {
        unsigned int kq = ck[q];
        int iq = ci[q];
        if (kq < T || (kq == T && iq <= TI)) sel[atomicAdd(cnt2, 1)] = iq;
    }
    *nbOut = 64;
    return sel[lane];
}

// ---------------------------------------------------------------------------
// SA1: radius r=0.2 grouping + PointNetConv(3->64->64->128) + max.
// L3 restructured: h2 staged to LDS (fp32, XOR-swizzled), lane = out channel,
// weights hoisted to registers as coalesced vector loads, running max over n.
// LDS union: grouping buffers (41KB) die before the 64KB h2 stage is written.
// ---------------------------------------------------------------------------
union U1 {
    struct {
        float4 sp[2048];
        unsigned ck[4][256];
        int ci[4][256];
        int sel[4][64];
        int cnt[4], cnt2[4];
    } p;
    float h2s[4][4096];   // [wave][n*64 + (j ^ ((n&7)<<3))]
};

__global__ __launch_bounds__(256, 2) void conv1_kernel(
    const float* __restrict__ pos, const float4* __restrict__ pos1,
    const float* __restrict__ W1, const float* __restrict__ B1,
    const float* __restrict__ W2, const float* __restrict__ B2,
    const float* __restrict__ W3, const float* __restrict__ B3,
    float* __restrict__ x1) {
    __shared__ U1 u;
    int cloud = blockIdx.x >> 8;
    int w4 = TID >> 6, lane = TID & 63;
    int cent = ((blockIdx.x & 255) << 2) + w4;
    int g = (cloud << 10) + cent;
    int base = cloud << 11;
    for (int j = TID; j < 2048; j += 256) {
        const float* p = pos + (size_t)(base + j) * 3;
        u.p.sp[j] = make_float4(p[0], p[1], p[2], 0.f);
    }
    if (lane == 0) { u.p.cnt[w4] = 0; u.p.cnt2[w4] = 0; }
    __syncthreads();
    float4 cq = pos1[g];
    double cx = cq.x, cy = cq.y, cz = cq.z;
    for (int s = 0; s < 32; ++s) {
        int j = (s << 6) + lane;
        float4 pj = u.p.sp[j];
        double dx = (double)pj.x - cx, dy = (double)pj.y - cy, dz = (double)pj.z - cz;
        double d2 = dx * dx + dy * dy + dz * dz;
        if (d2 <= 0.2 * 0.2) {
            int p = atomicAdd(&u.p.cnt[w4], 1);
            if (p < 256) { u.p.ck[w4][p] = __float_as_uint((float)d2); u.p.ci[w4][p] = j; }
        }
    }
    __syncthreads();
    int c = min(u.p.cnt[w4], 256);
    int nb;
    int idxn = select_k64(u.p.ck[w4], u.p.ci[w4], c, lane, &u.p.cnt2[w4],
                          u.p.sel[w4], &nb);
    float4 pn = u.p.sp[idxn];
    float rx = pn.x - cq.x, ry = pn.y - cq.y, rz = pn.z - cq.z;
    // L1: 3 -> 64 (relu)
    float h1[64];
#pragma unroll
    for (int cc2 = 0; cc2 < 64; ++cc2) {
        float v = fmaf(rx, W1[cc2], fmaf(ry, W1[64 + cc2], fmaf(rz, W1[128 + cc2], B1[cc2])));
        h1[cc2] = fmaxf(v, 0.f);
    }
    // L2: 64 -> 64 (relu)
    float h2[64];
#pragma unroll
    for (int cc2 = 0; cc2 < 64; ++cc2) h2[cc2] = B2[cc2];
#pragma unroll
    for (int i = 0; i < 64; ++i) {
        float hv = h1[i];
        const float* wr = W2 + i * 64;
#pragma unroll
        for (int cc2 = 0; cc2 < 64; ++cc2) h2[cc2] = fmaf(hv, wr[cc2], h2[cc2]);
    }
#pragma unroll
    for (int cc2 = 0; cc2 < 64; ++cc2) h2[cc2] = fmaxf(h2[cc2], 0.f);
    // --- stage h2 to LDS (fp32), lane = neighbor slot, XOR swizzle ---
    __syncthreads();   // all waves done with grouping buffers / sp
    {
        float* hrow = &u.h2s[w4][lane << 6];
        int sw = (lane & 7) << 3;
#pragma unroll
        for (int q = 0; q < 16; ++q) {
            int jp = (q << 2) ^ sw;   // position jp holds h2[jp ^ sw] = h2[4q+k]
            *(float4*)&hrow[jp] =
                make_float4(h2[(q << 2)], h2[(q << 2) + 1], h2[(q << 2) + 2], h2[(q << 2) + 3]);
        }
    }
    // --- L3: lane = output channel (2 passes worth held at once), max over n ---
    float w0[64], w1[64];
#pragma unroll
    for (int i = 0; i < 64; ++i) {
        w0[i] = W3[i * 128 + lane];
        w1[i] = W3[i * 128 + 64 + lane];
    }
    float b0v = B3[lane], b1v = B3[64 + lane];
    float m0 = -1e30f, m1 = -1e30f;
    for (int n = 0; n < nb; ++n) {
        const float* hr = &u.h2s[w4][n << 6];
        int sw2 = (n & 7) << 3;
        float a0 = 0.f, a1 = 0.f, a2 = 0.f, a3 = 0.f;
#pragma unroll
        for (int q = 0; q < 16; ++q) {
            float4 hv = *(const float4*)&hr[((q << 2) ^ sw2)];
            a0 = fmaf(hv.x, w0[(q << 2)], a0);
            a1 = fmaf(hv.y, w0[(q << 2) + 1], a1);
            a0 = fmaf(hv.z, w0[(q << 2) + 2], a0);
            a1 = fmaf(hv.w, w0[(q << 2) + 3], a1);
            a2 = fmaf(hv.x, w1[(q << 2)], a2);
            a3 = fmaf(hv.y, w1[(q << 2) + 1], a3);
            a2 = fmaf(hv.z, w1[(q << 2) + 2], a2);
            a3 = fmaf(hv.w, w1[(q << 2) + 3], a3);
        }
        m0 = fmaxf(m0, b0v + a0 + a1);
        m1 = fmaxf(m1, b1v + a2 + a3);
    }
    x1[(size_t)g * 128 + lane] = m0;
    x1[(size_t)g * 128 + 64 + lane] = m1;
}

// ---------------------------------------------------------------------------
// SA2: radius r=0.4 grouping + PointNetConv(131->128->128->256).
// L3 restructured as conv1 but h2 staged as fp16 pairs (fits 64KB LDS).
// Writes x2 into MLP3's A buffer (row stride 260; cols 256..258 = pos2).
// ---------------------------------------------------------------------------
union U2 {
    struct {
        float4 sp[1024];
        unsigned ck[4][512];
        int ci[4][512];
        int sel[4][64];
        int cnt[4], cnt2[4];
    } p;
    unsigned h2s[4][4096];  // [wave][n*64 + (j ^ ((n&7)<<3))], dword = half2
};

__global__ __launch_bounds__(256, 2) void conv2_kernel(
    const float4* __restrict__ pos1, const float4* __restrict__ pos2,
    const float* __restrict__ x1,
    const float* __restrict__ Wa, const float* __restrict__ Ba,
    const float* __restrict__ Wb, const float* __restrict__ Bb,
    const float* __restrict__ Wc, const float* __restrict__ Bc,
    float* __restrict__ Aout) {
    __shared__ U2 u;
    int cloud = blockIdx.x >> 6;
    int w4 = TID >> 6, lane = TID & 63;
    int cent = ((blockIdx.x & 63) << 2) + w4;
    int g = (cloud << 8) + cent;
    for (int j = TID; j < 1024; j += 256) u.p.sp[j] = pos1[(cloud << 10) + j];
    if (lane == 0) { u.p.cnt[w4] = 0; u.p.cnt2[w4] = 0; }
    __syncthreads();
    float4 cq = pos2[g];
    double cx = cq.x, cy = cq.y, cz = cq.z;
    for (int s = 0; s < 16; ++s) {
        int j = (s << 6) + lane;
        float4 pj = u.p.sp[j];
        double dx = (double)pj.x - cx, dy = (double)pj.y - cy, dz = (double)pj.z - cz;
        double d2 = dx * dx + dy * dy + dz * dz;
        if (d2 <= 0.4 * 0.4) {
            int p = atomicAdd(&u.p.cnt[w4], 1);
            if (p < 512) { u.p.ck[w4][p] = __float_as_uint((float)d2); u.p.ci[w4][p] = j; }
        }
    }
    __syncthreads();
    int c = min(u.p.cnt[w4], 512);
    int nb;
    int idxn = select_k64(u.p.ck[w4], u.p.ci[w4], c, lane, &u.p.cnt2[w4],
                          u.p.sel[w4], &nb);
    float4 pn = u.p.sp[idxn];
    float rx = pn.x - cq.x, ry = pn.y - cq.y, rz = pn.z - cq.z;
    const float4* xr = (const float4*)(x1 + (size_t)((cloud << 10) + idxn) * 128);
    // L1 (131 -> 128, relu) fused with L2 (128 -> 128) in two 64-channel halves.
    float h2[128];
#pragma unroll
    for (int cc2 = 0; cc2 < 128; ++cc2) h2[cc2] = Bb[cc2];
#pragma unroll
    for (int half = 0; half < 2; ++half) {
        float h1[64];
#pragma unroll
        for (int cc2 = 0; cc2 < 64; ++cc2) h1[cc2] = Ba[(half << 6) + cc2];
        for (int ic = 0; ic < 32; ++ic) {
            float4 xv = xr[ic];
            const float* wr = Wa + (ic * 4) * 128 + (half << 6);
#pragma unroll
            for (int ii = 0; ii < 4; ++ii) {
                float xs = (&xv.x)[ii];
#pragma unroll
                for (int cc2 = 0; cc2 < 64; ++cc2)
                    h1[cc2] = fmaf(xs, wr[ii * 128 + cc2], h1[cc2]);
            }
        }
#pragma unroll
        for (int cc2 = 0; cc2 < 64; ++cc2) {
            float v = fmaf(rx, Wa[128 * 128 + (half << 6) + cc2],
                    fmaf(ry, Wa[129 * 128 + (half << 6) + cc2],
                    fmaf(rz, Wa[130 * 128 + (half << 6) + cc2], h1[cc2])));
            h1[cc2] = fmaxf(v, 0.f);
        }
#pragma unroll
        for (int i = 0; i < 64; ++i) {
            float hv = h1[i];
            const float* wr = Wb + ((half << 6) + i) * 128;
#pragma unroll
            for (int cc2 = 0; cc2 < 128; ++cc2) h2[cc2] = fmaf(hv, wr[cc2], h2[cc2]);
        }
    }
#pragma unroll
    for (int cc2 = 0; cc2 < 128; ++cc2) h2[cc2] = fmaxf(h2[cc2], 0.f);
    // --- stage h2 as fp16 pairs into LDS, lane = neighbor slot, XOR swizzle ---
    __syncthreads();   // all waves done with grouping buffers / sp
    {
        unsigned* hrow = &u.h2s[w4][lane << 6];
        int sw = (lane & 7) << 3;
#pragma unroll
        for (int q = 0; q < 16; ++q) {
            unsigned tmp[4];
#pragma unroll
            for (int k2 = 0; k2 < 4; ++k2) {
                int j = (q << 2) + k2;
                __half2 hh = __floats2half2_rn(h2[2 * j], h2[2 * j + 1]);
                __builtin_memcpy(&tmp[k2], &hh, 4);
            }
            uint4 pk = make_uint4(tmp[0], tmp[1], tmp[2], tmp[3]);
            *(uint4*)&hrow[(q << 2) ^ sw] = pk;
        }
    }
    // --- L3: lane = output channel, 4 passes of 64 channels, max over n ---
    float* arow = Aout + (size_t)g * 260;
#pragma unroll 1
    for (int ch = 0; ch < 4; ++ch) {
        int cc = (ch << 6) + lane;
        float w[128];
#pragma unroll
        for (int i = 0; i < 128; ++i) w[i] = Wc[i * 256 + cc];
        float bb = Bc[cc];
        float m = -1e30f;
        for (int n = 0; n < nb; ++n) {
            const unsigned* hr = &u.h2s[w4][n << 6];
            int sw2 = (n & 7) << 3;
            float a0 = 0.f, a1 = 0.f, a2 = 0.f, a3 = 0.f;
#pragma unroll
            for (int q = 0; q < 16; ++q) {
                uint4 hv = *(const uint4*)&hr[((q << 2) ^ sw2)];
                int jb = (q << 3);  // h2 element base = 2 * 4q
                __half2 p0, p1, p2, p3;
                __builtin_memcpy(&p0, &hv.x, 4);
                __builtin_memcpy(&p1, &hv.y, 4);
                __builtin_memcpy(&p2, &hv.z, 4);
                __builtin_memcpy(&p3, &hv.w, 4);
                a0 = fmaf(__low2float(p0),  w[jb + 0], a0);
                a1 = fmaf(__high2float(p0), w[jb + 1], a1);
                a2 = fmaf(__low2float(p1),  w[jb + 2], a2);
                a3 = fmaf(__high2float(p1), w[jb + 3], a3);
                a0 = fmaf(__low2float(p2),  w[jb + 4], a0);
                a1 = fmaf(__high2float(p2), w[jb + 5], a1);
                a2 = fmaf(__low2float(p3),  w[jb + 6], a2);
                a3 = fmaf(__high2float(p3), w[jb + 7], a3);
            }
            m = fmaxf(m, bb + (a0 + a1) + (a2 + a3));
        }
        arow[cc] = m;
    }
}

// ---------------------------------------------------------------------------
// fp32 tiled GEMM: C[M,N] = A[M,K] @ B[K,N] + bias (+relu). 64x64 tiles.
// ---------------------------------------------------------------------------
__global__ __launch_bounds__(256, 2) void gemm_bias(
    const float* __restrict__ A, int lda, const float* __restrict__ Bw, int ldb,
    const float* __restrict__ bias, float* __restrict__ C, int ldc,
    int M, int N, int K, int relu) {
    __shared__ float As[16][68];
    __shared__ float Bs[16][68];
    int nbx = N >> 6;
    int bx = blockIdx.x % nbx, by = blockIdx.x / nbx;
    int tx = TID & 15, ty = TID >> 4;
    int r0 = by << 6, c0 = bx << 6;
    float acc[4][4];
#pragma unroll
    for (int i = 0; i < 4; ++i)
#pragma unroll
        for (int j = 0; j < 4; ++j) acc[i][j] = 0.f;
    int lr = TID >> 2, lk = (TID & 3) << 2;
    int ln = TID & 63, lk2 = TID >> 6;
    for (int k0 = 0; k0 < K; k0 += 16) {
#pragma unroll
        for (int u = 0; u < 4; ++u) {
            int kk = k0 + lk + u;
            As[lk + u][lr] = (kk < K) ? A[(size_t)(r0 + lr) * lda + kk] : 0.f;
        }
#pragma unroll
        for (int u = 0; u < 4; ++u) {
            int krow = lk2 + (u << 2);
            int kk = k0 + krow;
            Bs[krow][ln] = (kk < K) ? Bw[(size_t)kk * ldb + c0 + ln] : 0.f;
        }
        __syncthreads();
#pragma unroll
        for (int kk = 0; kk < 16; ++kk) {
            float av[4], bv[4];
#pragma unroll
            for (int i = 0; i < 4; ++i) av[i] = As[kk][(ty << 2) + i];
#pragma unroll
            for (int j = 0; j < 4; ++j) bv[j] = Bs[kk][(tx << 2) + j];
#pragma unroll
            for (int i = 0; i < 4; ++i)
#pragma unroll
                for (int j = 0; j < 4; ++j) acc[i][j] = fmaf(av[i], bv[j], acc[i][j]);
        }
        __syncthreads();
    }
#pragma unroll
    for (int i = 0; i < 4; ++i) {
        int row = r0 + (ty << 2) + i;
#pragma unroll
        for (int j = 0; j < 4; ++j) {
            int col = c0 + (tx << 2) + j;
            float v = acc[i][j] + bias[col];
            if (relu) v = fmaxf(v, 0.f);
            C[(size_t)row * ldc + col] = v;
        }
    }
}

// ---------------------------------------------------------------------------
// Per-cloud max over 256 rows of h3 -> gfeat[8][1024]
// ---------------------------------------------------------------------------
__global__ __launch_bounds__(256) void rowmax_kernel(const float* __restrict__ h3,
                                                     float* __restrict__ gfeat) {
    int cloud = blockIdx.x;
    for (int cc = TID; cc < 1024; cc += 256) {
        float m = -3.0e38f;
        for (int r = 0; r < 256; ++r)
            m = fmaxf(m, h3[(size_t)((cloud << 8) + r) * 1024 + cc]);
        gfeat[(cloud << 10) + cc] = m;
    }
}

// ---------------------------------------------------------------------------
// Head MLP 1024->512->256->10 + log_softmax (one block per cloud)
// ---------------------------------------------------------------------------
__global__ __launch_bounds__(256) void head_kernel(
    const float* __restrict__ gfeat,
    const float* __restrict__ Wh1, const float* __restrict__ bh1,
    const float* __restrict__ Wh2, const float* __restrict__ bh2,
    const float* __restrict__ Wh3, const float* __restrict__ bh3,
    float* __restrict__ out) {
    __shared__ float gg[1024];
    __shared__ float s1[512];
    __shared__ float s2[256];
    __shared__ float lg[10];
    int cloud = blockIdx.x;
    for (int i = TID; i < 1024; i += 256) gg[i] = gfeat[(cloud << 10) + i];
    __syncthreads();
    for (int cc = TID; cc < 512; cc += 256) {
        float v = bh1[cc];
        for (int i = 0; i < 1024; ++i) v = fmaf(gg[i], Wh1[i * 512 + cc], v);
        s1[cc] = fmaxf(v, 0.f);
    }
    __syncthreads();
    for (int cc = TID; cc < 256; cc += 256) {
        float v = bh2[cc];
        for (int i = 0; i < 512; ++i) v = fmaf(s1[i], Wh2[i * 256 + cc], v);
        s2[cc] = fmaxf(v, 0.f);
    }
    __syncthreads();
    if (TID < 10) {
        float v = bh3[TID];
        for (int i = 0; i < 256; ++i) v = fmaf(s2[i], Wh3[i * 10 + TID], v);
        lg[TID] = v;
    }
    __syncthreads();
    if (TID == 0) {
        float mx = lg[0];
        for (int i = 1; i < 10; ++i) mx = fmaxf(mx, lg[i]);
        float s = 0.f;
        for (int i = 0; i < 10; ++i) s += expf(lg[i] - mx);
        float lse = mx + logf(s);
        for (int i = 0; i < 10; ++i) out[cloud * 10 + i] = lg[i] - lse;
    }
}

// ---------------------------------------------------------------------------
// Launch. Workspace layout (12.5 MB total; regions reused across phases).
// ---------------------------------------------------------------------------
extern "C" void kernel_launch(void* const* d_in, const int* in_sizes, int n_in,
                              void* d_out, int out_size, void* d_ws, size_t ws_size,
                              hipStream_t stream) {
    (void)in_sizes; (void)n_in; (void)out_size; (void)ws_size;
    const float* pos = (const float*)d_in[0];
    const float* W1a = (const float*)d_in[1];  const float* b1a = (const float*)d_in[2];
    const float* W1b = (const float*)d_in[3];  const float* b1b = (const float*)d_in[4];
    const float* W1c = (const float*)d_in[5];  const float* b1c = (const float*)d_in[6];
    const float* W2a = (const float*)d_in[7];  const float* b2a = (const float*)d_in[8];
    const float* W2b = (const float*)d_in[9];  const float* b2b = (const float*)d_in[10];
    const float* W2c = (const float*)d_in[11]; const float* b2c = (const float*)d_in[12];
    const float* W3a = (const float*)d_in[13]; const float* b3a = (const float*)d_in[14];
    const float* W3b = (const float*)d_in[15]; const float* b3b = (const float*)d_in[16];
    const float* W3c = (const float*)d_in[17]; const float* b3c = (const float*)d_in[18];
    const float* Wh1 = (const float*)d_in[19]; const float* bh1 = (const float*)d_in[20];
    const float* Wh2 = (const float*)d_in[21]; const float* bh2 = (const float*)d_in[22];
    const float* Wh3 = (const float*)d_in[23]; const float* bh3 = (const float*)d_in[24];

    char* ws = (char*)d_ws;
    float*  curv  = (float*)(ws + 0);
    int*    idx1  = (int*)(ws + 65536);
    float4* pos1  = (float4*)(ws + 98304);
    float*  curv1 = (float*)(ws + 229376);
    int*    idx2  = (int*)(ws + 262144);
    float4* pos2  = (float4*)(ws + 270336);
    float*  gfeat = (float*)(ws + 303104);
    float*  x1    = (float*)(ws + 524288);
    float*  Abuf  = (float*)(ws + 4718592);
    float*  h1g   = (float*)(ws + 6848512);
    float*  h2g   = x1;     // x1 dead after conv2
    float*  h3g   = Abuf;   // A + h1g dead after gemm2

    curv_kernel<<<64, 256, 0, stream>>>(pos, curv);
    fps_kernel<2048, 1024, 8><<<8, 256, 0, stream>>>(pos, 3, curv, idx1, pos1, curv1,
                                                     nullptr, 0);
    fps_kernel<1024, 256, 4><<<8, 256, 0, stream>>>((const float*)pos1, 4, curv1, idx2,
                                                    pos2, nullptr, Abuf, 260);
    conv1_kernel<<<2048, 256, 0, stream>>>(pos, pos1, W1a, b1a, W1b, b1b, W1c, b1c, x1);
    conv2_kernel<<<512, 256, 0, stream>>>(pos1, pos2, x1, W2a, b2a, W2b, b2b, W2c, b2c,
                                          Abuf);
    gemm_bias<<<128, 256, 0, stream>>>(Abuf, 260, W3a, 256, b3a, h1g, 256,
                                       2048, 256, 259, 1);
    gemm_bias<<<256, 256, 0, stream>>>(h1g, 256, W3b, 512, b3b, h2g, 512,
                                       2048, 512, 256, 1);
    gemm_bias<<<512, 256, 0, stream>>>(h2g, 512, W3c, 1024, b3c, h3g, 1024,
                                       2048, 1024, 512, 0);
    rowmax_kernel<<<8, 256, 0, stream>>>(h3g, gfeat);
    head_kernel<<<8, 256, 0, stream>>>(gfeat, Wh1, bh1, Wh2, bh2, Wh3, bh3,
                                       (float*)d_out);
}

// Round 3
// 2709.026 us; speedup vs baseline: 1.9682x; 1.1310x over previous
//
#include <hip/hip_runtime.h>
#include <hip/hip_fp16.h>
#include <math.h>

#define TID threadIdx.x

static __device__ __forceinline__ int wave_sum(int v) {
#pragma unroll
    for (int o = 32; o >= 1; o >>= 1) v += __shfl_xor(v, o, 64);
    return v;
}

// ---------------------------------------------------------------------------
// Curvature: per-point 10-NN covariance, lambda_min / sum(lambda)
// ---------------------------------------------------------------------------
__global__ __launch_bounds__(256) void curv_kernel(const float* __restrict__ pos,
                                                   float* __restrict__ curv) {
    __shared__ float4 sp[2048];
    int cloud = blockIdx.x >> 3;
    int base = cloud << 11;
    for (int j = TID; j < 2048; j += 256) {
        const float* p = pos + (size_t)(base + j) * 3;
        float x = p[0], y = p[1], z = p[2];
        sp[j] = make_float4(x, y, z, fmaf(x, x, fmaf(y, y, z * z)));
    }
    __syncthreads();
    int li = ((blockIdx.x & 7) << 8) + TID;
    float4 pi = sp[li];
    float bd[10];
    int bi[10];
#pragma unroll
    for (int t = 0; t < 10; ++t) { bd[t] = 3.0e38f; bi[t] = 0; }
    for (int j = 0; j < 2048; ++j) {
        float4 pj = sp[j];
        float dot = fmaf(pi.x, pj.x, fmaf(pi.y, pj.y, pi.z * pj.z));
        float d2 = pi.w + pj.w - 2.0f * dot;   // same form as reference _sqdist
        if (d2 < bd[9]) {
            bd[9] = d2; bi[9] = j;
#pragma unroll
            for (int t = 9; t > 0; --t) {
                if (bd[t] < bd[t - 1]) {
                    float td = bd[t]; bd[t] = bd[t - 1]; bd[t - 1] = td;
                    int ti = bi[t]; bi[t] = bi[t - 1]; bi[t - 1] = ti;
                }
            }
        }
    }
    double sx = 0, sy = 0, sz = 0;
#pragma unroll
    for (int t = 0; t < 10; ++t) { float4 p = sp[bi[t]]; sx += p.x; sy += p.y; sz += p.z; }
    double mx = sx / 10.0, my = sy / 10.0, mz = sz / 10.0;
    double cxx = 0, cxy = 0, cxz = 0, cyy = 0, cyz = 0, czz = 0;
#pragma unroll
    for (int t = 0; t < 10; ++t) {
        float4 p = sp[bi[t]];
        double dx = p.x - mx, dy = p.y - my, dz = p.z - mz;
        cxx += dx * dx; cxy += dx * dy; cxz += dx * dz;
        cyy += dy * dy; cyz += dy * dz; czz += dz * dz;
    }
    cxx /= 10.0; cxy /= 10.0; cxz /= 10.0; cyy /= 10.0; cyz /= 10.0; czz /= 10.0;
    double q = (cxx + cyy + czz) / 3.0;
    double b00 = cxx - q, b11 = cyy - q, b22 = czz - q;
    double p2 = b00 * b00 + b11 * b11 + b22 * b22 +
                2.0 * (cxy * cxy + cxz * cxz + cyz * cyz);
    double lmin;
    if (p2 <= 0.0) {
        lmin = q;
    } else {
        double p = sqrt(p2 / 6.0);
        double inv = 1.0 / p;
        double c00 = b00 * inv, c01 = cxy * inv, c02 = cxz * inv;
        double c11 = b11 * inv, c12 = cyz * inv, c22 = b22 * inv;
        double detB = c00 * (c11 * c22 - c12 * c12)
                    - c01 * (c01 * c22 - c12 * c02)
                    + c02 * (c01 * c12 - c11 * c02);
        double r = 0.5 * detB;
        r = fmin(1.0, fmax(-1.0, r));
        double phi = acos(r) / 3.0;
        lmin = q + 2.0 * p * cos(phi + 2.0943951023931953);  // smallest eigenvalue
    }
    double s3 = cxx + cyy + czz;
    curv[base + li] = (float)(lmin / (s3 + 1e-8));
}

// ---------------------------------------------------------------------------
// Weighted FPS body. One barrier/iter: all 256 threads post (score,idx) to a
// parity-double-buffered record array; after the barrier every thread folds 4
// stride-64 records and all waves run the butterfly redundantly -> all threads
// agree on the winner with no 2nd reduction/barrier. Winner coords via one
// uniform LDS read (off the old 2-barrier critical path).
// ---------------------------------------------------------------------------
template <int N, int M, int SLOTS>
static __device__ void fps_body(
    const float* __restrict__ srcpos, int stride, const float* __restrict__ srccurv,
    int cloud, float4* __restrict__ outPos, float* __restrict__ outCurv,
    float* __restrict__ outA, int ldA,
    float4* sp, int* sidx, float2* rec) {
    const float* cp = srcpos + (size_t)cloud * N * stride;
    for (int j = TID; j < N; j += 256)
        sp[j] = make_float4(cp[j * stride], cp[j * stride + 1], cp[j * stride + 2], 0.f);
    if (TID == 0) sidx[0] = 0;
    __syncthreads();
    float md[SLOTS], wv[SLOTS], px[SLOTS], py[SLOTS], pz[SLOTS];
#pragma unroll
    for (int s = 0; s < SLOTS; ++s) {
        int p = (s << 8) + TID;
        float4 q = sp[p];
        px[s] = q.x; py[s] = q.y; pz[s] = q.z;
        md[s] = 3.0e38f;
        wv[s] = fmaf(10.0f, srccurv[cloud * N + p], 1.0f);
    }
    int lane = TID & 63;
    float4 c0 = sp[0];
    float cx = c0.x, cy = c0.y, cz = c0.z;
    for (int t = 1; t < M; ++t) {
        float best = -1.0f;
        int bix = 0;
#pragma unroll
        for (int s = 0; s < SLOTS; ++s) {
            float dx = px[s] - cx, dy = py[s] - cy, dz = pz[s] - cz;
            float nd = fmaf(dx, dx, fmaf(dy, dy, dz * dz));
            float m2 = fminf(md[s], nd);
            md[s] = m2;
            float sc = m2 * wv[s];
            bool g = sc > best;           // strict > keeps earliest (lowest idx)
            best = g ? sc : best;
            bix = g ? ((s << 8) + TID) : bix;
        }
        float2* rb = rec + ((t & 1) << 8);
        rb[TID] = make_float2(best, __int_as_float(bix));
        __syncthreads();
        float2 r0 = rb[lane];
        float2 r1 = rb[lane + 64];
        float2 r2 = rb[lane + 128];
        float2 r3 = rb[lane + 192];
#define FPS_FOLD(r) { float os = (r).x; int oi = __float_as_int((r).y); \
        if (os > best || (os == best && oi < bix)) { best = os; bix = oi; } }
        FPS_FOLD(r0) FPS_FOLD(r1) FPS_FOLD(r2) FPS_FOLD(r3)
#undef FPS_FOLD
#pragma unroll
        for (int o = 32; o >= 1; o >>= 1) {
            float ob = __shfl_xor(best, o, 64);
            int oi = __shfl_xor(bix, o, 64);
            if (ob > best || (ob == best && oi < bix)) { best = ob; bix = oi; }
        }
        if (TID == 0) sidx[t] = bix;
        float4 cc = sp[bix];   // uniform (broadcast) read
        cx = cc.x; cy = cc.y; cz = cc.z;
    }
    __syncthreads();
    for (int j = TID; j < M; j += 256) {
        int id = sidx[j];
        float4 qv = sp[id];
        outPos[cloud * M + j] = qv;
        if (outCurv) outCurv[cloud * M + j] = srccurv[cloud * N + id];
        if (outA) {
            float* a = outA + (size_t)(cloud * M + j) * ldA;
            a[256] = qv.x; a[257] = qv.y; a[258] = qv.z;
        }
    }
}

// Standalone fps1 (2048 -> 1024): sp 32KB + rec 4KB + sidx 4KB = 40KB LDS
__global__ __launch_bounds__(256, 1) void fps1_kernel(
    const float* __restrict__ pos, const float* __restrict__ curv,
    float4* __restrict__ pos1, float* __restrict__ curv1) {
    __shared__ float4 sp[2048];
    __shared__ int sidx[1024];
    __shared__ float2 rec[512];
    fps_body<2048, 1024, 8>(pos, 3, curv, blockIdx.x, pos1, curv1, nullptr, 0,
                            sp, sidx, rec);
}

// ---------------------------------------------------------------------------
// Exact top-64 (smallest d2, idx tie-break) selection within one wave.
// ---------------------------------------------------------------------------
static __device__ __forceinline__ int select_k64(const unsigned int* ck, const int* ci,
                                                 int c, int lane, int* cnt2, int* sel,
                                                 int* nbOut) {
    if (c <= 64) {
        *nbOut = c;
        return (lane < c) ? ci[lane] : 0;
    }
    unsigned int T = 0;  // becomes the 64th-smallest key
    for (int bit = 31; bit >= 0; --bit) {
        unsigned int mid = T | (1u << bit);
        int cl = 0;
        for (int q = lane; q < c; q += 64) cl += (ck[q] < mid) ? 1 : 0;
        if (wave_sum(cl) < 64) T = mid;
    }
    int cl = 0;
    for (int q = lane; q < c; q += 64) cl += (ck[q] < T) ? 1 : 0;
    int need = 64 - wave_sum(cl);
    int TI = 0;  // becomes the need-th smallest idx among keys == T
    for (int bit = 11; bit >= 0; --bit) {
        int mid = TI | (1 << bit);
        int ce = 0;
        for (int q = lane; q < c; q += 64) ce += (ck[q] == T && ci[q] < mid) ? 1 : 0;
        if (wave_sum(ce) < need) TI = mid;
    }
    for (int q = lane; q < c; q += 64) {
        unsigned int kq = ck[q];
        int iq = ci[q];
        if (kq < T || (kq == T && iq <= TI)) sel[atomicAdd(cnt2, 1)] = iq;
    }
    *nbOut = 64;
    return sel[lane];
}

// ---------------------------------------------------------------------------
// SA1 conv body (3->64->64->128) — as round 2 (h2 LDS-staged, lane=channel L3)
// ---------------------------------------------------------------------------
union U1 {
    struct {
        float4 sp[2048];
        unsigned ck[4][256];
        int ci[4][256];
        int sel[4][64];
        int cnt[4], cnt2[4];
    } p;
    float h2s[4][4096];   // [wave][n*64 + (j ^ ((n&7)<<3))]
};

static __device__ void conv1_body(
    int bid, U1& u,
    const float* __restrict__ pos, const float4* __restrict__ pos1,
    const float* __restrict__ W1, const float* __restrict__ B1,
    const float* __restrict__ W2, const float* __restrict__ B2,
    const float* __restrict__ W3, const float* __restrict__ B3,
    float* __restrict__ x1) {
    int cloud = bid >> 8;
    int w4 = TID >> 6, lane = TID & 63;
    int cent = ((bid & 255) << 2) + w4;
    int g = (cloud << 10) + cent;
    int base = cloud << 11;
    for (int j = TID; j < 2048; j += 256) {
        const float* p = pos + (size_t)(base + j) * 3;
        u.p.sp[j] = make_float4(p[0], p[1], p[2], 0.f);
    }
    if (lane == 0) { u.p.cnt[w4] = 0; u.p.cnt2[w4] = 0; }
    __syncthreads();
    float4 cq = pos1[g];
    double cx = cq.x, cy = cq.y, cz = cq.z;
    for (int s = 0; s < 32; ++s) {
        int j = (s << 6) + lane;
        float4 pj = u.p.sp[j];
        double dx = (double)pj.x - cx, dy = (double)pj.y - cy, dz = (double)pj.z - cz;
        double d2 = dx * dx + dy * dy + dz * dz;
        if (d2 <= 0.2 * 0.2) {
            int p = atomicAdd(&u.p.cnt[w4], 1);
            if (p < 256) { u.p.ck[w4][p] = __float_as_uint((float)d2); u.p.ci[w4][p] = j; }
        }
    }
    __syncthreads();
    int c = min(u.p.cnt[w4], 256);
    int nb;
    int idxn = select_k64(u.p.ck[w4], u.p.ci[w4], c, lane, &u.p.cnt2[w4],
                          u.p.sel[w4], &nb);
    float4 pn = u.p.sp[idxn];
    float rx = pn.x - cq.x, ry = pn.y - cq.y, rz = pn.z - cq.z;
    float h1[64];
#pragma unroll
    for (int cc2 = 0; cc2 < 64; ++cc2) {
        float v = fmaf(rx, W1[cc2], fmaf(ry, W1[64 + cc2], fmaf(rz, W1[128 + cc2], B1[cc2])));
        h1[cc2] = fmaxf(v, 0.f);
    }
    float h2[64];
#pragma unroll
    for (int cc2 = 0; cc2 < 64; ++cc2) h2[cc2] = B2[cc2];
#pragma unroll
    for (int i = 0; i < 64; ++i) {
        float hv = h1[i];
        const float* wr = W2 + i * 64;
#pragma unroll
        for (int cc2 = 0; cc2 < 64; ++cc2) h2[cc2] = fmaf(hv, wr[cc2], h2[cc2]);
    }
#pragma unroll
    for (int cc2 = 0; cc2 < 64; ++cc2) h2[cc2] = fmaxf(h2[cc2], 0.f);
    __syncthreads();   // all waves done with grouping buffers / sp
    {
        float* hrow = &u.h2s[w4][lane << 6];
        int sw = (lane & 7) << 3;
#pragma unroll
        for (int q = 0; q < 16; ++q) {
            int jp = (q << 2) ^ sw;
            *(float4*)&hrow[jp] =
                make_float4(h2[(q << 2)], h2[(q << 2) + 1], h2[(q << 2) + 2], h2[(q << 2) + 3]);
        }
    }
    float w0[64], w1[64];
#pragma unroll
    for (int i = 0; i < 64; ++i) {
        w0[i] = W3[i * 128 + lane];
        w1[i] = W3[i * 128 + 64 + lane];
    }
    float b0v = B3[lane], b1v = B3[64 + lane];
    float m0 = -1e30f, m1 = -1e30f;
    for (int n = 0; n < nb; ++n) {
        const float* hr = &u.h2s[w4][n << 6];
        int sw2 = (n & 7) << 3;
        float a0 = 0.f, a1 = 0.f, a2 = 0.f, a3 = 0.f;
#pragma unroll
        for (int q = 0; q < 16; ++q) {
            float4 hv = *(const float4*)&hr[((q << 2) ^ sw2)];
            a0 = fmaf(hv.x, w0[(q << 2)], a0);
            a1 = fmaf(hv.y, w0[(q << 2) + 1], a1);
            a0 = fmaf(hv.z, w0[(q << 2) + 2], a0);
            a1 = fmaf(hv.w, w0[(q << 2) + 3], a1);
            a2 = fmaf(hv.x, w1[(q << 2)], a2);
            a3 = fmaf(hv.y, w1[(q << 2) + 1], a3);
            a2 = fmaf(hv.z, w1[(q << 2) + 2], a2);
            a3 = fmaf(hv.w, w1[(q << 2) + 3], a3);
        }
        m0 = fmaxf(m0, b0v + a0 + a1);
        m1 = fmaxf(m1, b1v + a2 + a3);
    }
    x1[(size_t)g * 128 + lane] = m0;
    x1[(size_t)g * 128 + 64 + lane] = m1;
}

// ---------------------------------------------------------------------------
// Merged launch: blocks 0-7 run fps2 (1024->256), blocks 8.. run conv1.
// fps2 and conv1 both depend only on fps1 -> independent, overlap in one grid.
// ---------------------------------------------------------------------------
union UM {
    U1 c;
    struct {
        float4 sp[1024];
        float2 rec[512];
        int sidx[256];
    } f;
};

__global__ __launch_bounds__(256, 2) void fps2_conv1_kernel(
    const float* __restrict__ pos, const float4* __restrict__ pos1,
    const float* __restrict__ curv1, float4* __restrict__ pos2,
    float* __restrict__ Abuf,
    const float* __restrict__ W1, const float* __restrict__ B1,
    const float* __restrict__ W2, const float* __restrict__ B2,
    const float* __restrict__ W3, const float* __restrict__ B3,
    float* __restrict__ x1) {
    __shared__ UM u;
    if (blockIdx.x < 8) {
        fps_body<1024, 256, 4>((const float*)pos1, 4, curv1, blockIdx.x, pos2,
                               nullptr, Abuf, 260, u.f.sp, u.f.sidx, u.f.rec);
    } else {
        conv1_body(blockIdx.x - 8, u.c, pos, pos1, W1, B1, W2, B2, W3, B3, x1);
    }
}

// ---------------------------------------------------------------------------
// SA2: radius r=0.4 grouping + PointNetConv(131->128->128->256) — as round 2.
// ---------------------------------------------------------------------------
union U2 {
    struct {
        float4 sp[1024];
        unsigned ck[4][512];
        int ci[4][512];
        int sel[4][64];
        int cnt[4], cnt2[4];
    } p;
    unsigned h2s[4][4096];  // [wave][n*64 + (j ^ ((n&7)<<3))], dword = half2
};

__global__ __launch_bounds__(256, 2) void conv2_kernel(
    const float4* __restrict__ pos1, const float4* __restrict__ pos2,
    const float* __restrict__ x1,
    const float* __restrict__ Wa, const float* __restrict__ Ba,
    const float* __restrict__ Wb, const float* __restrict__ Bb,
    const float* __restrict__ Wc, const float* __restrict__ Bc,
    float* __restrict__ Aout) {
    __shared__ U2 u;
    int cloud = blockIdx.x >> 6;
    int w4 = TID >> 6, lane = TID & 63;
    int cent = ((blockIdx.x & 63) << 2) + w4;
    int g = (cloud << 8) + cent;
    for (int j = TID; j < 1024; j += 256) u.p.sp[j] = pos1[(cloud << 10) + j];
    if (lane == 0) { u.p.cnt[w4] = 0; u.p.cnt2[w4] = 0; }
    __syncthreads();
    float4 cq = pos2[g];
    double cx = cq.x, cy = cq.y, cz = cq.z;
    for (int s = 0; s < 16; ++s) {
        int j = (s << 6) + lane;
        float4 pj = u.p.sp[j];
        double dx = (double)pj.x - cx, dy = (double)pj.y - cy, dz = (double)pj.z - cz;
        double d2 = dx * dx + dy * dy + dz * dz;
        if (d2 <= 0.4 * 0.4) {
            int p = atomicAdd(&u.p.cnt[w4], 1);
            if (p < 512) { u.p.ck[w4][p] = __float_as_uint((float)d2); u.p.ci[w4][p] = j; }
        }
    }
    __syncthreads();
    int c = min(u.p.cnt[w4], 512);
    int nb;
    int idxn = select_k64(u.p.ck[w4], u.p.ci[w4], c, lane, &u.p.cnt2[w4],
                          u.p.sel[w4], &nb);
    float4 pn = u.p.sp[idxn];
    float rx = pn.x - cq.x, ry = pn.y - cq.y, rz = pn.z - cq.z;
    const float4* xr = (const float4*)(x1 + (size_t)((cloud << 10) + idxn) * 128);
    float h2[128];
#pragma unroll
    for (int cc2 = 0; cc2 < 128; ++cc2) h2[cc2] = Bb[cc2];
#pragma unroll
    for (int half = 0; half < 2; ++half) {
        float h1[64];
#pragma unroll
        for (int cc2 = 0; cc2 < 64; ++cc2) h1[cc2] = Ba[(half << 6) + cc2];
        for (int ic = 0; ic < 32; ++ic) {
            float4 xv = xr[ic];
            const float* wr = Wa + (ic * 4) * 128 + (half << 6);
#pragma unroll
            for (int ii = 0; ii < 4; ++ii) {
                float xs = (&xv.x)[ii];
#pragma unroll
                for (int cc2 = 0; cc2 < 64; ++cc2)
                    h1[cc2] = fmaf(xs, wr[ii * 128 + cc2], h1[cc2]);
            }
        }
#pragma unroll
        for (int cc2 = 0; cc2 < 64; ++cc2) {
            float v = fmaf(rx, Wa[128 * 128 + (half << 6) + cc2],
                    fmaf(ry, Wa[129 * 128 + (half << 6) + cc2],
                    fmaf(rz, Wa[130 * 128 + (half << 6) + cc2], h1[cc2])));
            h1[cc2] = fmaxf(v, 0.f);
        }
#pragma unroll
        for (int i = 0; i < 64; ++i) {
            float hv = h1[i];
            const float* wr = Wb + ((half << 6) + i) * 128;
#pragma unroll
            for (int cc2 = 0; cc2 < 128; ++cc2) h2[cc2] = fmaf(hv, wr[cc2], h2[cc2]);
        }
    }
#pragma unroll
    for (int cc2 = 0; cc2 < 128; ++cc2) h2[cc2] = fmaxf(h2[cc2], 0.f);
    __syncthreads();   // all waves done with grouping buffers / sp
    {
        unsigned* hrow = &u.h2s[w4][lane << 6];
        int sw = (lane & 7) << 3;
#pragma unroll
        for (int q = 0; q < 16; ++q) {
            unsigned tmp[4];
#pragma unroll
            for (int k2 = 0; k2 < 4; ++k2) {
                int j = (q << 2) + k2;
                __half2 hh = __floats2half2_rn(h2[2 * j], h2[2 * j + 1]);
                __builtin_memcpy(&tmp[k2], &hh, 4);
            }
            uint4 pk = make_uint4(tmp[0], tmp[1], tmp[2], tmp[3]);
            *(uint4*)&hrow[(q << 2) ^ sw] = pk;
        }
    }
    float* arow = Aout + (size_t)g * 260;
#pragma unroll 1
    for (int ch = 0; ch < 4; ++ch) {
        int cc = (ch << 6) + lane;
        float w[128];
#pragma unroll
        for (int i = 0; i < 128; ++i) w[i] = Wc[i * 256 + cc];
        float bb = Bc[cc];
        float m = -1e30f;
        for (int n = 0; n < nb; ++n) {
            const unsigned* hr = &u.h2s[w4][n << 6];
            int sw2 = (n & 7) << 3;
            float a0 = 0.f, a1 = 0.f, a2 = 0.f, a3 = 0.f;
#pragma unroll
            for (int q = 0; q < 16; ++q) {
                uint4 hv = *(const uint4*)&hr[((q << 2) ^ sw2)];
                int jb = (q << 3);
                __half2 p0, p1, p2, p3;
                __builtin_memcpy(&p0, &hv.x, 4);
                __builtin_memcpy(&p1, &hv.y, 4);
                __builtin_memcpy(&p2, &hv.z, 4);
                __builtin_memcpy(&p3, &hv.w, 4);
                a0 = fmaf(__low2float(p0),  w[jb + 0], a0);
                a1 = fmaf(__high2float(p0), w[jb + 1], a1);
                a2 = fmaf(__low2float(p1),  w[jb + 2], a2);
                a3 = fmaf(__high2float(p1), w[jb + 3], a3);
                a0 = fmaf(__low2float(p2),  w[jb + 4], a0);
                a1 = fmaf(__high2float(p2), w[jb + 5], a1);
                a2 = fmaf(__low2float(p3),  w[jb + 6], a2);
                a3 = fmaf(__high2float(p3), w[jb + 7], a3);
            }
            m = fmaxf(m, bb + (a0 + a1) + (a2 + a3));
        }
        arow[cc] = m;
    }
}

// ---------------------------------------------------------------------------
// fp32 tiled GEMM: C[M,N] = A[M,K] @ B[K,N] + bias (+relu). 64x64 tiles.
// ---------------------------------------------------------------------------
__global__ __launch_bounds__(256, 2) void gemm_bias(
    const float* __restrict__ A, int lda, const float* __restrict__ Bw, int ldb,
    const float* __restrict__ bias, float* __restrict__ C, int ldc,
    int M, int N, int K, int relu) {
    __shared__ float As[16][68];
    __shared__ float Bs[16][68];
    int nbx = N >> 6;
    int bx = blockIdx.x % nbx, by = blockIdx.x / nbx;
    int tx = TID & 15, ty = TID >> 4;
    int r0 = by << 6, c0 = bx << 6;
    float acc[4][4];
#pragma unroll
    for (int i = 0; i < 4; ++i)
#pragma unroll
        for (int j = 0; j < 4; ++j) acc[i][j] = 0.f;
    int lr = TID >> 2, lk = (TID & 3) << 2;
    int ln = TID & 63, lk2 = TID >> 6;
    for (int k0 = 0; k0 < K; k0 += 16) {
#pragma unroll
        for (int u = 0; u < 4; ++u) {
            int kk = k0 + lk + u;
            As[lk + u][lr] = (kk < K) ? A[(size_t)(r0 + lr) * lda + kk] : 0.f;
        }
#pragma unroll
        for (int u = 0; u < 4; ++u) {
            int krow = lk2 + (u << 2);
            int kk = k0 + krow;
            Bs[krow][ln] = (kk < K) ? Bw[(size_t)kk * ldb + c0 + ln] : 0.f;
        }
        __syncthreads();
#pragma unroll
        for (int kk = 0; kk < 16; ++kk) {
            float av[4], bv[4];
#pragma unroll
            for (int i = 0; i < 4; ++i) av[i] = As[kk][(ty << 2) + i];
#pragma unroll
            for (int j = 0; j < 4; ++j) bv[j] = Bs[kk][(tx << 2) + j];
#pragma unroll
            for (int i = 0; i < 4; ++i)
#pragma unroll
                for (int j = 0; j < 4; ++j) acc[i][j] = fmaf(av[i], bv[j], acc[i][j]);
        }
        __syncthreads();
    }
#pragma unroll
    for (int i = 0; i < 4; ++i) {
        int row = r0 + (ty << 2) + i;
#pragma unroll
        for (int j = 0; j < 4; ++j) {
            int col = c0 + (tx << 2) + j;
            float v = acc[i][j] + bias[col];
            if (relu) v = fmaxf(v, 0.f);
            C[(size_t)row * ldc + col] = v;
        }
    }
}

// ---------------------------------------------------------------------------
// Per-cloud max over 256 rows of h3 -> gfeat[8][1024]. 64 blocks (8/cloud).
// ---------------------------------------------------------------------------
__global__ __launch_bounds__(256) void rowmax_kernel(const float* __restrict__ h3,
                                                     float* __restrict__ gfeat) {
    __shared__ float pm[256];
    int cloud = blockIdx.x >> 3;
    int seg = blockIdx.x & 7;
    int col = (seg << 7) + (TID & 127);
    int half = TID >> 7;
    float m = -3.0e38f;
    for (int r = half << 7; r < (half << 7) + 128; ++r)
        m = fmaxf(m, h3[(size_t)((cloud << 8) + r) * 1024 + col]);
    pm[TID] = m;
    __syncthreads();
    if (TID < 128) gfeat[(cloud << 10) + col] = fmaxf(pm[TID], pm[TID + 128]);
}

// ---------------------------------------------------------------------------
// Head MLP 1024->512->256->10 + log_softmax (one block per cloud)
// ---------------------------------------------------------------------------
__global__ __launch_bounds__(256) void head_kernel(
    const float* __restrict__ gfeat,
    const float* __restrict__ Wh1, const float* __restrict__ bh1,
    const float* __restrict__ Wh2, const float* __restrict__ bh2,
    const float* __restrict__ Wh3, const float* __restrict__ bh3,
    float* __restrict__ out) {
    __shared__ float gg[1024];
    __shared__ float s1[512];
    __shared__ float s2[256];
    __shared__ float lg[10];
    int cloud = blockIdx.x;
    for (int i = TID; i < 1024; i += 256) gg[i] = gfeat[(cloud << 10) + i];
    __syncthreads();
    for (int cc = TID; cc < 512; cc += 256) {
        float v = bh1[cc];
        for (int i = 0; i < 1024; ++i) v = fmaf(gg[i], Wh1[i * 512 + cc], v);
        s1[cc] = fmaxf(v, 0.f);
    }
    __syncthreads();
    for (int cc = TID; cc < 256; cc += 256) {
        float v = bh2[cc];
        for (int i = 0; i < 512; ++i) v = fmaf(s1[i], Wh2[i * 256 + cc], v);
        s2[cc] = fmaxf(v, 0.f);
    }
    __syncthreads();
    if (TID < 10) {
        float v = bh3[TID];
        for (int i = 0; i < 256; ++i) v = fmaf(s2[i], Wh3[i * 10 + TID], v);
        lg[TID] = v;
    }
    __syncthreads();
    if (TID == 0) {
        float mx = lg[0];
        for (int i = 1; i < 10; ++i) mx = fmaxf(mx, lg[i]);
        float s = 0.f;
        for (int i = 0; i < 10; ++i) s += expf(lg[i] - mx);
        float lse = mx + logf(s);
        for (int i = 0; i < 10; ++i) out[cloud * 10 + i] = lg[i] - lse;
    }
}

// ---------------------------------------------------------------------------
// Launch. Workspace layout (12.5 MB total; regions reused across phases).
// ---------------------------------------------------------------------------
extern "C" void kernel_launch(void* const* d_in, const int* in_sizes, int n_in,
                              void* d_out, int out_size, void* d_ws, size_t ws_size,
                              hipStream_t stream) {
    (void)in_sizes; (void)n_in; (void)out_size; (void)ws_size;
    const float* pos = (const float*)d_in[0];
    const float* W1a = (const float*)d_in[1];  const float* b1a = (const float*)d_in[2];
    const float* W1b = (const float*)d_in[3];  const float* b1b = (const float*)d_in[4];
    const float* W1c = (const float*)d_in[5];  const float* b1c = (const float*)d_in[6];
    const float* W2a = (const float*)d_in[7];  const float* b2a = (const float*)d_in[8];
    const float* W2b = (const float*)d_in[9];  const float* b2b = (const float*)d_in[10];
    const float* W2c = (const float*)d_in[11]; const float* b2c = (const float*)d_in[12];
    const float* W3a = (const float*)d_in[13]; const float* b3a = (const float*)d_in[14];
    const float* W3b = (const float*)d_in[15]; const float* b3b = (const float*)d_in[16];
    const float* W3c = (const float*)d_in[17]; const float* b3c = (const float*)d_in[18];
    const float* Wh1 = (const float*)d_in[19]; const float* bh1 = (const float*)d_in[20];
    const float* Wh2 = (const float*)d_in[21]; const float* bh2 = (const float*)d_in[22];
    const float* Wh3 = (const float*)d_in[23]; const float* bh3 = (const float*)d_in[24];

    char* ws = (char*)d_ws;
    float*  curv  = (float*)(ws + 0);
    float4* pos1  = (float4*)(ws + 98304);
    float*  curv1 = (float*)(ws + 229376);
    float4* pos2  = (float4*)(ws + 270336);
    float*  gfeat = (float*)(ws + 303104);
    float*  x1    = (float*)(ws + 524288);
    float*  Abuf  = (float*)(ws + 4718592);
    float*  h1g   = (float*)(ws + 6848512);
    float*  h2g   = x1;     // x1 dead after conv2
    float*  h3g   = Abuf;   // A + h1g dead after gemm2

    curv_kernel<<<64, 256, 0, stream>>>(pos, curv);
    fps1_kernel<<<8, 256, 0, stream>>>(pos, curv, pos1, curv1);
    fps2_conv1_kernel<<<2056, 256, 0, stream>>>(pos, pos1, curv1, pos2, Abuf,
                                                W1a, b1a, W1b, b1b, W1c, b1c, x1);
    conv2_kernel<<<512, 256, 0, stream>>>(pos1, pos2, x1, W2a, b2a, W2b, b2b, W2c, b2c,
                                          Abuf);
    gemm_bias<<<128, 256, 0, stream>>>(Abuf, 260, W3a, 256, b3a, h1g, 256,
                                       2048, 256, 259, 1);
    gemm_bias<<<256, 256, 0, stream>>>(h1g, 256, W3b, 512, b3b, h2g, 512,
                                       2048, 512, 256, 1);
    gemm_bias<<<512, 256, 0, stream>>>(h2g, 512, W3c, 1024, b3c, h3g, 1024,
                                       2048, 1024, 512, 0);
    rowmax_kernel<<<64, 256, 0, stream>>>(h3g, gfeat);
    head_kernel<<<8, 256, 0, stream>>>(gfeat, Wh1, bh1, Wh2, bh2, Wh3, bh3,
                                       (float*)d_out);
}

// Round 4
// 2129.941 us; speedup vs baseline: 2.5033x; 1.2719x over previous
//
#include <hip/hip_runtime.h>
#include <hip/hip_fp16.h>
#include <math.h>

#define TID threadIdx.x

static __device__ __forceinline__ int wave_sum(int v) {
#pragma unroll
    for (int o = 32; o >= 1; o >>= 1) v += __shfl_xor(v, o, 64);
    return v;
}

// u64 max with the partner value brought in by a DPP cross-lane move.
// bound_ctrl=true shifts in 0, the identity for max over keys >= 0.
template <int CTRL>
static __device__ __forceinline__ unsigned long long dpp_max_u64(unsigned long long k) {
    int lo = (int)(unsigned)(k & 0xffffffffULL);
    int hi = (int)(unsigned)(k >> 32);
    int lo2 = __builtin_amdgcn_update_dpp(0, lo, CTRL, 0xf, 0xf, true);
    int hi2 = __builtin_amdgcn_update_dpp(0, hi, CTRL, 0xf, 0xf, true);
    unsigned long long k2 = ((unsigned long long)(unsigned)hi2 << 32) | (unsigned)lo2;
    return k2 > k ? k2 : k;
}

// ---------------------------------------------------------------------------
// Curvature: per-point 10-NN covariance, lambda_min / sum(lambda)
// ---------------------------------------------------------------------------
__global__ __launch_bounds__(256) void curv_kernel(const float* __restrict__ pos,
                                                   float* __restrict__ curv) {
    __shared__ float4 sp[2048];
    int cloud = blockIdx.x >> 3;
    int base = cloud << 11;
    for (int j = TID; j < 2048; j += 256) {
        const float* p = pos + (size_t)(base + j) * 3;
        float x = p[0], y = p[1], z = p[2];
        sp[j] = make_float4(x, y, z, fmaf(x, x, fmaf(y, y, z * z)));
    }
    __syncthreads();
    int li = ((blockIdx.x & 7) << 8) + TID;
    float4 pi = sp[li];
    float bd[10];
    int bi[10];
#pragma unroll
    for (int t = 0; t < 10; ++t) { bd[t] = 3.0e38f; bi[t] = 0; }
    for (int j = 0; j < 2048; ++j) {
        float4 pj = sp[j];
        float dot = fmaf(pi.x, pj.x, fmaf(pi.y, pj.y, pi.z * pj.z));
        float d2 = pi.w + pj.w - 2.0f * dot;   // same form as reference _sqdist
        if (d2 < bd[9]) {
            bd[9] = d2; bi[9] = j;
#pragma unroll
            for (int t = 9; t > 0; --t) {
                if (bd[t] < bd[t - 1]) {
                    float td = bd[t]; bd[t] = bd[t - 1]; bd[t - 1] = td;
                    int ti = bi[t]; bi[t] = bi[t - 1]; bi[t - 1] = ti;
                }
            }
        }
    }
    double sx = 0, sy = 0, sz = 0;
#pragma unroll
    for (int t = 0; t < 10; ++t) { float4 p = sp[bi[t]]; sx += p.x; sy += p.y; sz += p.z; }
    double mx = sx / 10.0, my = sy / 10.0, mz = sz / 10.0;
    double cxx = 0, cxy = 0, cxz = 0, cyy = 0, cyz = 0, czz = 0;
#pragma unroll
    for (int t = 0; t < 10; ++t) {
        float4 p = sp[bi[t]];
        double dx = p.x - mx, dy = p.y - my, dz = p.z - mz;
        cxx += dx * dx; cxy += dx * dy; cxz += dx * dz;
        cyy += dy * dy; cyz += dy * dz; czz += dz * dz;
    }
    cxx /= 10.0; cxy /= 10.0; cxz /= 10.0; cyy /= 10.0; cyz /= 10.0; czz /= 10.0;
    double q = (cxx + cyy + czz) / 3.0;
    double b00 = cxx - q, b11 = cyy - q, b22 = czz - q;
    double p2 = b00 * b00 + b11 * b11 + b22 * b22 +
                2.0 * (cxy * cxy + cxz * cxz + cyz * cyz);
    double lmin;
    if (p2 <= 0.0) {
        lmin = q;
    } else {
        double p = sqrt(p2 / 6.0);
        double inv = 1.0 / p;
        double c00 = b00 * inv, c01 = cxy * inv, c02 = cxz * inv;
        double c11 = b11 * inv, c12 = cyz * inv, c22 = b22 * inv;
        double detB = c00 * (c11 * c22 - c12 * c12)
                    - c01 * (c01 * c22 - c12 * c02)
                    + c02 * (c01 * c12 - c11 * c02);
        double r = 0.5 * detB;
        r = fmin(1.0, fmax(-1.0, r));
        double phi = acos(r) / 3.0;
        lmin = q + 2.0 * p * cos(phi + 2.0943951023931953);  // smallest eigenvalue
    }
    double s3 = cxx + cyy + czz;
    curv[base + li] = (float)(lmin / (s3 + 1e-8));
}

// ---------------------------------------------------------------------------
// Weighted FPS body. Per iteration: per-thread 8-slot fold (float ops byte-
// identical to the passing kernel), pack (score_bits<<32)|(2047-idx) into u64,
// post to parity-double-buffered LDS records, one barrier, every thread folds
// 4 stride-64 records and runs a DPP max ladder (VALU-speed cross-lane, not
// ds_swizzle) -> readlane(63) gives the wave-uniform argmax with exact
// lowest-index tie-break. One LDS write + 1 fold read + 1 broadcast read.
// ---------------------------------------------------------------------------
template <int N, int M, int SLOTS>
static __device__ void fps_body(
    const float* __restrict__ srcpos, int stride, const float* __restrict__ srccurv,
    int cloud, float4* __restrict__ outPos, float* __restrict__ outCurv,
    float* __restrict__ outA, int ldA,
    float4* sp, int* sidx, unsigned long long* rec) {
    const float* cp = srcpos + (size_t)cloud * N * stride;
    for (int j = TID; j < N; j += 256)
        sp[j] = make_float4(cp[j * stride], cp[j * stride + 1], cp[j * stride + 2], 0.f);
    if (TID == 0) sidx[0] = 0;
    __syncthreads();
    float md[SLOTS], wv[SLOTS], px[SLOTS], py[SLOTS], pz[SLOTS];
#pragma unroll
    for (int s = 0; s < SLOTS; ++s) {
        int p = (s << 8) + TID;
        float4 q = sp[p];
        px[s] = q.x; py[s] = q.y; pz[s] = q.z;
        md[s] = 3.0e38f;
        wv[s] = fmaf(10.0f, srccurv[cloud * N + p], 1.0f);
    }
    int lane = TID & 63;
    float4 c0 = sp[0];
    float cx = c0.x, cy = c0.y, cz = c0.z;
    for (int t = 1; t < M; ++t) {
        float best = -1.0f;
        int bix = 0;
#pragma unroll
        for (int s = 0; s < SLOTS; ++s) {
            float dx = px[s] - cx, dy = py[s] - cy, dz = pz[s] - cz;
            float nd = fmaf(dx, dx, fmaf(dy, dy, dz * dz));
            float m2 = fminf(md[s], nd);
            md[s] = m2;
            float sc = m2 * wv[s];
            bool g = sc > best;           // strict > keeps earliest (lowest idx)
            best = g ? sc : best;
            bix = g ? ((s << 8) + TID) : bix;
        }
        // score >= 0 always (squared distance * positive weight) -> bits monotone
        unsigned long long key =
            ((unsigned long long)__float_as_uint(best) << 32) | (unsigned)(2047 - bix);
        unsigned long long* rb = rec + ((t & 1) << 8);
        rb[TID] = key;
        __syncthreads();
        unsigned long long k0 = rb[lane];
        unsigned long long k1 = rb[lane + 64];
        unsigned long long k2 = rb[lane + 128];
        unsigned long long k3 = rb[lane + 192];
        unsigned long long ka = k0 > k1 ? k0 : k1;
        unsigned long long kb = k2 > k3 ? k2 : k3;
        unsigned long long k = ka > kb ? ka : kb;
        k = dpp_max_u64<0x111>(k);   // row_shr:1
        k = dpp_max_u64<0x112>(k);   // row_shr:2
        k = dpp_max_u64<0x114>(k);   // row_shr:4
        k = dpp_max_u64<0x118>(k);   // row_shr:8  -> lane15 of each row has row max
        k = dpp_max_u64<0x142>(k);   // row_bcast15 -> lane31/lane63 fold halves
        k = dpp_max_u64<0x143>(k);   // row_bcast31 -> lane63 has global max
        int lo = __builtin_amdgcn_readlane((int)(unsigned)(k & 0xffffffffULL), 63);
        int nbix = 2047 - lo;        // uniform winner index
        if (TID == 0) sidx[t] = nbix;
        float4 cc = sp[nbix];        // uniform (broadcast) read
        cx = cc.x; cy = cc.y; cz = cc.z;
    }
    __syncthreads();
    for (int j = TID; j < M; j += 256) {
        int id = sidx[j];
        float4 qv = sp[id];
        outPos[cloud * M + j] = qv;
        if (outCurv) outCurv[cloud * M + j] = srccurv[cloud * N + id];
        if (outA) {
            float* a = outA + (size_t)(cloud * M + j) * ldA;
            a[256] = qv.x; a[257] = qv.y; a[258] = qv.z;
        }
    }
}

// Standalone fps1 (2048 -> 1024): sp 32KB + rec 4KB + sidx 4KB = 40KB LDS
__global__ __launch_bounds__(256, 1) void fps1_kernel(
    const float* __restrict__ pos, const float* __restrict__ curv,
    float4* __restrict__ pos1, float* __restrict__ curv1) {
    __shared__ float4 sp[2048];
    __shared__ int sidx[1024];
    __shared__ unsigned long long rec[512];
    fps_body<2048, 1024, 8>(pos, 3, curv, blockIdx.x, pos1, curv1, nullptr, 0,
                            sp, sidx, rec);
}

// ---------------------------------------------------------------------------
// Exact top-64 (smallest d2, idx tie-break) selection within one wave.
// ---------------------------------------------------------------------------
static __device__ __forceinline__ int select_k64(const unsigned int* ck, const int* ci,
                                                 int c, int lane, int* cnt2, int* sel,
                                                 int* nbOut) {
    if (c <= 64) {
        *nbOut = c;
        return (lane < c) ? ci[lane] : 0;
    }
    unsigned int T = 0;  // becomes the 64th-smallest key
    for (int bit = 31; bit >= 0; --bit) {
        unsigned int mid = T | (1u << bit);
        int cl = 0;
        for (int q = lane; q < c; q += 64) cl += (ck[q] < mid) ? 1 : 0;
        if (wave_sum(cl) < 64) T = mid;
    }
    int cl = 0;
    for (int q = lane; q < c; q += 64) cl += (ck[q] < T) ? 1 : 0;
    int need = 64 - wave_sum(cl);
    int TI = 0;  // becomes the need-th smallest idx among keys == T
    for (int bit = 11; bit >= 0; --bit) {
        int mid = TI | (1 << bit);
        int ce = 0;
        for (int q = lane; q < c; q += 64) ce += (ck[q] == T && ci[q] < mid) ? 1 : 0;
        if (wave_sum(ce) < need) TI = mid;
    }
    for (int q = lane; q < c; q += 64) {
        unsigned int kq = ck[q];
        int iq = ci[q];
        if (kq < T || (kq == T && iq <= TI)) sel[atomicAdd(cnt2, 1)] = iq;
    }
    *nbOut = 64;
    return sel[lane];
}

// ---------------------------------------------------------------------------
// SA1 conv body (3->64->64->128) — h2 LDS-staged, lane=channel L3
// ---------------------------------------------------------------------------
union U1 {
    struct {
        float4 sp[2048];
        unsigned ck[4][256];
        int ci[4][256];
        int sel[4][64];
        int cnt[4], cnt2[4];
    } p;
    float h2s[4][4096];   // [wave][n*64 + (j ^ ((n&7)<<3))]
};

static __device__ void conv1_body(
    int bid, U1& u,
    const float* __restrict__ pos, const float4* __restrict__ pos1,
    const float* __restrict__ W1, const float* __restrict__ B1,
    const float* __restrict__ W2, const float* __restrict__ B2,
    const float* __restrict__ W3, const float* __restrict__ B3,
    float* __restrict__ x1) {
    int cloud = bid >> 8;
    int w4 = TID >> 6, lane = TID & 63;
    int cent = ((bid & 255) << 2) + w4;
    int g = (cloud << 10) + cent;
    int base = cloud << 11;
    for (int j = TID; j < 2048; j += 256) {
        const float* p = pos + (size_t)(base + j) * 3;
        u.p.sp[j] = make_float4(p[0], p[1], p[2], 0.f);
    }
    if (lane == 0) { u.p.cnt[w4] = 0; u.p.cnt2[w4] = 0; }
    __syncthreads();
    float4 cq = pos1[g];
    double cx = cq.x, cy = cq.y, cz = cq.z;
    for (int s = 0; s < 32; ++s) {
        int j = (s << 6) + lane;
        float4 pj = u.p.sp[j];
        double dx = (double)pj.x - cx, dy = (double)pj.y - cy, dz = (double)pj.z - cz;
        double d2 = dx * dx + dy * dy + dz * dz;
        if (d2 <= 0.2 * 0.2) {
            int p = atomicAdd(&u.p.cnt[w4], 1);
            if (p < 256) { u.p.ck[w4][p] = __float_as_uint((float)d2); u.p.ci[w4][p] = j; }
        }
    }
    __syncthreads();
    int c = min(u.p.cnt[w4], 256);
    int nb;
    int idxn = select_k64(u.p.ck[w4], u.p.ci[w4], c, lane, &u.p.cnt2[w4],
                          u.p.sel[w4], &nb);
    float4 pn = u.p.sp[idxn];
    float rx = pn.x - cq.x, ry = pn.y - cq.y, rz = pn.z - cq.z;
    float h1[64];
#pragma unroll
    for (int cc2 = 0; cc2 < 64; ++cc2) {
        float v = fmaf(rx, W1[cc2], fmaf(ry, W1[64 + cc2], fmaf(rz, W1[128 + cc2], B1[cc2])));
        h1[cc2] = fmaxf(v, 0.f);
    }
    float h2[64];
#pragma unroll
    for (int cc2 = 0; cc2 < 64; ++cc2) h2[cc2] = B2[cc2];
#pragma unroll
    for (int i = 0; i < 64; ++i) {
        float hv = h1[i];
        const float* wr = W2 + i * 64;
#pragma unroll
        for (int cc2 = 0; cc2 < 64; ++cc2) h2[cc2] = fmaf(hv, wr[cc2], h2[cc2]);
    }
#pragma unroll
    for (int cc2 = 0; cc2 < 64; ++cc2) h2[cc2] = fmaxf(h2[cc2], 0.f);
    __syncthreads();   // all waves done with grouping buffers / sp
    {
        float* hrow = &u.h2s[w4][lane << 6];
        int sw = (lane & 7) << 3;
#pragma unroll
        for (int q = 0; q < 16; ++q) {
            int jp = (q << 2) ^ sw;
            *(float4*)&hrow[jp] =
                make_float4(h2[(q << 2)], h2[(q << 2) + 1], h2[(q << 2) + 2], h2[(q << 2) + 3]);
        }
    }
    float w0[64], w1[64];
#pragma unroll
    for (int i = 0; i < 64; ++i) {
        w0[i] = W3[i * 128 + lane];
        w1[i] = W3[i * 128 + 64 + lane];
    }
    float b0v = B3[lane], b1v = B3[64 + lane];
    float m0 = -1e30f, m1 = -1e30f;
    for (int n = 0; n < nb; ++n) {
        const float* hr = &u.h2s[w4][n << 6];
        int sw2 = (n & 7) << 3;
        float a0 = 0.f, a1 = 0.f, a2 = 0.f, a3 = 0.f;
#pragma unroll
        for (int q = 0; q < 16; ++q) {
            float4 hv = *(const float4*)&hr[((q << 2) ^ sw2)];
            a0 = fmaf(hv.x, w0[(q << 2)], a0);
            a1 = fmaf(hv.y, w0[(q << 2) + 1], a1);
            a0 = fmaf(hv.z, w0[(q << 2) + 2], a0);
            a1 = fmaf(hv.w, w0[(q << 2) + 3], a1);
            a2 = fmaf(hv.x, w1[(q << 2)], a2);
            a3 = fmaf(hv.y, w1[(q << 2) + 1], a3);
            a2 = fmaf(hv.z, w1[(q << 2) + 2], a2);
            a3 = fmaf(hv.w, w1[(q << 2) + 3], a3);
        }
        m0 = fmaxf(m0, b0v + a0 + a1);
        m1 = fmaxf(m1, b1v + a2 + a3);
    }
    x1[(size_t)g * 128 + lane] = m0;
    x1[(size_t)g * 128 + 64 + lane] = m1;
}

// ---------------------------------------------------------------------------
// Merged launch: blocks 0-7 run fps2 (1024->256), blocks 8.. run conv1.
// ---------------------------------------------------------------------------
union UM {
    U1 c;
    struct {
        float4 sp[1024];
        unsigned long long rec[512];
        int sidx[256];
    } f;
};

__global__ __launch_bounds__(256, 2) void fps2_conv1_kernel(
    const float* __restrict__ pos, const float4* __restrict__ pos1,
    const float* __restrict__ curv1, float4* __restrict__ pos2,
    float* __restrict__ Abuf,
    const float* __restrict__ W1, const float* __restrict__ B1,
    const float* __restrict__ W2, const float* __restrict__ B2,
    const float* __restrict__ W3, const float* __restrict__ B3,
    float* __restrict__ x1) {
    __shared__ UM u;
    if (blockIdx.x < 8) {
        fps_body<1024, 256, 4>((const float*)pos1, 4, curv1, blockIdx.x, pos2,
                               nullptr, Abuf, 260, u.f.sp, u.f.sidx, u.f.rec);
    } else {
        conv1_body(blockIdx.x - 8, u.c, pos, pos1, W1, B1, W2, B2, W3, B3, x1);
    }
}

// ---------------------------------------------------------------------------
// SA2: radius r=0.4 grouping + PointNetConv(131->128->128->256)
// ---------------------------------------------------------------------------
union U2 {
    struct {
        float4 sp[1024];
        unsigned ck[4][512];
        int ci[4][512];
        int sel[4][64];
        int cnt[4], cnt2[4];
    } p;
    unsigned h2s[4][4096];  // [wave][n*64 + (j ^ ((n&7)<<3))], dword = half2
};

__global__ __launch_bounds__(256, 2) void conv2_kernel(
    const float4* __restrict__ pos1, const float4* __restrict__ pos2,
    const float* __restrict__ x1,
    const float* __restrict__ Wa, const float* __restrict__ Ba,
    const float* __restrict__ Wb, const float* __restrict__ Bb,
    const float* __restrict__ Wc, const float* __restrict__ Bc,
    float* __restrict__ Aout) {
    __shared__ U2 u;
    int cloud = blockIdx.x >> 6;
    int w4 = TID >> 6, lane = TID & 63;
    int cent = ((blockIdx.x & 63) << 2) + w4;
    int g = (cloud << 8) + cent;
    for (int j = TID; j < 1024; j += 256) u.p.sp[j] = pos1[(cloud << 10) + j];
    if (lane == 0) { u.p.cnt[w4] = 0; u.p.cnt2[w4] = 0; }
    __syncthreads();
    float4 cq = pos2[g];
    double cx = cq.x, cy = cq.y, cz = cq.z;
    for (int s = 0; s < 16; ++s) {
        int j = (s << 6) + lane;
        float4 pj = u.p.sp[j];
        double dx = (double)pj.x - cx, dy = (double)pj.y - cy, dz = (double)pj.z - cz;
        double d2 = dx * dx + dy * dy + dz * dz;
        if (d2 <= 0.4 * 0.4) {
            int p = atomicAdd(&u.p.cnt[w4], 1);
            if (p < 512) { u.p.ck[w4][p] = __float_as_uint((float)d2); u.p.ci[w4][p] = j; }
        }
    }
    __syncthreads();
    int c = min(u.p.cnt[w4], 512);
    int nb;
    int idxn = select_k64(u.p.ck[w4], u.p.ci[w4], c, lane, &u.p.cnt2[w4],
                          u.p.sel[w4], &nb);
    float4 pn = u.p.sp[idxn];
    float rx = pn.x - cq.x, ry = pn.y - cq.y, rz = pn.z - cq.z;
    const float4* xr = (const float4*)(x1 + (size_t)((cloud << 10) + idxn) * 128);
    float h2[128];
#pragma unroll
    for (int cc2 = 0; cc2 < 128; ++cc2) h2[cc2] = Bb[cc2];
#pragma unroll
    for (int half = 0; half < 2; ++half) {
        float h1[64];
#pragma unroll
        for (int cc2 = 0; cc2 < 64; ++cc2) h1[cc2] = Ba[(half << 6) + cc2];
        for (int ic = 0; ic < 32; ++ic) {
            float4 xv = xr[ic];
            const float* wr = Wa + (ic * 4) * 128 + (half << 6);
#pragma unroll
            for (int ii = 0; ii < 4; ++ii) {
                float xs = (&xv.x)[ii];
#pragma unroll
                for (int cc2 = 0; cc2 < 64; ++cc2)
                    h1[cc2] = fmaf(xs, wr[ii * 128 + cc2], h1[cc2]);
            }
        }
#pragma unroll
        for (int cc2 = 0; cc2 < 64; ++cc2) {
            float v = fmaf(rx, Wa[128 * 128 + (half << 6) + cc2],
                    fmaf(ry, Wa[129 * 128 + (half << 6) + cc2],
                    fmaf(rz, Wa[130 * 128 + (half << 6) + cc2], h1[cc2])));
            h1[cc2] = fmaxf(v, 0.f);
        }
#pragma unroll
        for (int i = 0; i < 64; ++i) {
            float hv = h1[i];
            const float* wr = Wb + ((half << 6) + i) * 128;
#pragma unroll
            for (int cc2 = 0; cc2 < 128; ++cc2) h2[cc2] = fmaf(hv, wr[cc2], h2[cc2]);
        }
    }
#pragma unroll
    for (int cc2 = 0; cc2 < 128; ++cc2) h2[cc2] = fmaxf(h2[cc2], 0.f);
    __syncthreads();   // all waves done with grouping buffers / sp
    {
        unsigned* hrow = &u.h2s[w4][lane << 6];
        int sw = (lane & 7) << 3;
#pragma unroll
        for (int q = 0; q < 16; ++q) {
            unsigned tmp[4];
#pragma unroll
            for (int k2 = 0; k2 < 4; ++k2) {
                int j = (q << 2) + k2;
                __half2 hh = __floats2half2_rn(h2[2 * j], h2[2 * j + 1]);
                __builtin_memcpy(&tmp[k2], &hh, 4);
            }
            uint4 pk = make_uint4(tmp[0], tmp[1], tmp[2], tmp[3]);
            *(uint4*)&hrow[(q << 2) ^ sw] = pk;
        }
    }
    float* arow = Aout + (size_t)g * 260;
#pragma unroll 1
    for (int ch = 0; ch < 4; ++ch) {
        int cc = (ch << 6) + lane;
        float w[128];
#pragma unroll
        for (int i = 0; i < 128; ++i) w[i] = Wc[i * 256 + cc];
        float bb = Bc[cc];
        float m = -1e30f;
        for (int n = 0; n < nb; ++n) {
            const unsigned* hr = &u.h2s[w4][n << 6];
            int sw2 = (n & 7) << 3;
            float a0 = 0.f, a1 = 0.f, a2 = 0.f, a3 = 0.f;
#pragma unroll
            for (int q = 0; q < 16; ++q) {
                uint4 hv = *(const uint4*)&hr[((q << 2) ^ sw2)];
                int jb = (q << 3);
                __half2 p0, p1, p2, p3;
                __builtin_memcpy(&p0, &hv.x, 4);
                __builtin_memcpy(&p1, &hv.y, 4);
                __builtin_memcpy(&p2, &hv.z, 4);
                __builtin_memcpy(&p3, &hv.w, 4);
                a0 = fmaf(__low2float(p0),  w[jb + 0], a0);
                a1 = fmaf(__high2float(p0), w[jb + 1], a1);
                a2 = fmaf(__low2float(p1),  w[jb + 2], a2);
                a3 = fmaf(__high2float(p1), w[jb + 3], a3);
                a0 = fmaf(__low2float(p2),  w[jb + 4], a0);
                a1 = fmaf(__high2float(p2), w[jb + 5], a1);
                a2 = fmaf(__low2float(p3),  w[jb + 6], a2);
                a3 = fmaf(__high2float(p3), w[jb + 7], a3);
            }
            m = fmaxf(m, bb + (a0 + a1) + (a2 + a3));
        }
        arow[cc] = m;
    }
}

// ---------------------------------------------------------------------------
// fp32 tiled GEMM: C[M,N] = A[M,K] @ B[K,N] + bias (+relu). 64x64 tiles.
// ---------------------------------------------------------------------------
__global__ __launch_bounds__(256, 2) void gemm_bias(
    const float* __restrict__ A, int lda, const float* __restrict__ Bw, int ldb,
    const float* __restrict__ bias, float* __restrict__ C, int ldc,
    int M, int N, int K, int relu) {
    __shared__ float As[16][68];
    __shared__ float Bs[16][68];
    int nbx = N >> 6;
    int bx = blockIdx.x % nbx, by = blockIdx.x / nbx;
    int tx = TID & 15, ty = TID >> 4;
    int r0 = by << 6, c0 = bx << 6;
    float acc[4][4];
#pragma unroll
    for (int i = 0; i < 4; ++i)
#pragma unroll
        for (int j = 0; j < 4; ++j) acc[i][j] = 0.f;
    int lr = TID >> 2, lk = (TID & 3) << 2;
    int ln = TID & 63, lk2 = TID >> 6;
    for (int k0 = 0; k0 < K; k0 += 16) {
#pragma unroll
        for (int u = 0; u < 4; ++u) {
            int kk = k0 + lk + u;
            As[lk + u][lr] = (kk < K) ? A[(size_t)(r0 + lr) * lda + kk] : 0.f;
        }
#pragma unroll
        for (int u = 0; u < 4; ++u) {
            int krow = lk2 + (u << 2);
            int kk = k0 + krow;
            Bs[krow][ln] = (kk < K) ? Bw[(size_t)kk * ldb + c0 + ln] : 0.f;
        }
        __syncthreads();
#pragma unroll
        for (int kk = 0; kk < 16; ++kk) {
            float av[4], bv[4];
#pragma unroll
            for (int i = 0; i < 4; ++i) av[i] = As[kk][(ty << 2) + i];
#pragma unroll
            for (int j = 0; j < 4; ++j) bv[j] = Bs[kk][(tx << 2) + j];
#pragma unroll
            for (int i = 0; i < 4; ++i)
#pragma unroll
                for (int j = 0; j < 4; ++j) acc[i][j] = fmaf(av[i], bv[j], acc[i][j]);
        }
        __syncthreads();
    }
#pragma unroll
    for (int i = 0; i < 4; ++i) {
        int row = r0 + (ty << 2) + i;
#pragma unroll
        for (int j = 0; j < 4; ++j) {
            int col = c0 + (tx << 2) + j;
            float v = acc[i][j] + bias[col];
            if (relu) v = fmaxf(v, 0.f);
            C[(size_t)row * ldc + col] = v;
        }
    }
}

// ---------------------------------------------------------------------------
// Per-cloud max over 256 rows of h3 -> gfeat[8][1024]. 64 blocks (8/cloud).
// ---------------------------------------------------------------------------
__global__ __launch_bounds__(256) void rowmax_kernel(const float* __restrict__ h3,
                                                     float* __restrict__ gfeat) {
    __shared__ float pm[256];
    int cloud = blockIdx.x >> 3;
    int seg = blockIdx.x & 7;
    int col = (seg << 7) + (TID & 127);
    int half = TID >> 7;
    float m = -3.0e38f;
    for (int r = half << 7; r < (half << 7) + 128; ++r)
        m = fmaxf(m, h3[(size_t)((cloud << 8) + r) * 1024 + col]);
    pm[TID] = m;
    __syncthreads();
    if (TID < 128) gfeat[(cloud << 10) + col] = fmaxf(pm[TID], pm[TID + 128]);
}

// ---------------------------------------------------------------------------
// Head MLP 1024->512->256->10 + log_softmax (one block per cloud)
// ---------------------------------------------------------------------------
__global__ __launch_bounds__(256) void head_kernel(
    const float* __restrict__ gfeat,
    const float* __restrict__ Wh1, const float* __restrict__ bh1,
    const float* __restrict__ Wh2, const float* __restrict__ bh2,
    const float* __restrict__ Wh3, const float* __restrict__ bh3,
    float* __restrict__ out) {
    __shared__ float gg[1024];
    __shared__ float s1[512];
    __shared__ float s2[256];
    __shared__ float lg[10];
    int cloud = blockIdx.x;
    for (int i = TID; i < 1024; i += 256) gg[i] = gfeat[(cloud << 10) + i];
    __syncthreads();
    for (int cc = TID; cc < 512; cc += 256) {
        float v = bh1[cc];
        for (int i = 0; i < 1024; ++i) v = fmaf(gg[i], Wh1[i * 512 + cc], v);
        s1[cc] = fmaxf(v, 0.f);
    }
    __syncthreads();
    for (int cc = TID; cc < 256; cc += 256) {
        float v = bh2[cc];
        for (int i = 0; i < 512; ++i) v = fmaf(s1[i], Wh2[i * 256 + cc], v);
        s2[cc] = fmaxf(v, 0.f);
    }
    __syncthreads();
    if (TID < 10) {
        float v = bh3[TID];
        for (int i = 0; i < 256; ++i) v = fmaf(s2[i], Wh3[i * 10 + TID], v);
        lg[TID] = v;
    }
    __syncthreads();
    if (TID == 0) {
        float mx = lg[0];
        for (int i = 1; i < 10; ++i) mx = fmaxf(mx, lg[i]);
        float s = 0.f;
        for (int i = 0; i < 10; ++i) s += expf(lg[i] - mx);
        float lse = mx + logf(s);
        for (int i = 0; i < 10; ++i) out[cloud * 10 + i] = lg[i] - lse;
    }
}

// ---------------------------------------------------------------------------
// Launch. Workspace layout (12.5 MB total; regions reused across phases).
// ---------------------------------------------------------------------------
extern "C" void kernel_launch(void* const* d_in, const int* in_sizes, int n_in,
                              void* d_out, int out_size, void* d_ws, size_t ws_size,
                              hipStream_t stream) {
    (void)in_sizes; (void)n_in; (void)out_size; (void)ws_size;
    const float* pos = (const float*)d_in[0];
    const float* W1a = (const float*)d_in[1];  const float* b1a = (const float*)d_in[2];
    const float* W1b = (const float*)d_in[3];  const float* b1b = (const float*)d_in[4];
    const float* W1c = (const float*)d_in[5];  const float* b1c = (const float*)d_in[6];
    const float* W2a = (const float*)d_in[7];  const float* b2a = (const float*)d_in[8];
    const float* W2b = (const float*)d_in[9];  const float* b2b = (const float*)d_in[10];
    const float* W2c = (const float*)d_in[11]; const float* b2c = (const float*)d_in[12];
    const float* W3a = (const float*)d_in[13]; const float* b3a = (const float*)d_in[14];
    const float* W3b = (const float*)d_in[15]; const float* b3b = (const float*)d_in[16];
    const float* W3c = (const float*)d_in[17]; const float* b3c = (const float*)d_in[18];
    const float* Wh1 = (const float*)d_in[19]; const float* bh1 = (const float*)d_in[20];
    const float* Wh2 = (const float*)d_in[21]; const float* bh2 = (const float*)d_in[22];
    const float* Wh3 = (const float*)d_in[23]; const float* bh3 = (const float*)d_in[24];

    char* ws = (char*)d_ws;
    float*  curv  = (float*)(ws + 0);
    float4* pos1  = (float4*)(ws + 98304);
    float*  curv1 = (float*)(ws + 229376);
    float4* pos2  = (float4*)(ws + 270336);
    float*  gfeat = (float*)(ws + 303104);
    float*  x1    = (float*)(ws + 524288);
    float*  Abuf  = (float*)(ws + 4718592);
    float*  h1g   = (float*)(ws + 6848512);
    float*  h2g   = x1;     // x1 dead after conv2
    float*  h3g   = Abuf;   // A + h1g dead after gemm2

    curv_kernel<<<64, 256, 0, stream>>>(pos, curv);
    fps1_kernel<<<8, 256, 0, stream>>>(pos, curv, pos1, curv1);
    fps2_conv1_kernel<<<2056, 256, 0, stream>>>(pos, pos1, curv1, pos2, Abuf,
                                                W1a, b1a, W1b, b1b, W1c, b1c, x1);
    conv2_kernel<<<512, 256, 0, stream>>>(pos1, pos2, x1, W2a, b2a, W2b, b2b, W2c, b2c,
                                          Abuf);
    gemm_bias<<<128, 256, 0, stream>>>(Abuf, 260, W3a, 256, b3a, h1g, 256,
                                       2048, 256, 259, 1);
    gemm_bias<<<256, 256, 0, stream>>>(h1g, 256, W3b, 512, b3b, h2g, 512,
                                       2048, 512, 256, 1);
    gemm_bias<<<512, 256, 0, stream>>>(h2g, 512, W3c, 1024, b3c, h3g, 1024,
                                       2048, 1024, 512, 0);
    rowmax_kernel<<<64, 256, 0, stream>>>(h3g, gfeat);
    head_kernel<<<8, 256, 0, stream>>>(gfeat, Wh1, bh1, Wh2, bh2, Wh3, bh3,
                                       (float*)d_out);
}

// Round 5
// 1866.305 us; speedup vs baseline: 2.8570x; 1.1413x over previous
//
#include <hip/hip_runtime.h>
#include <hip/hip_fp16.h>
#include <math.h>

#define TID threadIdx.x

typedef _Float16 h2vec __attribute__((ext_vector_type(2)));

// fp16 pair dot into fp32 accumulator: v_dot2_f32_f16
static __device__ __forceinline__ float fdot2(unsigned a, unsigned b, float c) {
    h2vec av, bv;
    __builtin_memcpy(&av, &a, 4);
    __builtin_memcpy(&bv, &b, 4);
    return __builtin_amdgcn_fdot2(av, bv, c, false);
}

static __device__ __forceinline__ unsigned packh2(float a, float b) {
    __half2 hh = __floats2half2_rn(a, b);
    unsigned u;
    __builtin_memcpy(&u, &hh, 4);
    return u;
}

static __device__ __forceinline__ int wave_sum(int v) {
#pragma unroll
    for (int o = 32; o >= 1; o >>= 1) v += __shfl_xor(v, o, 64);
    return v;
}

// u64 max with partner brought in by DPP; bound_ctrl=true shifts in 0 (identity).
template <int CTRL>
static __device__ __forceinline__ unsigned long long dpp_max_u64(unsigned long long k) {
    int lo = (int)(unsigned)(k & 0xffffffffULL);
    int hi = (int)(unsigned)(k >> 32);
    int lo2 = __builtin_amdgcn_update_dpp(0, lo, CTRL, 0xf, 0xf, true);
    int hi2 = __builtin_amdgcn_update_dpp(0, hi, CTRL, 0xf, 0xf, true);
    unsigned long long k2 = ((unsigned long long)(unsigned)hi2 << 32) | (unsigned)lo2;
    return k2 > k ? k2 : k;
}

// ---------------------------------------------------------------------------
// Curvature: per-point 10-NN covariance, lambda_min / sum(lambda)
// ---------------------------------------------------------------------------
__global__ __launch_bounds__(256) void curv_kernel(const float* __restrict__ pos,
                                                   float* __restrict__ curv) {
    __shared__ float4 sp[2048];
    int cloud = blockIdx.x >> 3;
    int base = cloud << 11;
    for (int j = TID; j < 2048; j += 256) {
        const float* p = pos + (size_t)(base + j) * 3;
        float x = p[0], y = p[1], z = p[2];
        sp[j] = make_float4(x, y, z, fmaf(x, x, fmaf(y, y, z * z)));
    }
    __syncthreads();
    int li = ((blockIdx.x & 7) << 8) + TID;
    float4 pi = sp[li];
    float bd[10];
    int bi[10];
#pragma unroll
    for (int t = 0; t < 10; ++t) { bd[t] = 3.0e38f; bi[t] = 0; }
    for (int j = 0; j < 2048; ++j) {
        float4 pj = sp[j];
        float dot = fmaf(pi.x, pj.x, fmaf(pi.y, pj.y, pi.z * pj.z));
        float d2 = pi.w + pj.w - 2.0f * dot;   // same form as reference _sqdist
        if (d2 < bd[9]) {
            bd[9] = d2; bi[9] = j;
#pragma unroll
            for (int t = 9; t > 0; --t) {
                if (bd[t] < bd[t - 1]) {
                    float td = bd[t]; bd[t] = bd[t - 1]; bd[t - 1] = td;
                    int ti = bi[t]; bi[t] = bi[t - 1]; bi[t - 1] = ti;
                }
            }
        }
    }
    double sx = 0, sy = 0, sz = 0;
#pragma unroll
    for (int t = 0; t < 10; ++t) { float4 p = sp[bi[t]]; sx += p.x; sy += p.y; sz += p.z; }
    double mx = sx / 10.0, my = sy / 10.0, mz = sz / 10.0;
    double cxx = 0, cxy = 0, cxz = 0, cyy = 0, cyz = 0, czz = 0;
#pragma unroll
    for (int t = 0; t < 10; ++t) {
        float4 p = sp[bi[t]];
        double dx = p.x - mx, dy = p.y - my, dz = p.z - mz;
        cxx += dx * dx; cxy += dx * dy; cxz += dx * dz;
        cyy += dy * dy; cyz += dy * dz; czz += dz * dz;
    }
    cxx /= 10.0; cxy /= 10.0; cxz /= 10.0; cyy /= 10.0; cyz /= 10.0; czz /= 10.0;
    double q = (cxx + cyy + czz) / 3.0;
    double b00 = cxx - q, b11 = cyy - q, b22 = czz - q;
    double p2 = b00 * b00 + b11 * b11 + b22 * b22 +
                2.0 * (cxy * cxy + cxz * cxz + cyz * cyz);
    double lmin;
    if (p2 <= 0.0) {
        lmin = q;
    } else {
        double p = sqrt(p2 / 6.0);
        double inv = 1.0 / p;
        double c00 = b00 * inv, c01 = cxy * inv, c02 = cxz * inv;
        double c11 = b11 * inv, c12 = cyz * inv, c22 = b22 * inv;
        double detB = c00 * (c11 * c22 - c12 * c12)
                    - c01 * (c01 * c22 - c12 * c02)
                    + c02 * (c01 * c12 - c11 * c02);
        double r = 0.5 * detB;
        r = fmin(1.0, fmax(-1.0, r));
        double phi = acos(r) / 3.0;
        lmin = q + 2.0 * p * cos(phi + 2.0943951023931953);  // smallest eigenvalue
    }
    double s3 = cxx + cyy + czz;
    curv[base + li] = (float)(lmin / (s3 + 1e-8));
}

// ---------------------------------------------------------------------------
// Weighted FPS body. Per iter: per-thread slot fold (byte-identical float ops),
// pack (score_bits<<32)|(2047-idx) u64, DPP-reduce within wave, lane63 posts
// one record/wave, one barrier, all threads fold the 4 uniform records ->
// uniform winner with exact lowest-index tie-break (max is associative).
// ---------------------------------------------------------------------------
template <int N, int M, int SLOTS>
static __device__ void fps_body(
    const float* __restrict__ srcpos, int stride, const float* __restrict__ srccurv,
    int cloud, float4* __restrict__ outPos, float* __restrict__ outCurv,
    float* __restrict__ outA, int ldA,
    float4* sp, int* sidx, unsigned long long* rec /* [8] */) {
    const float* cp = srcpos + (size_t)cloud * N * stride;
    for (int j = TID; j < N; j += 256)
        sp[j] = make_float4(cp[j * stride], cp[j * stride + 1], cp[j * stride + 2], 0.f);
    if (TID == 0) sidx[0] = 0;
    __syncthreads();
    float md[SLOTS], wv[SLOTS], px[SLOTS], py[SLOTS], pz[SLOTS];
#pragma unroll
    for (int s = 0; s < SLOTS; ++s) {
        int p = (s << 8) + TID;
        float4 q = sp[p];
        px[s] = q.x; py[s] = q.y; pz[s] = q.z;
        md[s] = 3.0e38f;
        wv[s] = fmaf(10.0f, srccurv[cloud * N + p], 1.0f);
    }
    int lane = TID & 63, w4 = TID >> 6;
    float4 c0 = sp[0];
    float cx = c0.x, cy = c0.y, cz = c0.z;
    for (int t = 1; t < M; ++t) {
        float best = -1.0f;
        int bix = 0;
#pragma unroll
        for (int s = 0; s < SLOTS; ++s) {
            float dx = px[s] - cx, dy = py[s] - cy, dz = pz[s] - cz;
            float nd = fmaf(dx, dx, fmaf(dy, dy, dz * dz));
            float m2 = fminf(md[s], nd);
            md[s] = m2;
            float sc = m2 * wv[s];
            bool g = sc > best;           // strict > keeps earliest (lowest idx)
            best = g ? sc : best;
            bix = g ? ((s << 8) + TID) : bix;
        }
        // score >= 0 always -> float bits monotone under unsigned compare
        unsigned long long k =
            ((unsigned long long)__float_as_uint(best) << 32) | (unsigned)(2047 - bix);
        k = dpp_max_u64<0x111>(k);   // row_shr:1
        k = dpp_max_u64<0x112>(k);   // row_shr:2
        k = dpp_max_u64<0x114>(k);   // row_shr:4
        k = dpp_max_u64<0x118>(k);   // row_shr:8
        k = dpp_max_u64<0x142>(k);   // row_bcast15
        k = dpp_max_u64<0x143>(k);   // row_bcast31 -> lane63 has wave max
        int pbase = (t & 1) << 2;
        if (lane == 63) rec[pbase | w4] = k;
        __syncthreads();
        unsigned long long k0 = rec[pbase + 0];
        unsigned long long k1 = rec[pbase + 1];
        unsigned long long k2 = rec[pbase + 2];
        unsigned long long k3 = rec[pbase + 3];
        unsigned long long ka = k0 > k1 ? k0 : k1;
        unsigned long long kb = k2 > k3 ? k2 : k3;
        unsigned long long km = ka > kb ? ka : kb;
        int nbix = 2047 - (int)(unsigned)(km & 0xffffffffULL);  // uniform winner
        if (TID == 0) sidx[t] = nbix;
        float4 cc = sp[nbix];        // uniform (broadcast) read
        cx = cc.x; cy = cc.y; cz = cc.z;
    }
    __syncthreads();
    for (int j = TID; j < M; j += 256) {
        int id = sidx[j];
        float4 qv = sp[id];
        outPos[cloud * M + j] = qv;
        if (outCurv) outCurv[cloud * M + j] = srccurv[cloud * N + id];
        if (outA) {
            float* a = outA + (size_t)(cloud * M + j) * ldA;
            a[256] = qv.x; a[257] = qv.y; a[258] = qv.z;
        }
    }
}

// Standalone fps1 (2048 -> 1024)
__global__ __launch_bounds__(256, 1) void fps1_kernel(
    const float* __restrict__ pos, const float* __restrict__ curv,
    float4* __restrict__ pos1, float* __restrict__ curv1) {
    __shared__ float4 sp[2048];
    __shared__ int sidx[1024];
    __shared__ unsigned long long rec[8];
    fps_body<2048, 1024, 8>(pos, 3, curv, blockIdx.x, pos1, curv1, nullptr, 0,
                            sp, sidx, rec);
}

// ---------------------------------------------------------------------------
// Exact top-64 (smallest d2, idx tie-break) selection within one wave.
// ---------------------------------------------------------------------------
static __device__ __forceinline__ int select_k64(const unsigned int* ck, const int* ci,
                                                 int c, int lane, int* cnt2, int* sel,
                                                 int* nbOut) {
    if (c <= 64) {
        *nbOut = c;
        return (lane < c) ? ci[lane] : 0;
    }
    unsigned int T = 0;  // becomes the 64th-smallest key
    for (int bit = 31; bit >= 0; --bit) {
        unsigned int mid = T | (1u << bit);
        int cl = 0;
        for (int q = lane; q < c; q += 64) cl += (ck[q] < mid) ? 1 : 0;
        if (wave_sum(cl) < 64) T = mid;
    }
    int cl = 0;
    for (int q = lane; q < c; q += 64) cl += (ck[q] < T) ? 1 : 0;
    int need = 64 - wave_sum(cl);
    int TI = 0;  // becomes the need-th smallest idx among keys == T
    for (int bit = 11; bit >= 0; --bit) {
        int mid = TI | (1 << bit);
        int ce = 0;
        for (int q = lane; q < c; q += 64) ce += (ck[q] == T && ci[q] < mid) ? 1 : 0;
        if (wave_sum(ce) < need) TI = mid;
    }
    for (int q = lane; q < c; q += 64) {
        unsigned int kq = ck[q];
        int iq = ci[q];
        if (kq < T || (kq == T && iq <= TI)) sel[atomicAdd(cnt2, 1)] = iq;
    }
    *nbOut = 64;
    return sel[lane];
}

// ---------------------------------------------------------------------------
// SA1 conv body (3->64->64->128). h2 staged to LDS as fp16 pairs; L3 is
// weights-stationary: lane = channel (wave-pair covers 128 ch), each lane's
// W3 column in 32 half2 regs reused across 2 centroids; fdot2 inner loop.
// ---------------------------------------------------------------------------
union U1 {
    struct {
        float4 sp[2048];
        unsigned ck[4][256];
        int ci[4][256];
        int sel[4][64];
        int cnt[4], cnt2[4];
    } p;
    unsigned h2s[4][2048];   // [cent][n*32 + ((q*4) ^ ((n&7)*4)) + k], half2 elems
};

static __device__ void conv1_body(
    int bid, U1& u,
    const float* __restrict__ pos, const float4* __restrict__ pos1,
    const float* __restrict__ W1, const float* __restrict__ B1,
    const float* __restrict__ W2, const float* __restrict__ B2,
    const float* __restrict__ W3, const float* __restrict__ B3,
    float* __restrict__ x1) {
    __shared__ int nbs[4];
    int cloud = bid >> 8;
    int w4 = TID >> 6, lane = TID & 63;
    int centb = (bid & 255) << 2;
    int g = (cloud << 10) + centb + w4;
    int base = cloud << 11;
    for (int j = TID; j < 2048; j += 256) {
        const float* p = pos + (size_t)(base + j) * 3;
        u.p.sp[j] = make_float4(p[0], p[1], p[2], 0.f);
    }
    if (lane == 0) { u.p.cnt[w4] = 0; u.p.cnt2[w4] = 0; }
    __syncthreads();
    float4 cq = pos1[g];
    double cx = cq.x, cy = cq.y, cz = cq.z;
    for (int s = 0; s < 32; ++s) {
        int j = (s << 6) + lane;
        float4 pj = u.p.sp[j];
        double dx = (double)pj.x - cx, dy = (double)pj.y - cy, dz = (double)pj.z - cz;
        double d2 = dx * dx + dy * dy + dz * dz;
        if (d2 <= 0.2 * 0.2) {
            int p = atomicAdd(&u.p.cnt[w4], 1);
            if (p < 256) { u.p.ck[w4][p] = __float_as_uint((float)d2); u.p.ci[w4][p] = j; }
        }
    }
    __syncthreads();
    int c = min(u.p.cnt[w4], 256);
    int nb;
    int idxn = select_k64(u.p.ck[w4], u.p.ci[w4], c, lane, &u.p.cnt2[w4],
                          u.p.sel[w4], &nb);
    if (lane == 0) nbs[w4] = nb;
    float4 pn = u.p.sp[idxn];
    float rx = pn.x - cq.x, ry = pn.y - cq.y, rz = pn.z - cq.z;
    float h1[64];
#pragma unroll
    for (int cc2 = 0; cc2 < 64; ++cc2) {
        float v = fmaf(rx, W1[cc2], fmaf(ry, W1[64 + cc2], fmaf(rz, W1[128 + cc2], B1[cc2])));
        h1[cc2] = fmaxf(v, 0.f);
    }
    float h2[64];
#pragma unroll
    for (int cc2 = 0; cc2 < 64; ++cc2) h2[cc2] = B2[cc2];
#pragma unroll
    for (int i = 0; i < 64; ++i) {
        float hv = h1[i];
        const float* wr = W2 + i * 64;
#pragma unroll
        for (int cc2 = 0; cc2 < 64; ++cc2) h2[cc2] = fmaf(hv, wr[cc2], h2[cc2]);
    }
#pragma unroll
    for (int cc2 = 0; cc2 < 64; ++cc2) h2[cc2] = fmaxf(h2[cc2], 0.f);
    __syncthreads();   // all waves done with grouping buffers / sp
    {
        unsigned* hrow = &u.h2s[w4][lane << 5];
        int sw = (lane & 7) << 2;
#pragma unroll
        for (int q = 0; q < 8; ++q) {
            unsigned tmp[4];
#pragma unroll
            for (int k2 = 0; k2 < 4; ++k2) {
                int j = (q << 2) + k2;
                tmp[k2] = packh2(h2[2 * j], h2[2 * j + 1]);
            }
            *(uint4*)&hrow[(q << 2) ^ sw] = make_uint4(tmp[0], tmp[1], tmp[2], tmp[3]);
        }
    }
    __syncthreads();   // h2s + nbs visible block-wide
    // L3: lane = channel (wave pairs cover 128 ch), 2 centroids per lane
    int ch = ((w4 & 1) << 6) + lane;
    int cbase = (w4 >> 1) << 1;
    unsigned w2[32];
#pragma unroll
    for (int p = 0; p < 32; ++p)
        w2[p] = packh2(W3[(2 * p) * 128 + ch], W3[(2 * p + 1) * 128 + ch]);
    float bv = B3[ch];
#pragma unroll 1
    for (int ci2 = 0; ci2 < 2; ++ci2) {
        int cc = cbase + ci2;
        int nbc = nbs[cc];
        float m = -1e30f;
        for (int n = 0; n < nbc; ++n) {
            const unsigned* hr = &u.h2s[cc][n << 5];
            int sw2 = (n & 7) << 2;
            float a0 = 0.f, a1 = 0.f, a2 = 0.f, a3 = 0.f;
#pragma unroll
            for (int q = 0; q < 8; ++q) {
                uint4 hv = *(const uint4*)&hr[(q << 2) ^ sw2];
                a0 = fdot2(hv.x, w2[(q << 2) + 0], a0);
                a1 = fdot2(hv.y, w2[(q << 2) + 1], a1);
                a2 = fdot2(hv.z, w2[(q << 2) + 2], a2);
                a3 = fdot2(hv.w, w2[(q << 2) + 3], a3);
            }
            m = fmaxf(m, bv + (a0 + a1) + (a2 + a3));
        }
        x1[(size_t)((cloud << 10) + centb + cc) * 128 + ch] = m;
    }
}

// ---------------------------------------------------------------------------
// Merged launch: blocks 0-7 run fps2 (1024->256), blocks 8.. run conv1.
// ---------------------------------------------------------------------------
union UM {
    U1 c;
    struct {
        float4 sp[1024];
        unsigned long long rec[8];
        int sidx[256];
    } f;
};

__global__ __launch_bounds__(256, 2) void fps2_conv1_kernel(
    const float* __restrict__ pos, const float4* __restrict__ pos1,
    const float* __restrict__ curv1, float4* __restrict__ pos2,
    float* __restrict__ Abuf,
    const float* __restrict__ W1, const float* __restrict__ B1,
    const float* __restrict__ W2, const float* __restrict__ B2,
    const float* __restrict__ W3, const float* __restrict__ B3,
    float* __restrict__ x1) {
    __shared__ UM u;
    if (blockIdx.x < 8) {
        fps_body<1024, 256, 4>((const float*)pos1, 4, curv1, blockIdx.x, pos2,
                               nullptr, Abuf, 260, u.f.sp, u.f.sidx, u.f.rec);
    } else {
        conv1_body(blockIdx.x - 8, u.c, pos, pos1, W1, B1, W2, B2, W3, B3, x1);
    }
}

// ---------------------------------------------------------------------------
// SA2: radius r=0.4 grouping + PointNetConv(131->128->128->256).
// L3 weights-stationary: lane = one of 256 channels, Wc column in 64 half2
// regs reused across all 4 centroids of the block (Wc traffic /4); fdot2.
// ---------------------------------------------------------------------------
union U2 {
    struct {
        float4 sp[1024];
        unsigned ck[4][512];
        int ci[4][512];
        int sel[4][64];
        int cnt[4], cnt2[4];
    } p;
    unsigned h2s[4][4096];  // [cent][n*64 + ((q*4) ^ ((n&7)*8)) + k], half2 elems
};

__global__ __launch_bounds__(256, 2) void conv2_kernel(
    const float4* __restrict__ pos1, const float4* __restrict__ pos2,
    const float* __restrict__ x1,
    const float* __restrict__ Wa, const float* __restrict__ Ba,
    const float* __restrict__ Wb, const float* __restrict__ Bb,
    const float* __restrict__ Wc, const float* __restrict__ Bc,
    float* __restrict__ Aout) {
    __shared__ U2 u;
    __shared__ int nbs[4];
    int cloud = blockIdx.x >> 6;
    int w4 = TID >> 6, lane = TID & 63;
    int centb = (blockIdx.x & 63) << 2;
    int g = (cloud << 8) + centb + w4;
    for (int j = TID; j < 1024; j += 256) u.p.sp[j] = pos1[(cloud << 10) + j];
    if (lane == 0) { u.p.cnt[w4] = 0; u.p.cnt2[w4] = 0; }
    __syncthreads();
    float4 cq = pos2[g];
    double cx = cq.x, cy = cq.y, cz = cq.z;
    for (int s = 0; s < 16; ++s) {
        int j = (s << 6) + lane;
        float4 pj = u.p.sp[j];
        double dx = (double)pj.x - cx, dy = (double)pj.y - cy, dz = (double)pj.z - cz;
        double d2 = dx * dx + dy * dy + dz * dz;
        if (d2 <= 0.4 * 0.4) {
            int p = atomicAdd(&u.p.cnt[w4], 1);
            if (p < 512) { u.p.ck[w4][p] = __float_as_uint((float)d2); u.p.ci[w4][p] = j; }
        }
    }
    __syncthreads();
    int c = min(u.p.cnt[w4], 512);
    int nb;
    int idxn = select_k64(u.p.ck[w4], u.p.ci[w4], c, lane, &u.p.cnt2[w4],
                          u.p.sel[w4], &nb);
    if (lane == 0) nbs[w4] = nb;
    float4 pn = u.p.sp[idxn];
    float rx = pn.x - cq.x, ry = pn.y - cq.y, rz = pn.z - cq.z;
    const float4* xr = (const float4*)(x1 + (size_t)((cloud << 10) + idxn) * 128);
    // L1 (131 -> 128, relu) fused with L2 (128 -> 128) in two 64-channel halves.
    float h2[128];
#pragma unroll
    for (int cc2 = 0; cc2 < 128; ++cc2) h2[cc2] = Bb[cc2];
#pragma unroll
    for (int half = 0; half < 2; ++half) {
        float h1[64];
#pragma unroll
        for (int cc2 = 0; cc2 < 64; ++cc2) h1[cc2] = Ba[(half << 6) + cc2];
        for (int ic = 0; ic < 32; ++ic) {
            float4 xv = xr[ic];
            const float* wr = Wa + (ic * 4) * 128 + (half << 6);
#pragma unroll
            for (int ii = 0; ii < 4; ++ii) {
                float xs = (&xv.x)[ii];
#pragma unroll
                for (int cc2 = 0; cc2 < 64; ++cc2)
                    h1[cc2] = fmaf(xs, wr[ii * 128 + cc2], h1[cc2]);
            }
        }
#pragma unroll
        for (int cc2 = 0; cc2 < 64; ++cc2) {
            float v = fmaf(rx, Wa[128 * 128 + (half << 6) + cc2],
                    fmaf(ry, Wa[129 * 128 + (half << 6) + cc2],
                    fmaf(rz, Wa[130 * 128 + (half << 6) + cc2], h1[cc2])));
            h1[cc2] = fmaxf(v, 0.f);
        }
#pragma unroll
        for (int i = 0; i < 64; ++i) {
            float hv = h1[i];
            const float* wr = Wb + ((half << 6) + i) * 128;
#pragma unroll
            for (int cc2 = 0; cc2 < 128; ++cc2) h2[cc2] = fmaf(hv, wr[cc2], h2[cc2]);
        }
    }
#pragma unroll
    for (int cc2 = 0; cc2 < 128; ++cc2) h2[cc2] = fmaxf(h2[cc2], 0.f);
    __syncthreads();   // all waves done with grouping buffers / sp
    {
        unsigned* hrow = &u.h2s[w4][lane << 6];
        int sw = (lane & 7) << 3;
#pragma unroll
        for (int q = 0; q < 16; ++q) {
            unsigned tmp[4];
#pragma unroll
            for (int k2 = 0; k2 < 4; ++k2) {
                int j = (q << 2) + k2;
                tmp[k2] = packh2(h2[2 * j], h2[2 * j + 1]);
            }
            *(uint4*)&hrow[(q << 2) ^ sw] = make_uint4(tmp[0], tmp[1], tmp[2], tmp[3]);
        }
    }
    __syncthreads();   // h2s + nbs visible block-wide
    // L3: lane = one of 256 output channels; loop the block's 4 centroids.
    int cc = (w4 << 6) + lane;
    unsigned w2[64];
#pragma unroll
    for (int p = 0; p < 64; ++p)
        w2[p] = packh2(Wc[(2 * p) * 256 + cc], Wc[(2 * p + 1) * 256 + cc]);
    float bb = Bc[cc];
#pragma unroll 1
    for (int ci2 = 0; ci2 < 4; ++ci2) {
        int nbc = nbs[ci2];
        float m = -1e30f;
        for (int n = 0; n < nbc; ++n) {
            const unsigned* hr = &u.h2s[ci2][n << 6];
            int sw2 = (n & 7) << 3;
            float a0 = 0.f, a1 = 0.f, a2 = 0.f, a3 = 0.f;
#pragma unroll
            for (int q = 0; q < 16; ++q) {
                uint4 hv = *(const uint4*)&hr[(q << 2) ^ sw2];
                a0 = fdot2(hv.x, w2[(q << 2) + 0], a0);
                a1 = fdot2(hv.y, w2[(q << 2) + 1], a1);
                a2 = fdot2(hv.z, w2[(q << 2) + 2], a2);
                a3 = fdot2(hv.w, w2[(q << 2) + 3], a3);
            }
            m = fmaxf(m, bb + (a0 + a1) + (a2 + a3));
        }
        Aout[(size_t)((cloud << 8) + centb + ci2) * 260 + cc] = m;
    }
}

// ---------------------------------------------------------------------------
// fp32 tiled GEMM: C[M,N] = A[M,K] @ B[K,N] + bias (+relu). 64x64 tiles.
// ---------------------------------------------------------------------------
__global__ __launch_bounds__(256, 2) void gemm_bias(
    const float* __restrict__ A, int lda, const float* __restrict__ Bw, int ldb,
    const float* __restrict__ bias, float* __restrict__ C, int ldc,
    int M, int N, int K, int relu) {
    __shared__ float As[16][68];
    __shared__ float Bs[16][68];
    int nbx = N >> 6;
    int bx = blockIdx.x % nbx, by = blockIdx.x / nbx;
    int tx = TID & 15, ty = TID >> 4;
    int r0 = by << 6, c0 = bx << 6;
    float acc[4][4];
#pragma unroll
    for (int i = 0; i < 4; ++i)
#pragma unroll
        for (int j = 0; j < 4; ++j) acc[i][j] = 0.f;
    int lr = TID >> 2, lk = (TID & 3) << 2;
    int ln = TID & 63, lk2 = TID >> 6;
    for (int k0 = 0; k0 < K; k0 += 16) {
#pragma unroll
        for (int u = 0; u < 4; ++u) {
            int kk = k0 + lk + u;
            As[lk + u][lr] = (kk < K) ? A[(size_t)(r0 + lr) * lda + kk] : 0.f;
        }
#pragma unroll
        for (int u = 0; u < 4; ++u) {
            int krow = lk2 + (u << 2);
            int kk = k0 + krow;
            Bs[krow][ln] = (kk < K) ? Bw[(size_t)kk * ldb + c0 + ln] : 0.f;
        }
        __syncthreads();
#pragma unroll
        for (int kk = 0; kk < 16; ++kk) {
            float av[4], bv[4];
#pragma unroll
            for (int i = 0; i < 4; ++i) av[i] = As[kk][(ty << 2) + i];
#pragma unroll
            for (int j = 0; j < 4; ++j) bv[j] = Bs[kk][(tx << 2) + j];
#pragma unroll
            for (int i = 0; i < 4; ++i)
#pragma unroll
                for (int j = 0; j < 4; ++j) acc[i][j] = fmaf(av[i], bv[j], acc[i][j]);
        }
        __syncthreads();
    }
#pragma unroll
    for (int i = 0; i < 4; ++i) {
        int row = r0 + (ty << 2) + i;
#pragma unroll
        for (int j = 0; j < 4; ++j) {
            int col = c0 + (tx << 2) + j;
            float v = acc[i][j] + bias[col];
            if (relu) v = fmaxf(v, 0.f);
            C[(size_t)row * ldc + col] = v;
        }
    }
}

// ---------------------------------------------------------------------------
// Per-cloud max over 256 rows of h3 -> gfeat[8][1024]. 64 blocks (8/cloud).
// ---------------------------------------------------------------------------
__global__ __launch_bounds__(256) void rowmax_kernel(const float* __restrict__ h3,
                                                     float* __restrict__ gfeat) {
    __shared__ float pm[256];
    int cloud = blockIdx.x >> 3;
    int seg = blockIdx.x & 7;
    int col = (seg << 7) + (TID & 127);
    int half = TID >> 7;
    float m = -3.0e38f;
    for (int r = half << 7; r < (half << 7) + 128; ++r)
        m = fmaxf(m, h3[(size_t)((cloud << 8) + r) * 1024 + col]);
    pm[TID] = m;
    __syncthreads();
    if (TID < 128) gfeat[(cloud << 10) + col] = fmaxf(pm[TID], pm[TID + 128]);
}

// ---------------------------------------------------------------------------
// Head MLP 1024->512->256->10 + log_softmax (one block per cloud)
// ---------------------------------------------------------------------------
__global__ __launch_bounds__(256) void head_kernel(
    const float* __restrict__ gfeat,
    const float* __restrict__ Wh1, const float* __restrict__ bh1,
    const float* __restrict__ Wh2, const float* __restrict__ bh2,
    const float* __restrict__ Wh3, const float* __restrict__ bh3,
    float* __restrict__ out) {
    __shared__ float gg[1024];
    __shared__ float s1[512];
    __shared__ float s2[256];
    __shared__ float lg[10];
    int cloud = blockIdx.x;
    for (int i = TID; i < 1024; i += 256) gg[i] = gfeat[(cloud << 10) + i];
    __syncthreads();
    for (int cc = TID; cc < 512; cc += 256) {
        float v = bh1[cc];
        for (int i = 0; i < 1024; ++i) v = fmaf(gg[i], Wh1[i * 512 + cc], v);
        s1[cc] = fmaxf(v, 0.f);
    }
    __syncthreads();
    for (int cc = TID; cc < 256; cc += 256) {
        float v = bh2[cc];
        for (int i = 0; i < 512; ++i) v = fmaf(s1[i], Wh2[i * 256 + cc], v);
        s2[cc] = fmaxf(v, 0.f);
    }
    __syncthreads();
    if (TID < 10) {
        float v = bh3[TID];
        for (int i = 0; i < 256; ++i) v = fmaf(s2[i], Wh3[i * 10 + TID], v);
        lg[TID] = v;
    }
    __syncthreads();
    if (TID == 0) {
        float mx = lg[0];
        for (int i = 1; i < 10; ++i) mx = fmaxf(mx, lg[i]);
        float s = 0.f;
        for (int i = 0; i < 10; ++i) s += expf(lg[i] - mx);
        float lse = mx + logf(s);
        for (int i = 0; i < 10; ++i) out[cloud * 10 + i] = lg[i] - lse;
    }
}

// ---------------------------------------------------------------------------
// Launch. Workspace layout (12.5 MB total; regions reused across phases).
// ---------------------------------------------------------------------------
extern "C" void kernel_launch(void* const* d_in, const int* in_sizes, int n_in,
                              void* d_out, int out_size, void* d_ws, size_t ws_size,
                              hipStream_t stream) {
    (void)in_sizes; (void)n_in; (void)out_size; (void)ws_size;
    const float* pos = (const float*)d_in[0];
    const float* W1a = (const float*)d_in[1];  const float* b1a = (const float*)d_in[2];
    const float* W1b = (const float*)d_in[3];  const float* b1b = (const float*)d_in[4];
    const float* W1c = (const float*)d_in[5];  const float* b1c = (const float*)d_in[6];
    const float* W2a = (const float*)d_in[7];  const float* b2a = (const float*)d_in[8];
    const float* W2b = (const float*)d_in[9];  const float* b2b = (const float*)d_in[10];
    const float* W2c = (const float*)d_in[11]; const float* b2c = (const float*)d_in[12];
    const float* W3a = (const float*)d_in[13]; const float* b3a = (const float*)d_in[14];
    const float* W3b = (const float*)d_in[15]; const float* b3b = (const float*)d_in[16];
    const float* W3c = (const float*)d_in[17]; const float* b3c = (const float*)d_in[18];
    const float* Wh1 = (const float*)d_in[19]; const float* bh1 = (const float*)d_in[20];
    const float* Wh2 = (const float*)d_in[21]; const float* bh2 = (const float*)d_in[22];
    const float* Wh3 = (const float*)d_in[23]; const float* bh3 = (const float*)d_in[24];

    char* ws = (char*)d_ws;
    float*  curv  = (float*)(ws + 0);
    float4* pos1  = (float4*)(ws + 98304);
    float*  curv1 = (float*)(ws + 229376);
    float4* pos2  = (float4*)(ws + 270336);
    float*  gfeat = (float*)(ws + 303104);
    float*  x1    = (float*)(ws + 524288);
    float*  Abuf  = (float*)(ws + 4718592);
    float*  h1g   = (float*)(ws + 6848512);
    float*  h2g   = x1;     // x1 dead after conv2
    float*  h3g   = Abuf;   // A + h1g dead after gemm2

    curv_kernel<<<64, 256, 0, stream>>>(pos, curv);
    fps1_kernel<<<8, 256, 0, stream>>>(pos, curv, pos1, curv1);
    fps2_conv1_kernel<<<2056, 256, 0, stream>>>(pos, pos1, curv1, pos2, Abuf,
                                                W1a, b1a, W1b, b1b, W1c, b1c, x1);
    conv2_kernel<<<512, 256, 0, stream>>>(pos1, pos2, x1, W2a, b2a, W2b, b2b, W2c, b2c,
                                          Abuf);
    gemm_bias<<<128, 256, 0, stream>>>(Abuf, 260, W3a, 256, b3a, h1g, 256,
                                       2048, 256, 259, 1);
    gemm_bias<<<256, 256, 0, stream>>>(h1g, 256, W3b, 512, b3b, h2g, 512,
                                       2048, 512, 256, 1);
    gemm_bias<<<512, 256, 0, stream>>>(h2g, 512, W3c, 1024, b3c, h3g, 1024,
                                       2048, 1024, 512, 0);
    rowmax_kernel<<<64, 256, 0, stream>>>(h3g, gfeat);
    head_kernel<<<8, 256, 0, stream>>>(gfeat, Wh1, bh1, Wh2, bh2, Wh3, bh3,
                                       (float*)d_out);
}

// Round 6
// 1812.815 us; speedup vs baseline: 2.9413x; 1.0295x over previous
//
#include <hip/hip_runtime.h>
#include <hip/hip_fp16.h>
#include <math.h>

#define TID threadIdx.x

typedef _Float16 h2vec __attribute__((ext_vector_type(2)));
typedef _Float16 f16x8 __attribute__((ext_vector_type(8)));
typedef float f32x4 __attribute__((ext_vector_type(4)));

// fp16 pair dot into fp32 accumulator: v_dot2_f32_f16
static __device__ __forceinline__ float fdot2(unsigned a, unsigned b, float c) {
    h2vec av, bv;
    __builtin_memcpy(&av, &a, 4);
    __builtin_memcpy(&bv, &b, 4);
    return __builtin_amdgcn_fdot2(av, bv, c, false);
}

static __device__ __forceinline__ unsigned packh2(float a, float b) {
    __half2 hh = __floats2half2_rn(a, b);
    unsigned u;
    __builtin_memcpy(&u, &hh, 4);
    return u;
}

static __device__ __forceinline__ int wave_sum(int v) {
#pragma unroll
    for (int o = 32; o >= 1; o >>= 1) v += __shfl_xor(v, o, 64);
    return v;
}

// u64 max with partner brought in by DPP; bound_ctrl=true shifts in 0 (identity).
template <int CTRL>
static __device__ __forceinline__ unsigned long long dpp_max_u64(unsigned long long k) {
    int lo = (int)(unsigned)(k & 0xffffffffULL);
    int hi = (int)(unsigned)(k >> 32);
    int lo2 = __builtin_amdgcn_update_dpp(0, lo, CTRL, 0xf, 0xf, true);
    int hi2 = __builtin_amdgcn_update_dpp(0, hi, CTRL, 0xf, 0xf, true);
    unsigned long long k2 = ((unsigned long long)(unsigned)hi2 << 32) | (unsigned)lo2;
    return k2 > k ? k2 : k;
}

// ---------------------------------------------------------------------------
// Pack Wc (128x256 fp32) into fp16 B-fragment order for mfma_f32_16x16x32_f16:
// frag (ks, ct): lane holds B[k = ks*32 + (lane>>4)*8 + j][cc = ct*16 + (lane&15)]
// stored contiguously -> one coalesced b128 load per fragment in conv2.
// ---------------------------------------------------------------------------
__global__ __launch_bounds__(256) void pack_wc_kernel(const float* __restrict__ Wc,
                                                      unsigned* __restrict__ WcH) {
    int t = blockIdx.x * 256 + TID;     // 4096 slots = 64 frags x 64 lanes
    int lane = t & 63;
    int frag = t >> 6;                  // frag = ks*16 + ct
    int ks = frag >> 4, ct = frag & 15;
    int kbase = (ks << 5) + ((lane >> 4) << 3);
    int cc = (ct << 4) + (lane & 15);
    unsigned o0 = packh2(Wc[(kbase + 0) * 256 + cc], Wc[(kbase + 1) * 256 + cc]);
    unsigned o1 = packh2(Wc[(kbase + 2) * 256 + cc], Wc[(kbase + 3) * 256 + cc]);
    unsigned o2 = packh2(Wc[(kbase + 4) * 256 + cc], Wc[(kbase + 5) * 256 + cc]);
    unsigned o3 = packh2(Wc[(kbase + 6) * 256 + cc], Wc[(kbase + 7) * 256 + cc]);
    *(uint4*)&WcH[(size_t)t * 4] = make_uint4(o0, o1, o2, o3);
}

// ---------------------------------------------------------------------------
// Curvature: per-point 10-NN covariance, lambda_min / sum(lambda)
// ---------------------------------------------------------------------------
__global__ __launch_bounds__(256) void curv_kernel(const float* __restrict__ pos,
                                                   float* __restrict__ curv) {
    __shared__ float4 sp[2048];
    int cloud = blockIdx.x >> 3;
    int base = cloud << 11;
    for (int j = TID; j < 2048; j += 256) {
        const float* p = pos + (size_t)(base + j) * 3;
        float x = p[0], y = p[1], z = p[2];
        sp[j] = make_float4(x, y, z, fmaf(x, x, fmaf(y, y, z * z)));
    }
    __syncthreads();
    int li = ((blockIdx.x & 7) << 8) + TID;
    float4 pi = sp[li];
    float bd[10];
    int bi[10];
#pragma unroll
    for (int t = 0; t < 10; ++t) { bd[t] = 3.0e38f; bi[t] = 0; }
    for (int j = 0; j < 2048; ++j) {
        float4 pj = sp[j];
        float dot = fmaf(pi.x, pj.x, fmaf(pi.y, pj.y, pi.z * pj.z));
        float d2 = pi.w + pj.w - 2.0f * dot;   // same form as reference _sqdist
        if (d2 < bd[9]) {
            bd[9] = d2; bi[9] = j;
#pragma unroll
            for (int t = 9; t > 0; --t) {
                if (bd[t] < bd[t - 1]) {
                    float td = bd[t]; bd[t] = bd[t - 1]; bd[t - 1] = td;
                    int ti = bi[t]; bi[t] = bi[t - 1]; bi[t - 1] = ti;
                }
            }
        }
    }
    double sx = 0, sy = 0, sz = 0;
#pragma unroll
    for (int t = 0; t < 10; ++t) { float4 p = sp[bi[t]]; sx += p.x; sy += p.y; sz += p.z; }
    double mx = sx / 10.0, my = sy / 10.0, mz = sz / 10.0;
    double cxx = 0, cxy = 0, cxz = 0, cyy = 0, cyz = 0, czz = 0;
#pragma unroll
    for (int t = 0; t < 10; ++t) {
        float4 p = sp[bi[t]];
        double dx = p.x - mx, dy = p.y - my, dz = p.z - mz;
        cxx += dx * dx; cxy += dx * dy; cxz += dx * dz;
        cyy += dy * dy; cyz += dy * dz; czz += dz * dz;
    }
    cxx /= 10.0; cxy /= 10.0; cxz /= 10.0; cyy /= 10.0; cyz /= 10.0; czz /= 10.0;
    double q = (cxx + cyy + czz) / 3.0;
    double b00 = cxx - q, b11 = cyy - q, b22 = czz - q;
    double p2 = b00 * b00 + b11 * b11 + b22 * b22 +
                2.0 * (cxy * cxy + cxz * cxz + cyz * cyz);
    double lmin;
    if (p2 <= 0.0) {
        lmin = q;
    } else {
        double p = sqrt(p2 / 6.0);
        double inv = 1.0 / p;
        double c00 = b00 * inv, c01 = cxy * inv, c02 = cxz * inv;
        double c11 = b11 * inv, c12 = cyz * inv, c22 = b22 * inv;
        double detB = c00 * (c11 * c22 - c12 * c12)
                    - c01 * (c01 * c22 - c12 * c02)
                    + c02 * (c01 * c12 - c11 * c02);
        double r = 0.5 * detB;
        r = fmin(1.0, fmax(-1.0, r));
        double phi = acos(r) / 3.0;
        lmin = q + 2.0 * p * cos(phi + 2.0943951023931953);  // smallest eigenvalue
    }
    double s3 = cxx + cyy + czz;
    curv[base + li] = (float)(lmin / (s3 + 1e-8));
}

// ---------------------------------------------------------------------------
// Weighted FPS body (DPP wave-max + single barrier cross-wave fold).
// ---------------------------------------------------------------------------
template <int N, int M, int SLOTS>
static __device__ void fps_body(
    const float* __restrict__ srcpos, int stride, const float* __restrict__ srccurv,
    int cloud, float4* __restrict__ outPos, float* __restrict__ outCurv,
    float* __restrict__ outA, int ldA,
    float4* sp, int* sidx, unsigned long long* rec /* [8] */) {
    const float* cp = srcpos + (size_t)cloud * N * stride;
    for (int j = TID; j < N; j += 256)
        sp[j] = make_float4(cp[j * stride], cp[j * stride + 1], cp[j * stride + 2], 0.f);
    if (TID == 0) sidx[0] = 0;
    __syncthreads();
    float md[SLOTS], wv[SLOTS], px[SLOTS], py[SLOTS], pz[SLOTS];
#pragma unroll
    for (int s = 0; s < SLOTS; ++s) {
        int p = (s << 8) + TID;
        float4 q = sp[p];
        px[s] = q.x; py[s] = q.y; pz[s] = q.z;
        md[s] = 3.0e38f;
        wv[s] = fmaf(10.0f, srccurv[cloud * N + p], 1.0f);
    }
    int lane = TID & 63, w4 = TID >> 6;
    float4 c0 = sp[0];
    float cx = c0.x, cy = c0.y, cz = c0.z;
    for (int t = 1; t < M; ++t) {
        float best = -1.0f;
        int bix = 0;
#pragma unroll
        for (int s = 0; s < SLOTS; ++s) {
            float dx = px[s] - cx, dy = py[s] - cy, dz = pz[s] - cz;
            float nd = fmaf(dx, dx, fmaf(dy, dy, dz * dz));
            float m2 = fminf(md[s], nd);
            md[s] = m2;
            float sc = m2 * wv[s];
            bool g = sc > best;           // strict > keeps earliest (lowest idx)
            best = g ? sc : best;
            bix = g ? ((s << 8) + TID) : bix;
        }
        // score >= 0 always -> float bits monotone under unsigned compare
        unsigned long long k =
            ((unsigned long long)__float_as_uint(best) << 32) | (unsigned)(2047 - bix);
        k = dpp_max_u64<0x111>(k);   // row_shr:1
        k = dpp_max_u64<0x112>(k);   // row_shr:2
        k = dpp_max_u64<0x114>(k);   // row_shr:4
        k = dpp_max_u64<0x118>(k);   // row_shr:8
        k = dpp_max_u64<0x142>(k);   // row_bcast15
        k = dpp_max_u64<0x143>(k);   // row_bcast31 -> lane63 has wave max
        int pbase = (t & 1) << 2;
        if (lane == 63) rec[pbase | w4] = k;
        __syncthreads();
        unsigned long long k0 = rec[pbase + 0];
        unsigned long long k1 = rec[pbase + 1];
        unsigned long long k2 = rec[pbase + 2];
        unsigned long long k3 = rec[pbase + 3];
        unsigned long long ka = k0 > k1 ? k0 : k1;
        unsigned long long kb = k2 > k3 ? k2 : k3;
        unsigned long long km = ka > kb ? ka : kb;
        int nbix = 2047 - (int)(unsigned)(km & 0xffffffffULL);  // uniform winner
        if (TID == 0) sidx[t] = nbix;
        float4 cc = sp[nbix];        // uniform (broadcast) read
        cx = cc.x; cy = cc.y; cz = cc.z;
    }
    __syncthreads();
    for (int j = TID; j < M; j += 256) {
        int id = sidx[j];
        float4 qv = sp[id];
        outPos[cloud * M + j] = qv;
        if (outCurv) outCurv[cloud * M + j] = srccurv[cloud * N + id];
        if (outA) {
            float* a = outA + (size_t)(cloud * M + j) * ldA;
            a[256] = qv.x; a[257] = qv.y; a[258] = qv.z;
        }
    }
}

// Standalone fps1 (2048 -> 1024)
__global__ __launch_bounds__(256, 1) void fps1_kernel(
    const float* __restrict__ pos, const float* __restrict__ curv,
    float4* __restrict__ pos1, float* __restrict__ curv1) {
    __shared__ float4 sp[2048];
    __shared__ int sidx[1024];
    __shared__ unsigned long long rec[8];
    fps_body<2048, 1024, 8>(pos, 3, curv, blockIdx.x, pos1, curv1, nullptr, 0,
                            sp, sidx, rec);
}

// ---------------------------------------------------------------------------
// Exact top-64 (smallest d2, idx tie-break) selection within one wave.
// ---------------------------------------------------------------------------
static __device__ __forceinline__ int select_k64(const unsigned int* ck, const int* ci,
                                                 int c, int lane, int* cnt2, int* sel,
                                                 int* nbOut) {
    if (c <= 64) {
        *nbOut = c;
        return (lane < c) ? ci[lane] : 0;
    }
    unsigned int T = 0;  // becomes the 64th-smallest key
    for (int bit = 31; bit >= 0; --bit) {
        unsigned int mid = T | (1u << bit);
        int cl = 0;
        for (int q = lane; q < c; q += 64) cl += (ck[q] < mid) ? 1 : 0;
        if (wave_sum(cl) < 64) T = mid;
    }
    int cl = 0;
    for (int q = lane; q < c; q += 64) cl += (ck[q] < T) ? 1 : 0;
    int need = 64 - wave_sum(cl);
    int TI = 0;  // becomes the need-th smallest idx among keys == T
    for (int bit = 11; bit >= 0; --bit) {
        int mid = TI | (1 << bit);
        int ce = 0;
        for (int q = lane; q < c; q += 64) ce += (ck[q] == T && ci[q] < mid) ? 1 : 0;
        if (wave_sum(ce) < need) TI = mid;
    }
    for (int q = lane; q < c; q += 64) {
        unsigned int kq = ck[q];
        int iq = ci[q];
        if (kq < T || (kq == T && iq <= TI)) sel[atomicAdd(cnt2, 1)] = iq;
    }
    *nbOut = 64;
    return sel[lane];
}

// ---------------------------------------------------------------------------
// SA1 conv body (3->64->64->128). h2 staged to LDS as fp16 pairs; L3 is
// weights-stationary: lane = channel (wave-pair covers 128 ch), fdot2 inner.
// ---------------------------------------------------------------------------
union U1 {
    struct {
        float4 sp[2048];
        unsigned ck[4][256];
        int ci[4][256];
        int sel[4][64];
        int cnt[4], cnt2[4];
    } p;
    unsigned h2s[4][2048];   // [cent][n*32 + ((q*4) ^ ((n&7)*4)) + k], half2 elems
};

static __device__ void conv1_body(
    int bid, U1& u,
    const float* __restrict__ pos, const float4* __restrict__ pos1,
    const float* __restrict__ W1, const float* __restrict__ B1,
    const float* __restrict__ W2, const float* __restrict__ B2,
    const float* __restrict__ W3, const float* __restrict__ B3,
    float* __restrict__ x1) {
    __shared__ int nbs[4];
    int cloud = bid >> 8;
    int w4 = TID >> 6, lane = TID & 63;
    int centb = (bid & 255) << 2;
    int g = (cloud << 10) + centb + w4;
    int base = cloud << 11;
    for (int j = TID; j < 2048; j += 256) {
        const float* p = pos + (size_t)(base + j) * 3;
        u.p.sp[j] = make_float4(p[0], p[1], p[2], 0.f);
    }
    if (lane == 0) { u.p.cnt[w4] = 0; u.p.cnt2[w4] = 0; }
    __syncthreads();
    float4 cq = pos1[g];
    double cx = cq.x, cy = cq.y, cz = cq.z;
    for (int s = 0; s < 32; ++s) {
        int j = (s << 6) + lane;
        float4 pj = u.p.sp[j];
        double dx = (double)pj.x - cx, dy = (double)pj.y - cy, dz = (double)pj.z - cz;
        double d2 = dx * dx + dy * dy + dz * dz;
        if (d2 <= 0.2 * 0.2) {
            int p = atomicAdd(&u.p.cnt[w4], 1);
            if (p < 256) { u.p.ck[w4][p] = __float_as_uint((float)d2); u.p.ci[w4][p] = j; }
        }
    }
    __syncthreads();
    int c = min(u.p.cnt[w4], 256);
    int nb;
    int idxn = select_k64(u.p.ck[w4], u.p.ci[w4], c, lane, &u.p.cnt2[w4],
                          u.p.sel[w4], &nb);
    if (lane == 0) nbs[w4] = nb;
    float4 pn = u.p.sp[idxn];
    float rx = pn.x - cq.x, ry = pn.y - cq.y, rz = pn.z - cq.z;
    float h1[64];
#pragma unroll
    for (int cc2 = 0; cc2 < 64; ++cc2) {
        float v = fmaf(rx, W1[cc2], fmaf(ry, W1[64 + cc2], fmaf(rz, W1[128 + cc2], B1[cc2])));
        h1[cc2] = fmaxf(v, 0.f);
    }
    float h2[64];
#pragma unroll
    for (int cc2 = 0; cc2 < 64; ++cc2) h2[cc2] = B2[cc2];
#pragma unroll
    for (int i = 0; i < 64; ++i) {
        float hv = h1[i];
        const float* wr = W2 + i * 64;
#pragma unroll
        for (int cc2 = 0; cc2 < 64; ++cc2) h2[cc2] = fmaf(hv, wr[cc2], h2[cc2]);
    }
#pragma unroll
    for (int cc2 = 0; cc2 < 64; ++cc2) h2[cc2] = fmaxf(h2[cc2], 0.f);
    __syncthreads();   // all waves done with grouping buffers / sp
    {
        unsigned* hrow = &u.h2s[w4][lane << 5];
        int sw = (lane & 7) << 2;
#pragma unroll
        for (int q = 0; q < 8; ++q) {
            unsigned tmp[4];
#pragma unroll
            for (int k2 = 0; k2 < 4; ++k2) {
                int j = (q << 2) + k2;
                tmp[k2] = packh2(h2[2 * j], h2[2 * j + 1]);
            }
            *(uint4*)&hrow[(q << 2) ^ sw] = make_uint4(tmp[0], tmp[1], tmp[2], tmp[3]);
        }
    }
    __syncthreads();   // h2s + nbs visible block-wide
    // L3: lane = channel (wave pairs cover 128 ch), 2 centroids per lane
    int ch = ((w4 & 1) << 6) + lane;
    int cbase = (w4 >> 1) << 1;
    unsigned w2[32];
#pragma unroll
    for (int p = 0; p < 32; ++p)
        w2[p] = packh2(W3[(2 * p) * 128 + ch], W3[(2 * p + 1) * 128 + ch]);
    float bv = B3[ch];
#pragma unroll 1
    for (int ci2 = 0; ci2 < 2; ++ci2) {
        int cc = cbase + ci2;
        int nbc = nbs[cc];
        float m = -1e30f;
        for (int n = 0; n < nbc; ++n) {
            const unsigned* hr = &u.h2s[cc][n << 5];
            int sw2 = (n & 7) << 2;
            float a0 = 0.f, a1 = 0.f, a2 = 0.f, a3 = 0.f;
#pragma unroll
            for (int q = 0; q < 8; ++q) {
                uint4 hv = *(const uint4*)&hr[(q << 2) ^ sw2];
                a0 = fdot2(hv.x, w2[(q << 2) + 0], a0);
                a1 = fdot2(hv.y, w2[(q << 2) + 1], a1);
                a2 = fdot2(hv.z, w2[(q << 2) + 2], a2);
                a3 = fdot2(hv.w, w2[(q << 2) + 3], a3);
            }
            m = fmaxf(m, bv + (a0 + a1) + (a2 + a3));
        }
        x1[(size_t)((cloud << 10) + centb + cc) * 128 + ch] = m;
    }
}

// ---------------------------------------------------------------------------
// Merged launch: blocks 0-7 run fps2 (1024->256), blocks 8.. run conv1.
// ---------------------------------------------------------------------------
union UM {
    U1 c;
    struct {
        float4 sp[1024];
        unsigned long long rec[8];
        int sidx[256];
    } f;
};

__global__ __launch_bounds__(256, 2) void fps2_conv1_kernel(
    const float* __restrict__ pos, const float4* __restrict__ pos1,
    const float* __restrict__ curv1, float4* __restrict__ pos2,
    float* __restrict__ Abuf,
    const float* __restrict__ W1, const float* __restrict__ B1,
    const float* __restrict__ W2, const float* __restrict__ B2,
    const float* __restrict__ W3, const float* __restrict__ B3,
    float* __restrict__ x1) {
    __shared__ UM u;
    if (blockIdx.x < 8) {
        fps_body<1024, 256, 4>((const float*)pos1, 4, curv1, blockIdx.x, pos2,
                               nullptr, Abuf, 260, u.f.sp, u.f.sidx, u.f.rec);
    } else {
        conv1_body(blockIdx.x - 8, u.c, pos, pos1, W1, B1, W2, B2, W3, B3, x1);
    }
}

// ---------------------------------------------------------------------------
// SA2: radius r=0.4 grouping + PointNetConv(131->128->128->256).
// L3 as MFMA GEMM: per block C[256 n, 256 cc] = h2s[256,128]f16 x WcH[128,256]f16
// via v_mfma_f32_16x16x32_f16; masked max folded per C-tile in registers.
// h2s layout: row n = cent*64+l (256 B fp16), 16B-chunk c stored at c^(l&15)
// -> structurally minimal LDS phases on both store and A-fragment read.
// ---------------------------------------------------------------------------
union U2 {
    struct {
        float4 sp[1024];
        unsigned ck[4][512];
        int ci[4][512];
        int sel[4][64];
        int cnt[4], cnt2[4];
    } p;
    unsigned h2s[4][4096];  // [cent][row l: l*64 dwords, chunk-swizzled]
};

__global__ __launch_bounds__(256, 2) void conv2_kernel(
    const float4* __restrict__ pos1, const float4* __restrict__ pos2,
    const float* __restrict__ x1,
    const float* __restrict__ Wa, const float* __restrict__ Ba,
    const float* __restrict__ Wb, const float* __restrict__ Bb,
    const unsigned* __restrict__ WcH, const float* __restrict__ Bc,
    float* __restrict__ Aout) {
    __shared__ U2 u;
    __shared__ int nbs[4];
    int cloud = blockIdx.x >> 6;
    int w4 = TID >> 6, lane = TID & 63;
    int centb = (blockIdx.x & 63) << 2;
    int g = (cloud << 8) + centb + w4;
    for (int j = TID; j < 1024; j += 256) u.p.sp[j] = pos1[(cloud << 10) + j];
    if (lane == 0) { u.p.cnt[w4] = 0; u.p.cnt2[w4] = 0; }
    __syncthreads();
    float4 cq = pos2[g];
    double cx = cq.x, cy = cq.y, cz = cq.z;
    for (int s = 0; s < 16; ++s) {
        int j = (s << 6) + lane;
        float4 pj = u.p.sp[j];
        double dx = (double)pj.x - cx, dy = (double)pj.y - cy, dz = (double)pj.z - cz;
        double d2 = dx * dx + dy * dy + dz * dz;
        if (d2 <= 0.4 * 0.4) {
            int p = atomicAdd(&u.p.cnt[w4], 1);
            if (p < 512) { u.p.ck[w4][p] = __float_as_uint((float)d2); u.p.ci[w4][p] = j; }
        }
    }
    __syncthreads();
    int c = min(u.p.cnt[w4], 512);
    int nb;
    int idxn = select_k64(u.p.ck[w4], u.p.ci[w4], c, lane, &u.p.cnt2[w4],
                          u.p.sel[w4], &nb);
    if (lane == 0) nbs[w4] = nb;
    float4 pn = u.p.sp[idxn];
    float rx = pn.x - cq.x, ry = pn.y - cq.y, rz = pn.z - cq.z;
    const float4* xr = (const float4*)(x1 + (size_t)((cloud << 10) + idxn) * 128);
    // L1 (131 -> 128, relu) fused with L2 (128 -> 128) in two 64-channel halves.
    float h2[128];
#pragma unroll
    for (int cc2 = 0; cc2 < 128; ++cc2) h2[cc2] = Bb[cc2];
#pragma unroll
    for (int half = 0; half < 2; ++half) {
        float h1[64];
#pragma unroll
        for (int cc2 = 0; cc2 < 64; ++cc2) h1[cc2] = Ba[(half << 6) + cc2];
        for (int ic = 0; ic < 32; ++ic) {
            float4 xv = xr[ic];
            const float* wr = Wa + (ic * 4) * 128 + (half << 6);
#pragma unroll
            for (int ii = 0; ii < 4; ++ii) {
                float xs = (&xv.x)[ii];
#pragma unroll
                for (int cc2 = 0; cc2 < 64; ++cc2)
                    h1[cc2] = fmaf(xs, wr[ii * 128 + cc2], h1[cc2]);
            }
        }
#pragma unroll
        for (int cc2 = 0; cc2 < 64; ++cc2) {
            float v = fmaf(rx, Wa[128 * 128 + (half << 6) + cc2],
                    fmaf(ry, Wa[129 * 128 + (half << 6) + cc2],
                    fmaf(rz, Wa[130 * 128 + (half << 6) + cc2], h1[cc2])));
            h1[cc2] = fmaxf(v, 0.f);
        }
#pragma unroll
        for (int i = 0; i < 64; ++i) {
            float hv = h1[i];
            const float* wr = Wb + ((half << 6) + i) * 128;
#pragma unroll
            for (int cc2 = 0; cc2 < 128; ++cc2) h2[cc2] = fmaf(hv, wr[cc2], h2[cc2]);
        }
    }
#pragma unroll
    for (int cc2 = 0; cc2 < 128; ++cc2) h2[cc2] = fmaxf(h2[cc2], 0.f);
    __syncthreads();   // all waves done with grouping buffers / sp
    // stage h2 fp16, row l = lane within cent w4; chunk c (16B) stored at c^(l&15)
    {
        unsigned* hrow = &u.h2s[w4][lane << 6];
        int sw = lane & 15;
#pragma unroll
        for (int q = 0; q < 16; ++q) {
            unsigned tmp[4];
#pragma unroll
            for (int k2 = 0; k2 < 4; ++k2) {
                int j = (q << 2) + k2;
                tmp[k2] = packh2(h2[2 * j], h2[2 * j + 1]);
            }
            *(uint4*)&hrow[(q ^ sw) << 2] = make_uint4(tmp[0], tmp[1], tmp[2], tmp[3]);
        }
    }
    __syncthreads();   // h2s + nbs visible block-wide
    // --- MFMA L3: wave w4 owns col-tiles [4*w4, 4*w4+4) of 16 ---
    int quad = lane >> 4, l15 = lane & 15;
    int ctb = w4 << 2;
    f16x8 bfrag[4][4];   // [ct][ks]
#pragma unroll
    for (int ct = 0; ct < 4; ++ct)
#pragma unroll
        for (int ks = 0; ks < 4; ++ks) {
            uint4 bv = *(const uint4*)&WcH[(size_t)((((ks << 4) | (ctb + ct)) << 6) | lane) << 2];
            __builtin_memcpy(&bfrag[ct][ks], &bv, 16);
        }
#pragma unroll 1
    for (int cent = 0; cent < 4; ++cent) {
        int nbc = nbs[cent];
        float runM[4][4];
#pragma unroll
        for (int ct = 0; ct < 4; ++ct)
#pragma unroll
            for (int r = 0; r < 4; ++r) runM[ct][r] = -1e30f;
#pragma unroll
        for (int rt = 0; rt < 4; ++rt) {
            int nl = (rt << 4) + l15;          // A row (neighbor) for this lane
            f16x8 afrag[4];
#pragma unroll
            for (int ks = 0; ks < 4; ++ks) {
                int cp = ((ks << 2) | quad) ^ l15;
                uint4 av = *(const uint4*)&u.h2s[cent][(nl << 6) + (cp << 2)];
                __builtin_memcpy(&afrag[ks], &av, 16);
            }
#pragma unroll
            for (int ct = 0; ct < 4; ++ct) {
                f32x4 acc = {0.f, 0.f, 0.f, 0.f};
#pragma unroll
                for (int ks = 0; ks < 4; ++ks)
                    acc = __builtin_amdgcn_mfma_f32_16x16x32_f16(afrag[ks], bfrag[ct][ks],
                                                                 acc, 0, 0, 0);
                int nb0 = (rt << 4) + (quad << 2);   // C row = quad*4 + r
#pragma unroll
                for (int r = 0; r < 4; ++r) {
                    float v = (nb0 + r < nbc) ? acc[r] : -1e30f;
                    runM[ct][r] = fmaxf(runM[ct][r], v);
                }
            }
        }
#pragma unroll
        for (int ct = 0; ct < 4; ++ct) {
            float m = fmaxf(fmaxf(runM[ct][0], runM[ct][1]),
                            fmaxf(runM[ct][2], runM[ct][3]));
            m = fmaxf(m, __shfl_xor(m, 16, 64));
            m = fmaxf(m, __shfl_xor(m, 32, 64));
            if (lane < 16) {
                int cc = ((ctb + ct) << 4) | l15;   // C col = lane&15
                Aout[(size_t)((cloud << 8) + centb + cent) * 260 + cc] = m + Bc[cc];
            }
        }
    }
}

// ---------------------------------------------------------------------------
// fp32 tiled GEMM: C[M,N] = A[M,K] @ B[K,N] + bias (+relu). 64x64 tiles.
// ---------------------------------------------------------------------------
__global__ __launch_bounds__(256, 2) void gemm_bias(
    const float* __restrict__ A, int lda, const float* __restrict__ Bw, int ldb,
    const float* __restrict__ bias, float* __restrict__ C, int ldc,
    int M, int N, int K, int relu) {
    __shared__ float As[16][68];
    __shared__ float Bs[16][68];
    int nbx = N >> 6;
    int bx = blockIdx.x % nbx, by = blockIdx.x / nbx;
    int tx = TID & 15, ty = TID >> 4;
    int r0 = by << 6, c0 = bx << 6;
    float acc[4][4];
#pragma unroll
    for (int i = 0; i < 4; ++i)
#pragma unroll
        for (int j = 0; j < 4; ++j) acc[i][j] = 0.f;
    int lr = TID >> 2, lk = (TID & 3) << 2;
    int ln = TID & 63, lk2 = TID >> 6;
    for (int k0 = 0; k0 < K; k0 += 16) {
#pragma unroll
        for (int u = 0; u < 4; ++u) {
            int kk = k0 + lk + u;
            As[lk + u][lr] = (kk < K) ? A[(size_t)(r0 + lr) * lda + kk] : 0.f;
        }
#pragma unroll
        for (int u = 0; u < 4; ++u) {
            int krow = lk2 + (u << 2);
            int kk = k0 + krow;
            Bs[krow][ln] = (kk < K) ? Bw[(size_t)kk * ldb + c0 + ln] : 0.f;
        }
        __syncthreads();
#pragma unroll
        for (int kk = 0; kk < 16; ++kk) {
            float av[4], bv[4];
#pragma unroll
            for (int i = 0; i < 4; ++i) av[i] = As[kk][(ty << 2) + i];
#pragma unroll
            for (int j = 0; j < 4; ++j) bv[j] = Bs[kk][(tx << 2) + j];
#pragma unroll
            for (int i = 0; i < 4; ++i)
#pragma unroll
                for (int j = 0; j < 4; ++j) acc[i][j] = fmaf(av[i], bv[j], acc[i][j]);
        }
        __syncthreads();
    }
#pragma unroll
    for (int i = 0; i < 4; ++i) {
        int row = r0 + (ty << 2) + i;
#pragma unroll
        for (int j = 0; j < 4; ++j) {
            int col = c0 + (tx << 2) + j;
            float v = acc[i][j] + bias[col];
            if (relu) v = fmaxf(v, 0.f);
            C[(size_t)row * ldc + col] = v;
        }
    }
}

// ---------------------------------------------------------------------------
// Per-cloud max over 256 rows of h3 -> gfeat[8][1024]. 64 blocks (8/cloud).
// ---------------------------------------------------------------------------
__global__ __launch_bounds__(256) void rowmax_kernel(const float* __restrict__ h3,
                                                     float* __restrict__ gfeat) {
    __shared__ float pm[256];
    int cloud = blockIdx.x >> 3;
    int seg = blockIdx.x & 7;
    int col = (seg << 7) + (TID & 127);
    int half = TID >> 7;
    float m = -3.0e38f;
    for (int r = half << 7; r < (half << 7) + 128; ++r)
        m = fmaxf(m, h3[(size_t)((cloud << 8) + r) * 1024 + col]);
    pm[TID] = m;
    __syncthreads();
    if (TID < 128) gfeat[(cloud << 10) + col] = fmaxf(pm[TID], pm[TID + 128]);
}

// ---------------------------------------------------------------------------
// Head MLP 1024->512->256->10 + log_softmax (one block per cloud)
// ---------------------------------------------------------------------------
__global__ __launch_bounds__(256) void head_kernel(
    const float* __restrict__ gfeat,
    const float* __restrict__ Wh1, const float* __restrict__ bh1,
    const float* __restrict__ Wh2, const float* __restrict__ bh2,
    const float* __restrict__ Wh3, const float* __restrict__ bh3,
    float* __restrict__ out) {
    __shared__ float gg[1024];
    __shared__ float s1[512];
    __shared__ float s2[256];
    __shared__ float lg[10];
    int cloud = blockIdx.x;
    for (int i = TID; i < 1024; i += 256) gg[i] = gfeat[(cloud << 10) + i];
    __syncthreads();
    for (int cc = TID; cc < 512; cc += 256) {
        float v = bh1[cc];
        for (int i = 0; i < 1024; ++i) v = fmaf(gg[i], Wh1[i * 512 + cc], v);
        s1[cc] = fmaxf(v, 0.f);
    }
    __syncthreads();
    for (int cc = TID; cc < 256; cc += 256) {
        float v = bh2[cc];
        for (int i = 0; i < 512; ++i) v = fmaf(s1[i], Wh2[i * 256 + cc], v);
        s2[cc] = fmaxf(v, 0.f);
    }
    __syncthreads();
    if (TID < 10) {
        float v = bh3[TID];
        for (int i = 0; i < 256; ++i) v = fmaf(s2[i], Wh3[i * 10 + TID], v);
        lg[TID] = v;
    }
    __syncthreads();
    if (TID == 0) {
        float mx = lg[0];
        for (int i = 1; i < 10; ++i) mx = fmaxf(mx, lg[i]);
        float s = 0.f;
        for (int i = 0; i < 10; ++i) s += expf(lg[i] - mx);
        float lse = mx + logf(s);
        for (int i = 0; i < 10; ++i) out[cloud * 10 + i] = lg[i] - lse;
    }
}

// ---------------------------------------------------------------------------
// Launch. Workspace layout (12.5 MB total; regions reused across phases).
// WcH (64 KB, fp16 fragment-packed W2c) lives at 335872..401407.
// ---------------------------------------------------------------------------
extern "C" void kernel_launch(void* const* d_in, const int* in_sizes, int n_in,
                              void* d_out, int out_size, void* d_ws, size_t ws_size,
                              hipStream_t stream) {
    (void)in_sizes; (void)n_in; (void)out_size; (void)ws_size;
    const float* pos = (const float*)d_in[0];
    const float* W1a = (const float*)d_in[1];  const float* b1a = (const float*)d_in[2];
    const float* W1b = (const float*)d_in[3];  const float* b1b = (const float*)d_in[4];
    const float* W1c = (const float*)d_in[5];  const float* b1c = (const float*)d_in[6];
    const float* W2a = (const float*)d_in[7];  const float* b2a = (const float*)d_in[8];
    const float* W2b = (const float*)d_in[9];  const float* b2b = (const float*)d_in[10];
    const float* W2c = (const float*)d_in[11]; const float* b2c = (const float*)d_in[12];
    const float* W3a = (const float*)d_in[13]; const float* b3a = (const float*)d_in[14];
    const float* W3b = (const float*)d_in[15]; const float* b3b = (const float*)d_in[16];
    const float* W3c = (const float*)d_in[17]; const float* b3c = (const float*)d_in[18];
    const float* Wh1 = (const float*)d_in[19]; const float* bh1 = (const float*)d_in[20];
    const float* Wh2 = (const float*)d_in[21]; const float* bh2 = (const float*)d_in[22];
    const float* Wh3 = (const float*)d_in[23]; const float* bh3 = (const float*)d_in[24];

    char* ws = (char*)d_ws;
    float*    curv  = (float*)(ws + 0);
    float4*   pos1  = (float4*)(ws + 98304);
    float*    curv1 = (float*)(ws + 229376);
    float4*   pos2  = (float4*)(ws + 270336);
    float*    gfeat = (float*)(ws + 303104);
    unsigned* WcH   = (unsigned*)(ws + 335872);
    float*    x1    = (float*)(ws + 524288);
    float*    Abuf  = (float*)(ws + 4718592);
    float*    h1g   = (float*)(ws + 6848512);
    float*    h2g   = x1;     // x1 dead after conv2
    float*    h3g   = Abuf;   // A + h1g dead after gemm2

    pack_wc_kernel<<<16, 256, 0, stream>>>(W2c, WcH);
    curv_kernel<<<64, 256, 0, stream>>>(pos, curv);
    fps1_kernel<<<8, 256, 0, stream>>>(pos, curv, pos1, curv1);
    fps2_conv1_kernel<<<2056, 256, 0, stream>>>(pos, pos1, curv1, pos2, Abuf,
                                                W1a, b1a, W1b, b1b, W1c, b1c, x1);
    conv2_kernel<<<512, 256, 0, stream>>>(pos1, pos2, x1, W2a, b2a, W2b, b2b, WcH, b2c,
                                          Abuf);
    gemm_bias<<<128, 256, 0, stream>>>(Abuf, 260, W3a, 256, b3a, h1g, 256,
                                       2048, 256, 259, 1);
    gemm_bias<<<256, 256, 0, stream>>>(h1g, 256, W3b, 512, b3b, h2g, 512,
                                       2048, 512, 256, 1);
    gemm_bias<<<512, 256, 0, stream>>>(h2g, 512, W3c, 1024, b3c, h3g, 1024,
                                       2048, 1024, 512, 0);
    rowmax_kernel<<<64, 256, 0, stream>>>(h3g, gfeat);
    head_kernel<<<8, 256, 0, stream>>>(gfeat, Wh1, bh1, Wh2, bh2, Wh3, bh3,
                                       (float*)d_out);
}

// Round 7
// 1480.811 us; speedup vs baseline: 3.6007x; 1.2242x over previous
//
#include <hip/hip_runtime.h>
#include <hip/hip_fp16.h>
#include <math.h>

#define TID threadIdx.x

typedef _Float16 h2vec __attribute__((ext_vector_type(2)));
typedef _Float16 f16x8 __attribute__((ext_vector_type(8)));
typedef float f32x4 __attribute__((ext_vector_type(4)));

// fp16 pair dot into fp32 accumulator: v_dot2_f32_f16
static __device__ __forceinline__ float fdot2(unsigned a, unsigned b, float c) {
    h2vec av, bv;
    __builtin_memcpy(&av, &a, 4);
    __builtin_memcpy(&bv, &b, 4);
    return __builtin_amdgcn_fdot2(av, bv, c, false);
}

static __device__ __forceinline__ unsigned packh2(float a, float b) {
    __half2 hh = __floats2half2_rn(a, b);
    unsigned u;
    __builtin_memcpy(&u, &hh, 4);
    return u;
}

static __device__ __forceinline__ int wave_sum(int v) {
#pragma unroll
    for (int o = 32; o >= 1; o >>= 1) v += __shfl_xor(v, o, 64);
    return v;
}

// u64 max with partner brought in by DPP; bound_ctrl=true shifts in 0 (identity).
template <int CTRL>
static __device__ __forceinline__ unsigned long long dpp_max_u64(unsigned long long k) {
    int lo = (int)(unsigned)(k & 0xffffffffULL);
    int hi = (int)(unsigned)(k >> 32);
    int lo2 = __builtin_amdgcn_update_dpp(0, lo, CTRL, 0xf, 0xf, true);
    int hi2 = __builtin_amdgcn_update_dpp(0, hi, CTRL, 0xf, 0xf, true);
    unsigned long long k2 = ((unsigned long long)(unsigned)hi2 << 32) | (unsigned)lo2;
    return k2 > k ? k2 : k;
}

// ---------------------------------------------------------------------------
// Generic fp32 -> fp16 B-fragment pack for mfma_f32_16x16x32_f16.
// frag f = ks*(ncols/16) + ct: lane holds B[k=ks*32+(lane>>4)*8+j][ct*16+(lane&15)]
// rows k >= K read as 0 (K-padding). One coalesced uint4 per (frag,lane).
// ---------------------------------------------------------------------------
__global__ __launch_bounds__(256) void pack_w_kernel(const float* __restrict__ W,
                                                     unsigned* __restrict__ out,
                                                     int K, int ncols) {
    int t = blockIdx.x * 256 + TID;
    int lane = t & 63;
    int frag = t >> 6;
    int nct = ncols >> 4;
    int ks = frag / nct, ct = frag - ks * nct;
    int kbase = (ks << 5) + ((lane >> 4) << 3);
    int cc = (ct << 4) + (lane & 15);
    unsigned o[4];
#pragma unroll
    for (int i = 0; i < 4; ++i) {
        int k0 = kbase + 2 * i, k1 = kbase + 2 * i + 1;
        float f0 = (k0 < K) ? W[(size_t)k0 * ncols + cc] : 0.f;
        float f1 = (k1 < K) ? W[(size_t)k1 * ncols + cc] : 0.f;
        o[i] = packh2(f0, f1);
    }
    *(uint4*)&out[(size_t)t * 4] = make_uint4(o[0], o[1], o[2], o[3]);
}

// ---------------------------------------------------------------------------
// Curvature: per-point 10-NN covariance, lambda_min / sum(lambda)
// ---------------------------------------------------------------------------
__global__ __launch_bounds__(256) void curv_kernel(const float* __restrict__ pos,
                                                   float* __restrict__ curv) {
    __shared__ float4 sp[2048];
    int cloud = blockIdx.x >> 3;
    int base = cloud << 11;
    for (int j = TID; j < 2048; j += 256) {
        const float* p = pos + (size_t)(base + j) * 3;
        float x = p[0], y = p[1], z = p[2];
        sp[j] = make_float4(x, y, z, fmaf(x, x, fmaf(y, y, z * z)));
    }
    __syncthreads();
    int li = ((blockIdx.x & 7) << 8) + TID;
    float4 pi = sp[li];
    float bd[10];
    int bi[10];
#pragma unroll
    for (int t = 0; t < 10; ++t) { bd[t] = 3.0e38f; bi[t] = 0; }
    for (int j = 0; j < 2048; ++j) {
        float4 pj = sp[j];
        float dot = fmaf(pi.x, pj.x, fmaf(pi.y, pj.y, pi.z * pj.z));
        float d2 = pi.w + pj.w - 2.0f * dot;   // same form as reference _sqdist
        if (d2 < bd[9]) {
            bd[9] = d2; bi[9] = j;
#pragma unroll
            for (int t = 9; t > 0; --t) {
                if (bd[t] < bd[t - 1]) {
                    float td = bd[t]; bd[t] = bd[t - 1]; bd[t - 1] = td;
                    int ti = bi[t]; bi[t] = bi[t - 1]; bi[t - 1] = ti;
                }
            }
        }
    }
    double sx = 0, sy = 0, sz = 0;
#pragma unroll
    for (int t = 0; t < 10; ++t) { float4 p = sp[bi[t]]; sx += p.x; sy += p.y; sz += p.z; }
    double mx = sx / 10.0, my = sy / 10.0, mz = sz / 10.0;
    double cxx = 0, cxy = 0, cxz = 0, cyy = 0, cyz = 0, czz = 0;
#pragma unroll
    for (int t = 0; t < 10; ++t) {
        float4 p = sp[bi[t]];
        double dx = p.x - mx, dy = p.y - my, dz = p.z - mz;
        cxx += dx * dx; cxy += dx * dy; cxz += dx * dz;
        cyy += dy * dy; cyz += dy * dz; czz += dz * dz;
    }
    cxx /= 10.0; cxy /= 10.0; cxz /= 10.0; cyy /= 10.0; cyz /= 10.0; czz /= 10.0;
    double q = (cxx + cyy + czz) / 3.0;
    double b00 = cxx - q, b11 = cyy - q, b22 = czz - q;
    double p2 = b00 * b00 + b11 * b11 + b22 * b22 +
                2.0 * (cxy * cxy + cxz * cxz + cyz * cyz);
    double lmin;
    if (p2 <= 0.0) {
        lmin = q;
    } else {
        double p = sqrt(p2 / 6.0);
        double inv = 1.0 / p;
        double c00 = b00 * inv, c01 = cxy * inv, c02 = cxz * inv;
        double c11 = b11 * inv, c12 = cyz * inv, c22 = b22 * inv;
        double detB = c00 * (c11 * c22 - c12 * c12)
                    - c01 * (c01 * c22 - c12 * c02)
                    + c02 * (c01 * c12 - c11 * c02);
        double r = 0.5 * detB;
        r = fmin(1.0, fmax(-1.0, r));
        double phi = acos(r) / 3.0;
        lmin = q + 2.0 * p * cos(phi + 2.0943951023931953);  // smallest eigenvalue
    }
    double s3 = cxx + cyy + czz;
    curv[base + li] = (float)(lmin / (s3 + 1e-8));
}

// ---------------------------------------------------------------------------
// Weighted FPS body (DPP wave-max + single barrier cross-wave fold).
// ---------------------------------------------------------------------------
template <int N, int M, int SLOTS>
static __device__ void fps_body(
    const float* __restrict__ srcpos, int stride, const float* __restrict__ srccurv,
    int cloud, float4* __restrict__ outPos, float* __restrict__ outCurv,
    float* __restrict__ outA, int ldA,
    float4* sp, int* sidx, unsigned long long* rec /* [8] */) {
    const float* cp = srcpos + (size_t)cloud * N * stride;
    for (int j = TID; j < N; j += 256)
        sp[j] = make_float4(cp[j * stride], cp[j * stride + 1], cp[j * stride + 2], 0.f);
    if (TID == 0) sidx[0] = 0;
    __syncthreads();
    float md[SLOTS], wv[SLOTS], px[SLOTS], py[SLOTS], pz[SLOTS];
#pragma unroll
    for (int s = 0; s < SLOTS; ++s) {
        int p = (s << 8) + TID;
        float4 q = sp[p];
        px[s] = q.x; py[s] = q.y; pz[s] = q.z;
        md[s] = 3.0e38f;
        wv[s] = fmaf(10.0f, srccurv[cloud * N + p], 1.0f);
    }
    int lane = TID & 63, w4 = TID >> 6;
    float4 c0 = sp[0];
    float cx = c0.x, cy = c0.y, cz = c0.z;
    for (int t = 1; t < M; ++t) {
        float best = -1.0f;
        int bix = 0;
#pragma unroll
        for (int s = 0; s < SLOTS; ++s) {
            float dx = px[s] - cx, dy = py[s] - cy, dz = pz[s] - cz;
            float nd = fmaf(dx, dx, fmaf(dy, dy, dz * dz));
            float m2 = fminf(md[s], nd);
            md[s] = m2;
            float sc = m2 * wv[s];
            bool g = sc > best;           // strict > keeps earliest (lowest idx)
            best = g ? sc : best;
            bix = g ? ((s << 8) + TID) : bix;
        }
        // score >= 0 always -> float bits monotone under unsigned compare
        unsigned long long k =
            ((unsigned long long)__float_as_uint(best) << 32) | (unsigned)(2047 - bix);
        k = dpp_max_u64<0x111>(k);   // row_shr:1
        k = dpp_max_u64<0x112>(k);   // row_shr:2
        k = dpp_max_u64<0x114>(k);   // row_shr:4
        k = dpp_max_u64<0x118>(k);   // row_shr:8
        k = dpp_max_u64<0x142>(k);   // row_bcast15
        k = dpp_max_u64<0x143>(k);   // row_bcast31 -> lane63 has wave max
        int pbase = (t & 1) << 2;
        if (lane == 63) rec[pbase | w4] = k;
        __syncthreads();
        unsigned long long k0 = rec[pbase + 0];
        unsigned long long k1 = rec[pbase + 1];
        unsigned long long k2 = rec[pbase + 2];
        unsigned long long k3 = rec[pbase + 3];
        unsigned long long ka = k0 > k1 ? k0 : k1;
        unsigned long long kb = k2 > k3 ? k2 : k3;
        unsigned long long km = ka > kb ? ka : kb;
        int nbix = 2047 - (int)(unsigned)(km & 0xffffffffULL);  // uniform winner
        if (TID == 0) sidx[t] = nbix;
        float4 cc = sp[nbix];        // uniform (broadcast) read
        cx = cc.x; cy = cc.y; cz = cc.z;
    }
    __syncthreads();
    for (int j = TID; j < M; j += 256) {
        int id = sidx[j];
        float4 qv = sp[id];
        outPos[cloud * M + j] = qv;
        if (outCurv) outCurv[cloud * M + j] = srccurv[cloud * N + id];
        if (outA) {
            float* a = outA + (size_t)(cloud * M + j) * ldA;
            a[256] = qv.x; a[257] = qv.y; a[258] = qv.z;
        }
    }
}

// Standalone fps1 (2048 -> 1024)
__global__ __launch_bounds__(256, 1) void fps1_kernel(
    const float* __restrict__ pos, const float* __restrict__ curv,
    float4* __restrict__ pos1, float* __restrict__ curv1) {
    __shared__ float4 sp[2048];
    __shared__ int sidx[1024];
    __shared__ unsigned long long rec[8];
    fps_body<2048, 1024, 8>(pos, 3, curv, blockIdx.x, pos1, curv1, nullptr, 0,
                            sp, sidx, rec);
}

// ---------------------------------------------------------------------------
// Exact top-64 (smallest d2, idx tie-break) selection within one wave.
// ---------------------------------------------------------------------------
static __device__ __forceinline__ int select_k64(const unsigned int* ck, const int* ci,
                                                 int c, int lane, int* cnt2, int* sel,
                                                 int* nbOut) {
    if (c <= 64) {
        *nbOut = c;
        return (lane < c) ? ci[lane] : 0;
    }
    unsigned int T = 0;  // becomes the 64th-smallest key
    for (int bit = 31; bit >= 0; --bit) {
        unsigned int mid = T | (1u << bit);
        int cl = 0;
        for (int q = lane; q < c; q += 64) cl += (ck[q] < mid) ? 1 : 0;
        if (wave_sum(cl) < 64) T = mid;
    }
    int cl = 0;
    for (int q = lane; q < c; q += 64) cl += (ck[q] < T) ? 1 : 0;
    int need = 64 - wave_sum(cl);
    int TI = 0;  // becomes the need-th smallest idx among keys == T
    for (int bit = 11; bit >= 0; --bit) {
        int mid = TI | (1 << bit);
        int ce = 0;
        for (int q = lane; q < c; q += 64) ce += (ck[q] == T && ci[q] < mid) ? 1 : 0;
        if (wave_sum(ce) < need) TI = mid;
    }
    for (int q = lane; q < c; q += 64) {
        unsigned int kq = ck[q];
        int iq = ci[q];
        if (kq < T || (kq == T && iq <= TI)) sel[atomicAdd(cnt2, 1)] = iq;
    }
    *nbOut = 64;
    return sel[lane];
}

// ---------------------------------------------------------------------------
// SA1 conv body (3->64->64->128). h2 staged to LDS as fp16 pairs; L3 is
// weights-stationary: lane = channel (wave-pair covers 128 ch), fdot2 inner.
// ---------------------------------------------------------------------------
union U1 {
    struct {
        float4 sp[2048];
        unsigned ck[4][256];
        int ci[4][256];
        int sel[4][64];
        int cnt[4], cnt2[4];
    } p;
    unsigned h2s[4][2048];   // [cent][n*32 + ((q*4) ^ ((n&7)*4)) + k], half2 elems
};

static __device__ void conv1_body(
    int bid, U1& u,
    const float* __restrict__ pos, const float4* __restrict__ pos1,
    const float* __restrict__ W1, const float* __restrict__ B1,
    const float* __restrict__ W2, const float* __restrict__ B2,
    const float* __restrict__ W3, const float* __restrict__ B3,
    float* __restrict__ x1) {
    __shared__ int nbs[4];
    int cloud = bid >> 8;
    int w4 = TID >> 6, lane = TID & 63;
    int centb = (bid & 255) << 2;
    int g = (cloud << 10) + centb + w4;
    int base = cloud << 11;
    for (int j = TID; j < 2048; j += 256) {
        const float* p = pos + (size_t)(base + j) * 3;
        u.p.sp[j] = make_float4(p[0], p[1], p[2], 0.f);
    }
    if (lane == 0) { u.p.cnt[w4] = 0; u.p.cnt2[w4] = 0; }
    __syncthreads();
    float4 cq = pos1[g];
    double cx = cq.x, cy = cq.y, cz = cq.z;
    for (int s = 0; s < 32; ++s) {
        int j = (s << 6) + lane;
        float4 pj = u.p.sp[j];
        double dx = (double)pj.x - cx, dy = (double)pj.y - cy, dz = (double)pj.z - cz;
        double d2 = dx * dx + dy * dy + dz * dz;
        if (d2 <= 0.2 * 0.2) {
            int p = atomicAdd(&u.p.cnt[w4], 1);
            if (p < 256) { u.p.ck[w4][p] = __float_as_uint((float)d2); u.p.ci[w4][p] = j; }
        }
    }
    __syncthreads();
    int c = min(u.p.cnt[w4], 256);
    int nb;
    int idxn = select_k64(u.p.ck[w4], u.p.ci[w4], c, lane, &u.p.cnt2[w4],
                          u.p.sel[w4], &nb);
    if (lane == 0) nbs[w4] = nb;
    float4 pn = u.p.sp[idxn];
    float rx = pn.x - cq.x, ry = pn.y - cq.y, rz = pn.z - cq.z;
    float h1[64];
#pragma unroll
    for (int cc2 = 0; cc2 < 64; ++cc2) {
        float v = fmaf(rx, W1[cc2], fmaf(ry, W1[64 + cc2], fmaf(rz, W1[128 + cc2], B1[cc2])));
        h1[cc2] = fmaxf(v, 0.f);
    }
    float h2[64];
#pragma unroll
    for (int cc2 = 0; cc2 < 64; ++cc2) h2[cc2] = B2[cc2];
#pragma unroll
    for (int i = 0; i < 64; ++i) {
        float hv = h1[i];
        const float* wr = W2 + i * 64;
#pragma unroll
        for (int cc2 = 0; cc2 < 64; ++cc2) h2[cc2] = fmaf(hv, wr[cc2], h2[cc2]);
    }
#pragma unroll
    for (int cc2 = 0; cc2 < 64; ++cc2) h2[cc2] = fmaxf(h2[cc2], 0.f);
    __syncthreads();   // all waves done with grouping buffers / sp
    {
        unsigned* hrow = &u.h2s[w4][lane << 5];
        int sw = (lane & 7) << 2;
#pragma unroll
        for (int q = 0; q < 8; ++q) {
            unsigned tmp[4];
#pragma unroll
            for (int k2 = 0; k2 < 4; ++k2) {
                int j = (q << 2) + k2;
                tmp[k2] = packh2(h2[2 * j], h2[2 * j + 1]);
            }
            *(uint4*)&hrow[(q << 2) ^ sw] = make_uint4(tmp[0], tmp[1], tmp[2], tmp[3]);
        }
    }
    __syncthreads();   // h2s + nbs visible block-wide
    // L3: lane = channel (wave pairs cover 128 ch), 2 centroids per lane
    int ch = ((w4 & 1) << 6) + lane;
    int cbase = (w4 >> 1) << 1;
    unsigned w2[32];
#pragma unroll
    for (int p = 0; p < 32; ++p)
        w2[p] = packh2(W3[(2 * p) * 128 + ch], W3[(2 * p + 1) * 128 + ch]);
    float bv = B3[ch];
#pragma unroll 1
    for (int ci2 = 0; ci2 < 2; ++ci2) {
        int cc = cbase + ci2;
        int nbc = nbs[cc];
        float m = -1e30f;
        for (int n = 0; n < nbc; ++n) {
            const unsigned* hr = &u.h2s[cc][n << 5];
            int sw2 = (n & 7) << 2;
            float a0 = 0.f, a1 = 0.f, a2 = 0.f, a3 = 0.f;
#pragma unroll
            for (int q = 0; q < 8; ++q) {
                uint4 hv = *(const uint4*)&hr[(q << 2) ^ sw2];
                a0 = fdot2(hv.x, w2[(q << 2) + 0], a0);
                a1 = fdot2(hv.y, w2[(q << 2) + 1], a1);
                a2 = fdot2(hv.z, w2[(q << 2) + 2], a2);
                a3 = fdot2(hv.w, w2[(q << 2) + 3], a3);
            }
            m = fmaxf(m, bv + (a0 + a1) + (a2 + a3));
        }
        x1[(size_t)((cloud << 10) + centb + cc) * 128 + ch] = m;
    }
}

// ---------------------------------------------------------------------------
// Merged launch: blocks 0-7 run fps2 (1024->256), blocks 8.. run conv1.
// ---------------------------------------------------------------------------
union UM {
    U1 c;
    struct {
        float4 sp[1024];
        unsigned long long rec[8];
        int sidx[256];
    } f;
};

__global__ __launch_bounds__(256, 2) void fps2_conv1_kernel(
    const float* __restrict__ pos, const float4* __restrict__ pos1,
    const float* __restrict__ curv1, float4* __restrict__ pos2,
    float* __restrict__ Abuf,
    const float* __restrict__ W1, const float* __restrict__ B1,
    const float* __restrict__ W2, const float* __restrict__ B2,
    const float* __restrict__ W3, const float* __restrict__ B3,
    float* __restrict__ x1) {
    __shared__ UM u;
    if (blockIdx.x < 8) {
        fps_body<1024, 256, 4>((const float*)pos1, 4, curv1, blockIdx.x, pos2,
                               nullptr, Abuf, 260, u.f.sp, u.f.sidx, u.f.rec);
    } else {
        conv1_body(blockIdx.x - 8, u.c, pos, pos1, W1, B1, W2, B2, W3, B3, x1);
    }
}

// ---------------------------------------------------------------------------
// SA2: radius r=0.4 grouping + PointNetConv(131->128->128->256), all 3 layers
// as MFMA GEMMs (v_mfma_f32_16x16x32_f16):
//   L1: C[64n,128] = xs[64,160] x WaH[160,128]  (K=160: 128 x-feats + 3 rel + 0s)
//   L2: C[64n,128] = h1s[64,128] x WbH[128,128]
//   L3: C[256n,256] = h2s x WcH (block-wide, masked max in C layout)
// xs: stride-84-dword rows (bank step 20 -> <=2-way); h1s: stride-68; h2s:
// chunk-XOR layout matching L3 reads. All L1/L2 flow is wave-local (no
// barriers); h2s aliases xs (same wave). 1 block/CU (152 KB LDS).
// ---------------------------------------------------------------------------
union U2 {
    struct {
        float4 sp[1024];
        unsigned ck[4][512];
        int ci[4][512];
        int sel[4][64];
        int cnt[4], cnt2[4];
    } p;
    unsigned xs[4][5376];   // 84 dwords/row x 64 rows; h2s[cent]=xs[cent][0..4095]
};

__global__ __launch_bounds__(256, 1) void conv2_kernel(
    const float4* __restrict__ pos1, const float4* __restrict__ pos2,
    const float* __restrict__ x1,
    const unsigned* __restrict__ WaH, const float* __restrict__ Ba,
    const unsigned* __restrict__ WbH, const float* __restrict__ Bb,
    const unsigned* __restrict__ WcH, const float* __restrict__ Bc,
    float* __restrict__ Aout) {
    __shared__ U2 u;
    __shared__ unsigned h1s[4][4352];   // 68 dwords/row x 64 rows (fp16 pairs)
    __shared__ int nbs[4];
    int cloud = blockIdx.x >> 6;
    int w4 = TID >> 6, lane = TID & 63;
    int centb = (blockIdx.x & 63) << 2;
    int g = (cloud << 8) + centb + w4;
    int quad = lane >> 4, l15 = lane & 15;
    for (int j = TID; j < 1024; j += 256) u.p.sp[j] = pos1[(cloud << 10) + j];
    if (lane == 0) { u.p.cnt[w4] = 0; u.p.cnt2[w4] = 0; }
    __syncthreads();
    float4 cq = pos2[g];
    double cx = cq.x, cy = cq.y, cz = cq.z;
    for (int s = 0; s < 16; ++s) {
        int j = (s << 6) + lane;
        float4 pj = u.p.sp[j];
        double dx = (double)pj.x - cx, dy = (double)pj.y - cy, dz = (double)pj.z - cz;
        double d2 = dx * dx + dy * dy + dz * dz;
        if (d2 <= 0.4 * 0.4) {
            int p = atomicAdd(&u.p.cnt[w4], 1);
            if (p < 512) { u.p.ck[w4][p] = __float_as_uint((float)d2); u.p.ci[w4][p] = j; }
        }
    }
    __syncthreads();
    int c = min(u.p.cnt[w4], 512);
    int nb;
    int idxn = select_k64(u.p.ck[w4], u.p.ci[w4], c, lane, &u.p.cnt2[w4],
                          u.p.sel[w4], &nb);
    if (lane == 0) nbs[w4] = nb;
    float4 pn = u.p.sp[idxn];
    float rx = pn.x - cq.x, ry = pn.y - cq.y, rz = pn.z - cq.z;
    __syncthreads();   // grouping LDS dead -> xs may overwrite
    // --- stage xs: lane = row, gathered x1 row as fp16 + rel + zero pad ---
    {
        const float4* xr = (const float4*)(x1 + (size_t)((cloud << 10) + idxn) * 128);
        unsigned* row = &u.xs[w4][lane * 84];
#pragma unroll
        for (int q = 0; q < 16; ++q) {
            float4 a = xr[q * 2], b = xr[q * 2 + 1];
            *(uint4*)&row[q << 2] = make_uint4(packh2(a.x, a.y), packh2(a.z, a.w),
                                               packh2(b.x, b.y), packh2(b.z, b.w));
        }
        *(uint4*)&row[64] = make_uint4(packh2(rx, ry), packh2(rz, 0.f), 0u, 0u);
        *(uint4*)&row[68] = make_uint4(0u, 0u, 0u, 0u);
        *(uint4*)&row[72] = make_uint4(0u, 0u, 0u, 0u);
        *(uint4*)&row[76] = make_uint4(0u, 0u, 0u, 0u);
    }
    // --- L1 MFMA: h1[64 x 128] = xs[64 x 160] @ WaH; bias+relu; pack to h1s ---
    float ba8[8];
#pragma unroll
    for (int ct = 0; ct < 8; ++ct) ba8[ct] = Ba[(ct << 4) + l15];
#pragma unroll 1
    for (int ct = 0; ct < 8; ++ct) {
        f16x8 bfrag[5];
#pragma unroll
        for (int ks = 0; ks < 5; ++ks) {
            uint4 bv = *(const uint4*)&WaH[(size_t)((((ks << 3) | ct) << 6) | lane) << 2];
            __builtin_memcpy(&bfrag[ks], &bv, 16);
        }
#pragma unroll
        for (int rt = 0; rt < 4; ++rt) {
            f32x4 acc = {0.f, 0.f, 0.f, 0.f};
#pragma unroll
            for (int ks = 0; ks < 5; ++ks) {
                f16x8 af;
                uint4 av = *(const uint4*)&u.xs[w4][((rt << 4) + l15) * 84 +
                                                    (((ks << 2) + quad) << 2)];
                __builtin_memcpy(&af, &av, 16);
                acc = __builtin_amdgcn_mfma_f32_16x16x32_f16(af, bfrag[ks], acc, 0, 0, 0);
            }
#pragma unroll
            for (int r = 0; r < 4; ++r) {
                float v = fmaxf(acc[r] + ba8[ct], 0.f);
                float vp = __shfl_xor(v, 1, 64);
                if (!(l15 & 1)) {
                    int rowi = (rt << 4) + (quad << 2) + r;
                    h1s[w4][rowi * 68 + (ct << 3) + (l15 >> 1)] = packh2(v, vp);
                }
            }
        }
    }
    // --- L2 MFMA: h2[64 x 128] = h1s[64 x 128] @ WbH; bias+relu; pack to h2s ---
    unsigned* h2w = &u.xs[w4][0];   // h2s region aliases own xs (dead)
#pragma unroll
    for (int ct = 0; ct < 8; ++ct) ba8[ct] = Bb[(ct << 4) + l15];
#pragma unroll 1
    for (int ct = 0; ct < 8; ++ct) {
        f16x8 bfrag[4];
#pragma unroll
        for (int ks = 0; ks < 4; ++ks) {
            uint4 bv = *(const uint4*)&WbH[(size_t)((((ks << 3) | ct) << 6) | lane) << 2];
            __builtin_memcpy(&bfrag[ks], &bv, 16);
        }
#pragma unroll
        for (int rt = 0; rt < 4; ++rt) {
            f32x4 acc = {0.f, 0.f, 0.f, 0.f};
#pragma unroll
            for (int ks = 0; ks < 4; ++ks) {
                f16x8 af;
                uint4 av = *(const uint4*)&h1s[w4][((rt << 4) + l15) * 68 +
                                                   (((ks << 2) + quad) << 2)];
                __builtin_memcpy(&af, &av, 16);
                acc = __builtin_amdgcn_mfma_f32_16x16x32_f16(af, bfrag[ks], acc, 0, 0, 0);
            }
#pragma unroll
            for (int r = 0; r < 4; ++r) {
                float v = fmaxf(acc[r] + ba8[ct], 0.f);
                float vp = __shfl_xor(v, 1, 64);
                if (!(l15 & 1)) {
                    int rowi = (rt << 4) + (quad << 2) + r;
                    int d = (ct << 3) + (l15 >> 1);
                    int ch = d >> 2, din = d & 3;
                    h2w[(rowi << 6) + ((ch ^ (rowi & 15)) << 2) + din] = packh2(v, vp);
                }
            }
        }
    }
    __syncthreads();   // all h2s + nbs visible block-wide
    // --- L3 MFMA: wave w4 owns col-tiles [4*w4, 4*w4+4) of 16 ---
    int ctb = w4 << 2;
    f16x8 cfrag[4][4];   // [ct][ks]
#pragma unroll
    for (int ct = 0; ct < 4; ++ct)
#pragma unroll
        for (int ks = 0; ks < 4; ++ks) {
            uint4 bv = *(const uint4*)&WcH[(size_t)((((ks << 4) | (ctb + ct)) << 6) | lane) << 2];
            __builtin_memcpy(&cfrag[ct][ks], &bv, 16);
        }
#pragma unroll 1
    for (int cent = 0; cent < 4; ++cent) {
        const unsigned* h2r = &u.xs[cent][0];
        int nbc = nbs[cent];
        float runM[4][4];
#pragma unroll
        for (int ct = 0; ct < 4; ++ct)
#pragma unroll
            for (int r = 0; r < 4; ++r) runM[ct][r] = -1e30f;
#pragma unroll
        for (int rt = 0; rt < 4; ++rt) {
            int nl = (rt << 4) + l15;          // A row (neighbor) for this lane
            f16x8 afrag[4];
#pragma unroll
            for (int ks = 0; ks < 4; ++ks) {
                int cp = ((ks << 2) | quad) ^ l15;
                uint4 av = *(const uint4*)&h2r[(nl << 6) + (cp << 2)];
                __builtin_memcpy(&afrag[ks], &av, 16);
            }
#pragma unroll
            for (int ct = 0; ct < 4; ++ct) {
                f32x4 acc = {0.f, 0.f, 0.f, 0.f};
#pragma unroll
                for (int ks = 0; ks < 4; ++ks)
                    acc = __builtin_amdgcn_mfma_f32_16x16x32_f16(afrag[ks], cfrag[ct][ks],
                                                                 acc, 0, 0, 0);
                int nb0 = (rt << 4) + (quad << 2);   // C row = quad*4 + r
#pragma unroll
                for (int r = 0; r < 4; ++r) {
                    float v = (nb0 + r < nbc) ? acc[r] : -1e30f;
                    runM[ct][r] = fmaxf(runM[ct][r], v);
                }
            }
        }
#pragma unroll
        for (int ct = 0; ct < 4; ++ct) {
            float m = fmaxf(fmaxf(runM[ct][0], runM[ct][1]),
                            fmaxf(runM[ct][2], runM[ct][3]));
            m = fmaxf(m, __shfl_xor(m, 16, 64));
            m = fmaxf(m, __shfl_xor(m, 32, 64));
            if (lane < 16) {
                int cc = ((ctb + ct) << 4) | l15;   // C col = lane&15
                Aout[(size_t)((cloud << 8) + centb + cent) * 260 + cc] = m + Bc[cc];
            }
        }
    }
}

// ---------------------------------------------------------------------------
// fp32 tiled GEMM: C[M,N] = A[M,K] @ B[K,N] + bias (+relu). 64x64 tiles.
// ---------------------------------------------------------------------------
__global__ __launch_bounds__(256, 2) void gemm_bias(
    const float* __restrict__ A, int lda, const float* __restrict__ Bw, int ldb,
    const float* __restrict__ bias, float* __restrict__ C, int ldc,
    int M, int N, int K, int relu) {
    __shared__ float As[16][68];
    __shared__ float Bs[16][68];
    int nbx = N >> 6;
    int bx = blockIdx.x % nbx, by = blockIdx.x / nbx;
    int tx = TID & 15, ty = TID >> 4;
    int r0 = by << 6, c0 = bx << 6;
    float acc[4][4];
#pragma unroll
    for (int i = 0; i < 4; ++i)
#pragma unroll
        for (int j = 0; j < 4; ++j) acc[i][j] = 0.f;
    int lr = TID >> 2, lk = (TID & 3) << 2;
    int ln = TID & 63, lk2 = TID >> 6;
    for (int k0 = 0; k0 < K; k0 += 16) {
#pragma unroll
        for (int u = 0; u < 4; ++u) {
            int kk = k0 + lk + u;
            As[lk + u][lr] = (kk < K) ? A[(size_t)(r0 + lr) * lda + kk] : 0.f;
        }
#pragma unroll
        for (int u = 0; u < 4; ++u) {
            int krow = lk2 + (u << 2);
            int kk = k0 + krow;
            Bs[krow][ln] = (kk < K) ? Bw[(size_t)kk * ldb + c0 + ln] : 0.f;
        }
        __syncthreads();
#pragma unroll
        for (int kk = 0; kk < 16; ++kk) {
            float av[4], bv[4];
#pragma unroll
            for (int i = 0; i < 4; ++i) av[i] = As[kk][(ty << 2) + i];
#pragma unroll
            for (int j = 0; j < 4; ++j) bv[j] = Bs[kk][(tx << 2) + j];
#pragma unroll
            for (int i = 0; i < 4; ++i)
#pragma unroll
                for (int j = 0; j < 4; ++j) acc[i][j] = fmaf(av[i], bv[j], acc[i][j]);
        }
        __syncthreads();
    }
#pragma unroll
    for (int i = 0; i < 4; ++i) {
        int row = r0 + (ty << 2) + i;
#pragma unroll
        for (int j = 0; j < 4; ++j) {
            int col = c0 + (tx << 2) + j;
            float v = acc[i][j] + bias[col];
            if (relu) v = fmaxf(v, 0.f);
            C[(size_t)row * ldc + col] = v;
        }
    }
}

// ---------------------------------------------------------------------------
// Per-cloud max over 256 rows of h3 -> gfeat[8][1024]. 64 blocks (8/cloud).
// ---------------------------------------------------------------------------
__global__ __launch_bounds__(256) void rowmax_kernel(const float* __restrict__ h3,
                                                     float* __restrict__ gfeat) {
    __shared__ float pm[256];
    int cloud = blockIdx.x >> 3;
    int seg = blockIdx.x & 7;
    int col = (seg << 7) + (TID & 127);
    int half = TID >> 7;
    float m = -3.0e38f;
    for (int r = half << 7; r < (half << 7) + 128; ++r)
        m = fmaxf(m, h3[(size_t)((cloud << 8) + r) * 1024 + col]);
    pm[TID] = m;
    __syncthreads();
    if (TID < 128) gfeat[(cloud << 10) + col] = fmaxf(pm[TID], pm[TID + 128]);
}

// ---------------------------------------------------------------------------
// Head MLP 1024->512->256->10 + log_softmax (one block per cloud)
// ---------------------------------------------------------------------------
__global__ __launch_bounds__(256) void head_kernel(
    const float* __restrict__ gfeat,
    const float* __restrict__ Wh1, const float* __restrict__ bh1,
    const float* __restrict__ Wh2, const float* __restrict__ bh2,
    const float* __restrict__ Wh3, const float* __restrict__ bh3,
    float* __restrict__ out) {
    __shared__ float gg[1024];
    __shared__ float s1[512];
    __shared__ float s2[256];
    __shared__ float lg[10];
    int cloud = blockIdx.x;
    for (int i = TID; i < 1024; i += 256) gg[i] = gfeat[(cloud << 10) + i];
    __syncthreads();
    for (int cc = TID; cc < 512; cc += 256) {
        float v = bh1[cc];
        for (int i = 0; i < 1024; ++i) v = fmaf(gg[i], Wh1[i * 512 + cc], v);
        s1[cc] = fmaxf(v, 0.f);
    }
    __syncthreads();
    for (int cc = TID; cc < 256; cc += 256) {
        float v = bh2[cc];
        for (int i = 0; i < 512; ++i) v = fmaf(s1[i], Wh2[i * 256 + cc], v);
        s2[cc] = fmaxf(v, 0.f);
    }
    __syncthreads();
    if (TID < 10) {
        float v = bh3[TID];
        for (int i = 0; i < 256; ++i) v = fmaf(s2[i], Wh3[i * 10 + TID], v);
        lg[TID] = v;
    }
    __syncthreads();
    if (TID == 0) {
        float mx = lg[0];
        for (int i = 1; i < 10; ++i) mx = fmaxf(mx, lg[i]);
        float s = 0.f;
        for (int i = 0; i < 10; ++i) s += expf(lg[i] - mx);
        float lse = mx + logf(s);
        for (int i = 0; i < 10; ++i) out[cloud * 10 + i] = lg[i] - lse;
    }
}

// ---------------------------------------------------------------------------
// Launch. Workspace layout (12.5 MB total; regions reused across phases).
// Packed fp16 weights: WcH @335872 (64K), WaH @401408 (40K), WbH @442368 (32K).
// ---------------------------------------------------------------------------
extern "C" void kernel_launch(void* const* d_in, const int* in_sizes, int n_in,
                              void* d_out, int out_size, void* d_ws, size_t ws_size,
                              hipStream_t stream) {
    (void)in_sizes; (void)n_in; (void)out_size; (void)ws_size;
    const float* pos = (const float*)d_in[0];
    const float* W1a = (const float*)d_in[1];  const float* b1a = (const float*)d_in[2];
    const float* W1b = (const float*)d_in[3];  const float* b1b = (const float*)d_in[4];
    const float* W1c = (const float*)d_in[5];  const float* b1c = (const float*)d_in[6];
    const float* W2a = (const float*)d_in[7];  const float* b2a = (const float*)d_in[8];
    const float* W2b = (const float*)d_in[9];  const float* b2b = (const float*)d_in[10];
    const float* W2c = (const float*)d_in[11]; const float* b2c = (const float*)d_in[12];
    const float* W3a = (const float*)d_in[13]; const float* b3a = (const float*)d_in[14];
    const float* W3b = (const float*)d_in[15]; const float* b3b = (const float*)d_in[16];
    const float* W3c = (const float*)d_in[17]; const float* b3c = (const float*)d_in[18];
    const float* Wh1 = (const float*)d_in[19]; const float* bh1 = (const float*)d_in[20];
    const float* Wh2 = (const float*)d_in[21]; const float* bh2 = (const float*)d_in[22];
    const float* Wh3 = (const float*)d_in[23]; const float* bh3 = (const float*)d_in[24];

    char* ws = (char*)d_ws;
    float*    curv  = (float*)(ws + 0);
    float4*   pos1  = (float4*)(ws + 98304);
    float*    curv1 = (float*)(ws + 229376);
    float4*   pos2  = (float4*)(ws + 270336);
    float*    gfeat = (float*)(ws + 303104);
    unsigned* WcH   = (unsigned*)(ws + 335872);
    unsigned* WaH   = (unsigned*)(ws + 401408);
    unsigned* WbH   = (unsigned*)(ws + 442368);
    float*    x1    = (float*)(ws + 524288);
    float*    Abuf  = (float*)(ws + 4718592);
    float*    h1g   = (float*)(ws + 6848512);
    float*    h2g   = x1;     // x1 dead after conv2
    float*    h3g   = Abuf;   // A + h1g dead after gemm2

    pack_w_kernel<<<16, 256, 0, stream>>>(W2c, WcH, 128, 256);
    pack_w_kernel<<<10, 256, 0, stream>>>(W2a, WaH, 131, 128);
    pack_w_kernel<<<8, 256, 0, stream>>>(W2b, WbH, 128, 128);
    curv_kernel<<<64, 256, 0, stream>>>(pos, curv);
    fps1_kernel<<<8, 256, 0, stream>>>(pos, curv, pos1, curv1);
    fps2_conv1_kernel<<<2056, 256, 0, stream>>>(pos, pos1, curv1, pos2, Abuf,
                                                W1a, b1a, W1b, b1b, W1c, b1c, x1);
    conv2_kernel<<<512, 256, 0, stream>>>(pos1, pos2, x1, WaH, b2a, WbH, b2b, WcH, b2c,
                                          Abuf);
    gemm_bias<<<128, 256, 0, stream>>>(Abuf, 260, W3a, 256, b3a, h1g, 256,
                                       2048, 256, 259, 1);
    gemm_bias<<<256, 256, 0, stream>>>(h1g, 256, W3b, 512, b3b, h2g, 512,
                                       2048, 512, 256, 1);
    gemm_bias<<<512, 256, 0, stream>>>(h2g, 512, W3c, 1024, b3c, h3g, 1024,
                                       2048, 1024, 512, 0);
    rowmax_kernel<<<64, 256, 0, stream>>>(h3g, gfeat);
    head_kernel<<<8, 256, 0, stream>>>(gfeat, Wh1, bh1, Wh2, bh2, Wh3, bh3,
                                       (float*)d_out);
}